// Round 1
// baseline (1458.365 us; speedup 1.0000x reference)
//
#include <hip/hip_runtime.h>
#include <hip/hip_bf16.h>
#include <math.h>

// Problem constants
#define D_MODEL   768
#define D_INNER   1536
#define D_STATE   128
#define HEADDIM   64
#define NHEADS    24
#define D_CONV    4
#define CONV_DIM  1792            // D_INNER + 2*D_STATE
#define D_IN_PROJ 3352            // 2*D_INNER + 2*D_STATE + NHEADS
#define BATCH     2
#define SEQLEN    2048
#define NROWS     (BATCH*SEQLEN)  // 4096
#define EPS       1e-5f

// ---------------------------------------------------------------------------
// GEMM: C[m][n] = sum_k A[m*K+k] * W[n*K+k]   (A row-major MxK, W row-major NxK)
// 64x64 tile, BK=16, 256 threads, 4x4 per-thread micro-tile. fp32.
// ---------------------------------------------------------------------------
__global__ __launch_bounds__(256) void gemm_at_kernel(
    const float* __restrict__ A, const float* __restrict__ W,
    float* __restrict__ C, int M, int N, int K)
{
    const int BK = 16;
    __shared__ float As[BK][68];   // 68*4 = 272 bytes/row: 16B-aligned float4 reads
    __shared__ float Ws[BK][68];
    int m0 = blockIdx.y * 64;
    int n0 = blockIdx.x * 64;
    int t  = threadIdx.x;
    int tx = t & 15, ty = t >> 4;
    float acc[4][4] = {};

    for (int k0 = 0; k0 < K; k0 += BK) {
        int row = t >> 2, kq = t & 3;
        // stage A (M divisible by 64: no m guard needed)
        float4 av = *(const float4*)(A + (size_t)(m0 + row) * K + k0 + kq * 4);
        As[kq*4+0][row] = av.x;
        As[kq*4+1][row] = av.y;
        As[kq*4+2][row] = av.z;
        As[kq*4+3][row] = av.w;
        // stage W with n guard (N=3352 not divisible by 64)
        float4 wv = make_float4(0.f, 0.f, 0.f, 0.f);
        if (n0 + row < N)
            wv = *(const float4*)(W + (size_t)(n0 + row) * K + k0 + kq * 4);
        Ws[kq*4+0][row] = wv.x;
        Ws[kq*4+1][row] = wv.y;
        Ws[kq*4+2][row] = wv.z;
        Ws[kq*4+3][row] = wv.w;
        __syncthreads();
        #pragma unroll
        for (int k = 0; k < BK; ++k) {
            float4 a  = *(const float4*)&As[k][ty * 4];
            float4 bb = *(const float4*)&Ws[k][tx * 4];
            float avv[4] = {a.x, a.y, a.z, a.w};
            float bvv[4] = {bb.x, bb.y, bb.z, bb.w};
            #pragma unroll
            for (int i = 0; i < 4; ++i)
                #pragma unroll
                for (int j = 0; j < 4; ++j)
                    acc[i][j] = fmaf(avv[i], bvv[j], acc[i][j]);
        }
        __syncthreads();
    }
    #pragma unroll
    for (int i = 0; i < 4; ++i) {
        int m = m0 + ty * 4 + i;
        #pragma unroll
        for (int j = 0; j < 4; ++j) {
            int n = n0 + tx * 4 + j;
            if (n < N) C[(size_t)m * N + n] = acc[i][j];
        }
    }
}

// ---------------------------------------------------------------------------
// Depthwise causal conv (k=4) + bias + SiLU over xBC slice of zxbcdt.
// zx: [NROWS][3352], cols 1536..3327 are xBC. out: [NROWS][1792].
// ---------------------------------------------------------------------------
__global__ __launch_bounds__(256) void conv_silu_kernel(
    const float* __restrict__ zx, float* __restrict__ out,
    const float* __restrict__ cw, const float* __restrict__ cb)
{
    int c = blockIdx.x * 256 + threadIdx.x;   // channel 0..1791
    int r = blockIdx.y;                       // row 0..4095
    if (c >= CONV_DIM) return;
    int l = r & (SEQLEN - 1);
    const float4 w = *(const float4*)(cw + (size_t)c * 4);
    const float wj[4] = {w.x, w.y, w.z, w.w};
    const float* col = zx + D_INNER + c;
    float acc = cb[c];
    #pragma unroll
    for (int j = 0; j < 4; ++j) {
        int ll = l - 3 + j;
        if (ll >= 0) acc = fmaf(col[(size_t)(r - 3 + j) * D_IN_PROJ], wj[j], acc);
    }
    // SiLU
    out[(size_t)r * CONV_DIM + c] = acc / (1.f + expf(-acc));
}

// ---------------------------------------------------------------------------
// dt_dis = softplus(dt + dt_bias),  dA = exp(dt_dis * (-exp(A_log)))
// dt lives at zx cols 3328..3351.
// ---------------------------------------------------------------------------
__global__ __launch_bounds__(256) void dt_kernel(
    const float* __restrict__ zx, const float* __restrict__ dt_bias,
    const float* __restrict__ A_log, float* __restrict__ dtb, float* __restrict__ dAb)
{
    int idx = blockIdx.x * 256 + threadIdx.x;   // r*24 + h
    if (idx >= NROWS * NHEADS) return;
    int r = idx / NHEADS, h = idx - r * NHEADS;
    float x = zx[(size_t)r * D_IN_PROJ + (D_INNER + CONV_DIM) + h] + dt_bias[h];
    float sp = (x > 20.f) ? x : log1pf(expf(x));
    float A  = -expf(A_log[h]);
    dtb[idx] = sp;
    dAb[idx] = expf(sp * A);
}

// ---------------------------------------------------------------------------
// Selective scan. Grid: 192 blocks = (b:2, h:24, pchunk:4). 256 threads:
// tid = p_local*16 + tn;  p = pchunk*16 + p_local;  n-range = tn*8 .. +7.
// 8 state elems / thread in registers; sequential over L with reg prefetch.
// y[r][h*64+p] = sum_n s[p][n]*C[n] + D[h]*x[p]
// ---------------------------------------------------------------------------
__global__ __launch_bounds__(256) void scan_kernel(
    const float* __restrict__ co,   // conv_out [NROWS][1792]
    const float* __restrict__ dtb,  // [NROWS][24]
    const float* __restrict__ dAb,  // [NROWS][24]
    const float* __restrict__ Dvec, // [24]
    float* __restrict__ ybuf)       // [NROWS][1536]
{
    int blk = blockIdx.x;
    int pc = blk & 3;
    int h  = (blk >> 2) % NHEADS;
    int b  = blk / (NHEADS * 4);
    int tid = threadIdx.x;
    int pl = tid >> 4;      // 0..15
    int tn = tid & 15;      // 0..15
    int p  = pc * 16 + pl;
    int n0 = tn * 8;
    const int R0 = b * SEQLEN;

    float s[8];
    #pragma unroll
    for (int i = 0; i < 8; ++i) s[i] = 0.f;
    const float Dh = Dvec[h];

    const float* base = co + (size_t)R0 * CONV_DIM;
    const int xcol = h * HEADDIM + p;
    const int bcol = D_INNER + n0;
    const int ccol = D_INNER + D_STATE + n0;

    // prefetch l = 0
    float4 Bv0 = *(const float4*)(base + bcol);
    float4 Bv1 = *(const float4*)(base + bcol + 4);
    float4 Cv0 = *(const float4*)(base + ccol);
    float4 Cv1 = *(const float4*)(base + ccol + 4);
    float xv  = base[xcol];
    float dAv = dAb[(size_t)R0 * NHEADS + h];
    float dtv = dtb[(size_t)R0 * NHEADS + h];

    for (int l = 0; l < SEQLEN; ++l) {
        float4 nB0 = make_float4(0,0,0,0), nB1 = nB0, nC0 = nB0, nC1 = nB0;
        float nx = 0.f, ndA = 0.f, ndt = 0.f;
        if (l + 1 < SEQLEN) {
            const float* row = base + (size_t)(l + 1) * CONV_DIM;
            nB0 = *(const float4*)(row + bcol);
            nB1 = *(const float4*)(row + bcol + 4);
            nC0 = *(const float4*)(row + ccol);
            nC1 = *(const float4*)(row + ccol + 4);
            nx  = row[xcol];
            ndA = dAb[(size_t)(R0 + l + 1) * NHEADS + h];
            ndt = dtb[(size_t)(R0 + l + 1) * NHEADS + h];
        }
        const float t = dtv * xv;
        float yp = 0.f;
        const float Barr[8] = {Bv0.x,Bv0.y,Bv0.z,Bv0.w,Bv1.x,Bv1.y,Bv1.z,Bv1.w};
        const float Carr[8] = {Cv0.x,Cv0.y,Cv0.z,Cv0.w,Cv1.x,Cv1.y,Cv1.z,Cv1.w};
        #pragma unroll
        for (int i = 0; i < 8; ++i) {
            s[i] = fmaf(s[i], dAv, Barr[i] * t);
            yp   = fmaf(s[i], Carr[i], yp);
        }
        // reduce over tn (16 lanes; tn occupies lane bits 0..3)
        yp += __shfl_xor(yp, 1);
        yp += __shfl_xor(yp, 2);
        yp += __shfl_xor(yp, 4);
        yp += __shfl_xor(yp, 8);
        if (tn == 0)
            ybuf[(size_t)(R0 + l) * D_INNER + xcol] = yp + Dh * xv;
        Bv0 = nB0; Bv1 = nB1; Cv0 = nC0; Cv1 = nC1;
        xv = nx; dAv = ndA; dtv = ndt;
    }
}

// ---------------------------------------------------------------------------
// yz = y * silu(z);  yn = yz * rsqrt(mean(yz^2) + eps) * norm_w
// One block per row; 256 threads x 6 elems.
// ---------------------------------------------------------------------------
__global__ __launch_bounds__(256) void gate_norm_kernel(
    const float* __restrict__ zx, const float* __restrict__ ybuf,
    const float* __restrict__ norm_w, float* __restrict__ yn)
{
    int r = blockIdx.x;
    const float* zrow = zx + (size_t)r * D_IN_PROJ;       // z = cols 0..1535
    const float* yrow = ybuf + (size_t)r * D_INNER;
    float vals[6];
    float ss = 0.f;
    #pragma unroll
    for (int i = 0; i < 6; ++i) {
        int c = threadIdx.x + i * 256;
        float z = zrow[c];
        float y = yrow[c];
        float v = y * (z / (1.f + expf(-z)));
        vals[i] = v;
        ss = fmaf(v, v, ss);
    }
    ss += __shfl_xor(ss, 1);
    ss += __shfl_xor(ss, 2);
    ss += __shfl_xor(ss, 4);
    ss += __shfl_xor(ss, 8);
    ss += __shfl_xor(ss, 16);
    ss += __shfl_xor(ss, 32);
    __shared__ float red[4];
    if ((threadIdx.x & 63) == 0) red[threadIdx.x >> 6] = ss;
    __syncthreads();
    float tot = red[0] + red[1] + red[2] + red[3];
    float scale = rsqrtf(tot / (float)D_INNER + EPS);
    #pragma unroll
    for (int i = 0; i < 6; ++i) {
        int c = threadIdx.x + i * 256;
        yn[(size_t)r * D_INNER + c] = vals[i] * scale * norm_w[c];
    }
}

// ---------------------------------------------------------------------------
extern "C" void kernel_launch(void* const* d_in, const int* in_sizes, int n_in,
                              void* d_out, int out_size, void* d_ws, size_t ws_size,
                              hipStream_t stream) {
    const float* u          = (const float*)d_in[0];
    const float* in_proj_w  = (const float*)d_in[1];
    const float* conv_w     = (const float*)d_in[2];
    const float* conv_b     = (const float*)d_in[3];
    const float* dt_bias    = (const float*)d_in[4];
    const float* A_log      = (const float*)d_in[5];
    const float* Dvec       = (const float*)d_in[6];
    const float* norm_w     = (const float*)d_in[7];
    const float* out_proj_w = (const float*)d_in[8];
    float* out = (float*)d_out;

    // workspace carve-up (fp32):
    float* zx   = (float*)d_ws;                       // 4096*3352
    float* co   = zx  + (size_t)NROWS * D_IN_PROJ;    // 4096*1792
    float* dtb  = co  + (size_t)NROWS * CONV_DIM;     // 4096*24
    float* dAb  = dtb + (size_t)NROWS * NHEADS;       // 4096*24
    float* ybuf = dAb + (size_t)NROWS * NHEADS;       // 4096*1536
    float* ynb  = co;  // reuse conv_out region after scan (conv_out dead by then)

    // 1) in-proj GEMM: zx = u @ in_proj_w.T   (M=4096, N=3352, K=768)
    {
        dim3 g((D_IN_PROJ + 63) / 64, NROWS / 64);
        gemm_at_kernel<<<g, 256, 0, stream>>>(u, in_proj_w, zx, NROWS, D_IN_PROJ, D_MODEL);
    }
    // 2) depthwise conv + SiLU
    conv_silu_kernel<<<dim3(CONV_DIM / 256, NROWS), 256, 0, stream>>>(zx, co, conv_w, conv_b);
    // 3) dt_dis / dA
    dt_kernel<<<(NROWS * NHEADS + 255) / 256, 256, 0, stream>>>(zx, dt_bias, A_log, dtb, dAb);
    // 4) selective scan
    scan_kernel<<<BATCH * NHEADS * 4, 256, 0, stream>>>(co, dtb, dAb, Dvec, ybuf);
    // 5) gate + RMSNorm
    gate_norm_kernel<<<NROWS, 256, 0, stream>>>(zx, ybuf, norm_w, ynb);
    // 6) out-proj GEMM: out = yn @ out_proj_w.T   (M=4096, N=768, K=1536)
    {
        dim3 g(D_MODEL / 64, NROWS / 64);
        gemm_at_kernel<<<g, 256, 0, stream>>>(ynb, out_proj_w, out, NROWS, D_MODEL, D_INNER);
    }
}

// Round 2
// 1000.307 us; speedup vs baseline: 1.4579x; 1.4579x over previous
//
#include <hip/hip_runtime.h>
#include <hip/hip_bf16.h>
#include <math.h>

// Problem constants
#define D_MODEL   768
#define D_INNER   1536
#define D_STATE   128
#define HEADDIM   64
#define NHEADS    24
#define D_CONV    4
#define CONV_DIM  1792            // D_INNER + 2*D_STATE
#define D_IN_PROJ 3352            // 2*D_INNER + 2*D_STATE + NHEADS
#define BATCH     2
#define SEQLEN    2048
#define NROWS     (BATCH*SEQLEN)  // 4096
#define EPS       1e-5f

#define NCHUNK    16
#define CHUNK     128             // SEQLEN / NCHUNK
#define STATE_SZ  (HEADDIM*D_STATE)   // 8192 per (b,h,chunk)

// ---------------------------------------------------------------------------
// GEMM: C[m][n] = sum_k A[m*K+k] * W[n*K+k]   (A row-major MxK, W row-major NxK)
// 64x64 tile, BK=16, 256 threads, 4x4 per-thread micro-tile. fp32.
// ---------------------------------------------------------------------------
__global__ __launch_bounds__(256) void gemm_at_kernel(
    const float* __restrict__ A, const float* __restrict__ W,
    float* __restrict__ C, int M, int N, int K)
{
    const int BK = 16;
    __shared__ float As[BK][68];
    __shared__ float Ws[BK][68];
    int m0 = blockIdx.y * 64;
    int n0 = blockIdx.x * 64;
    int t  = threadIdx.x;
    int tx = t & 15, ty = t >> 4;
    float acc[4][4] = {};

    for (int k0 = 0; k0 < K; k0 += BK) {
        int row = t >> 2, kq = t & 3;
        float4 av = *(const float4*)(A + (size_t)(m0 + row) * K + k0 + kq * 4);
        As[kq*4+0][row] = av.x;
        As[kq*4+1][row] = av.y;
        As[kq*4+2][row] = av.z;
        As[kq*4+3][row] = av.w;
        float4 wv = make_float4(0.f, 0.f, 0.f, 0.f);
        if (n0 + row < N)
            wv = *(const float4*)(W + (size_t)(n0 + row) * K + k0 + kq * 4);
        Ws[kq*4+0][row] = wv.x;
        Ws[kq*4+1][row] = wv.y;
        Ws[kq*4+2][row] = wv.z;
        Ws[kq*4+3][row] = wv.w;
        __syncthreads();
        #pragma unroll
        for (int k = 0; k < BK; ++k) {
            float4 a  = *(const float4*)&As[k][ty * 4];
            float4 bb = *(const float4*)&Ws[k][tx * 4];
            float avv[4] = {a.x, a.y, a.z, a.w};
            float bvv[4] = {bb.x, bb.y, bb.z, bb.w};
            #pragma unroll
            for (int i = 0; i < 4; ++i)
                #pragma unroll
                for (int j = 0; j < 4; ++j)
                    acc[i][j] = fmaf(avv[i], bvv[j], acc[i][j]);
        }
        __syncthreads();
    }
    #pragma unroll
    for (int i = 0; i < 4; ++i) {
        int m = m0 + ty * 4 + i;
        #pragma unroll
        for (int j = 0; j < 4; ++j) {
            int n = n0 + tx * 4 + j;
            if (n < N) C[(size_t)m * N + n] = acc[i][j];
        }
    }
}

// ---------------------------------------------------------------------------
// Depthwise causal conv (k=4) + bias + SiLU.
// ---------------------------------------------------------------------------
__global__ __launch_bounds__(256) void conv_silu_kernel(
    const float* __restrict__ zx, float* __restrict__ out,
    const float* __restrict__ cw, const float* __restrict__ cb)
{
    int c = blockIdx.x * 256 + threadIdx.x;
    int r = blockIdx.y;
    if (c >= CONV_DIM) return;
    int l = r & (SEQLEN - 1);
    const float4 w = *(const float4*)(cw + (size_t)c * 4);
    const float wj[4] = {w.x, w.y, w.z, w.w};
    const float* col = zx + D_INNER + c;
    float acc = cb[c];
    #pragma unroll
    for (int j = 0; j < 4; ++j) {
        int ll = l - 3 + j;
        if (ll >= 0) acc = fmaf(col[(size_t)(r - 3 + j) * D_IN_PROJ], wj[j], acc);
    }
    out[(size_t)r * CONV_DIM + c] = acc / (1.f + expf(-acc));
}

// ---------------------------------------------------------------------------
// dt_dis = softplus(dt + dt_bias),  dA = exp(dt_dis * (-exp(A_log)))
// ---------------------------------------------------------------------------
__global__ __launch_bounds__(256) void dt_kernel(
    const float* __restrict__ zx, const float* __restrict__ dt_bias,
    const float* __restrict__ A_log, float* __restrict__ dtb, float* __restrict__ dAb)
{
    int idx = blockIdx.x * 256 + threadIdx.x;
    if (idx >= NROWS * NHEADS) return;
    int r = idx / NHEADS, h = idx - r * NHEADS;
    float x = zx[(size_t)r * D_IN_PROJ + (D_INNER + CONV_DIM) + h] + dt_bias[h];
    float sp = (x > 20.f) ? x : log1pf(expf(x));
    float A  = -expf(A_log[h]);
    dtb[idx] = sp;
    dAb[idx] = expf(sp * A);
}

// ---------------------------------------------------------------------------
// Scan pass 1: per-chunk local scan (zero init), 128 steps.
// grid = b*h*chunk*pc = 2*24*16*4 = 6144 blocks, 256 threads (pl=tid>>4, tn=tid&15).
// Writes: y_intra (+ D*x) to ybuf, chunk-end local state to sstate,
//         within-chunk cumprod of dA to cumW (pc==0, tid==0 only).
// ---------------------------------------------------------------------------
__global__ __launch_bounds__(256) void scan_chunk_local(
    const float* __restrict__ co, const float* __restrict__ dtb,
    const float* __restrict__ dAb, const float* __restrict__ Dvec,
    float* __restrict__ ybuf, float* __restrict__ sstate, float* __restrict__ cumW)
{
    int t = blockIdx.x;
    int pc = t & 3;  t >>= 2;
    int c  = t & 15; t >>= 4;
    int h  = t % NHEADS;
    int b  = t / NHEADS;
    int tid = threadIdx.x;
    int pl = tid >> 4;
    int tn = tid & 15;
    int p  = pc * 16 + pl;
    int n0 = tn * 8;
    const int R0 = b * SEQLEN + c * CHUNK;

    float s[8];
    #pragma unroll
    for (int i = 0; i < 8; ++i) s[i] = 0.f;
    const float Dh = Dvec[h];

    const float* base = co + (size_t)R0 * CONV_DIM;
    const int xcol = h * HEADDIM + p;
    const int bcol = D_INNER + n0;
    const int ccol = D_INNER + D_STATE + n0;
    float* cwrow = cumW + ((size_t)(b * NHEADS + h)) * SEQLEN + c * CHUNK;

    // prefetch l = 0
    float4 Bv0 = *(const float4*)(base + bcol);
    float4 Bv1 = *(const float4*)(base + bcol + 4);
    float4 Cv0 = *(const float4*)(base + ccol);
    float4 Cv1 = *(const float4*)(base + ccol + 4);
    float xv  = base[xcol];
    float dAv = dAb[(size_t)R0 * NHEADS + h];
    float dtv = dtb[(size_t)R0 * NHEADS + h];
    float prodA = 1.f;

    for (int l = 0; l < CHUNK; ++l) {
        float4 nB0 = make_float4(0,0,0,0), nB1 = nB0, nC0 = nB0, nC1 = nB0;
        float nx = 0.f, ndA = 0.f, ndt = 0.f;
        if (l + 1 < CHUNK) {
            const float* row = base + (size_t)(l + 1) * CONV_DIM;
            nB0 = *(const float4*)(row + bcol);
            nB1 = *(const float4*)(row + bcol + 4);
            nC0 = *(const float4*)(row + ccol);
            nC1 = *(const float4*)(row + ccol + 4);
            nx  = row[xcol];
            ndA = dAb[(size_t)(R0 + l + 1) * NHEADS + h];
            ndt = dtb[(size_t)(R0 + l + 1) * NHEADS + h];
        }
        const float tt = dtv * xv;
        float yp = 0.f;
        const float Barr[8] = {Bv0.x,Bv0.y,Bv0.z,Bv0.w,Bv1.x,Bv1.y,Bv1.z,Bv1.w};
        const float Carr[8] = {Cv0.x,Cv0.y,Cv0.z,Cv0.w,Cv1.x,Cv1.y,Cv1.z,Cv1.w};
        #pragma unroll
        for (int i = 0; i < 8; ++i) {
            s[i] = fmaf(s[i], dAv, Barr[i] * tt);
            yp   = fmaf(s[i], Carr[i], yp);
        }
        prodA *= dAv;
        if (pc == 0 && tid == 0) cwrow[l] = prodA;
        yp += __shfl_xor(yp, 1);
        yp += __shfl_xor(yp, 2);
        yp += __shfl_xor(yp, 4);
        yp += __shfl_xor(yp, 8);
        if (tn == 0)
            ybuf[(size_t)(R0 + l) * D_INNER + xcol] = yp + Dh * xv;
        Bv0 = nB0; Bv1 = nB1; Cv0 = nC0; Cv1 = nC1;
        xv = nx; dAv = ndA; dtv = ndt;
    }
    // store chunk-end local state
    size_t sidx = (((size_t)(b * NHEADS + h)) * NCHUNK + c) * STATE_SZ + p * D_STATE + n0;
    *(float4*)(sstate + sidx)     = make_float4(s[0], s[1], s[2], s[3]);
    *(float4*)(sstate + sidx + 4) = make_float4(s[4], s[5], s[6], s[7]);
}

// ---------------------------------------------------------------------------
// Scan pass 2: prefix over chunk states per (b,h). In-place: slot c becomes
// the INITIAL state for chunk c. grid = 48 blocks, 256 threads x 32 elems.
// ---------------------------------------------------------------------------
__global__ __launch_bounds__(256) void scan_chunk_prefix(
    const float* __restrict__ cumW, float* __restrict__ sstate)
{
    int bh = blockIdx.x;   // 0..47
    int tid = threadIdx.x;
    float* base = sstate + (size_t)bh * NCHUNK * STATE_SZ;
    const float* cw = cumW + (size_t)bh * SEQLEN;
    float4 run[8];
    #pragma unroll
    for (int k = 0; k < 8; ++k) run[k] = make_float4(0.f, 0.f, 0.f, 0.f);
    for (int c = 0; c < NCHUNK; ++c) {
        float Ac = cw[c * CHUNK + (CHUNK - 1)];
        float* slab = base + (size_t)c * STATE_SZ;
        #pragma unroll
        for (int k = 0; k < 8; ++k) {
            float* ptr = slab + tid * 4 + k * 1024;
            float4 loc = *(float4*)ptr;
            float4 r = run[k];
            *(float4*)ptr = r;
            run[k].x = fmaf(Ac, r.x, loc.x);
            run[k].y = fmaf(Ac, r.y, loc.y);
            run[k].z = fmaf(Ac, r.z, loc.z);
            run[k].w = fmaf(Ac, r.w, loc.w);
        }
    }
}

// ---------------------------------------------------------------------------
// Scan pass 3: add inter-chunk contribution y[l] += cumW[l] * (C_l . s_init).
// Fully parallel over l. grid = 6144 blocks, 256 threads as pass 1.
// ---------------------------------------------------------------------------
__global__ __launch_bounds__(256) void scan_inter(
    const float* __restrict__ co, const float* __restrict__ cumW,
    const float* __restrict__ sstate, float* __restrict__ ybuf)
{
    int t = blockIdx.x;
    int pc = t & 3;  t >>= 2;
    int c  = t & 15; t >>= 4;
    int h  = t % NHEADS;
    int b  = t / NHEADS;
    int tid = threadIdx.x;
    int pl = tid >> 4;
    int tn = tid & 15;
    int p  = pc * 16 + pl;
    int n0 = tn * 8;
    const int R0 = b * SEQLEN + c * CHUNK;
    const int xcol = h * HEADDIM + p;
    const int ccol = D_INNER + D_STATE + n0;

    size_t sidx = (((size_t)(b * NHEADS + h)) * NCHUNK + c) * STATE_SZ + p * D_STATE + n0;
    float4 s0 = *(const float4*)(sstate + sidx);
    float4 s1 = *(const float4*)(sstate + sidx + 4);
    const float sin_[8] = {s0.x, s0.y, s0.z, s0.w, s1.x, s1.y, s1.z, s1.w};
    const float* cwrow = cumW + ((size_t)(b * NHEADS + h)) * SEQLEN + c * CHUNK;
    const float* base = co + (size_t)R0 * CONV_DIM;

    for (int l = 0; l < CHUNK; ++l) {
        const float* row = base + (size_t)l * CONV_DIM + ccol;
        float4 C0 = *(const float4*)(row);
        float4 C1 = *(const float4*)(row + 4);
        float dot = sin_[0] * C0.x;
        dot = fmaf(sin_[1], C0.y, dot);
        dot = fmaf(sin_[2], C0.z, dot);
        dot = fmaf(sin_[3], C0.w, dot);
        dot = fmaf(sin_[4], C1.x, dot);
        dot = fmaf(sin_[5], C1.y, dot);
        dot = fmaf(sin_[6], C1.z, dot);
        dot = fmaf(sin_[7], C1.w, dot);
        dot += __shfl_xor(dot, 1);
        dot += __shfl_xor(dot, 2);
        dot += __shfl_xor(dot, 4);
        dot += __shfl_xor(dot, 8);
        if (tn == 0) {
            float w = cwrow[l];
            size_t idx = (size_t)(R0 + l) * D_INNER + xcol;
            ybuf[idx] += w * dot;
        }
    }
}

// ---------------------------------------------------------------------------
// yz = y * silu(z);  yn = yz * rsqrt(mean(yz^2) + eps) * norm_w
// ---------------------------------------------------------------------------
__global__ __launch_bounds__(256) void gate_norm_kernel(
    const float* __restrict__ zx, const float* __restrict__ ybuf,
    const float* __restrict__ norm_w, float* __restrict__ yn)
{
    int r = blockIdx.x;
    const float* zrow = zx + (size_t)r * D_IN_PROJ;
    const float* yrow = ybuf + (size_t)r * D_INNER;
    float vals[6];
    float ss = 0.f;
    #pragma unroll
    for (int i = 0; i < 6; ++i) {
        int c = threadIdx.x + i * 256;
        float z = zrow[c];
        float y = yrow[c];
        float v = y * (z / (1.f + expf(-z)));
        vals[i] = v;
        ss = fmaf(v, v, ss);
    }
    ss += __shfl_xor(ss, 1);
    ss += __shfl_xor(ss, 2);
    ss += __shfl_xor(ss, 4);
    ss += __shfl_xor(ss, 8);
    ss += __shfl_xor(ss, 16);
    ss += __shfl_xor(ss, 32);
    __shared__ float red[4];
    if ((threadIdx.x & 63) == 0) red[threadIdx.x >> 6] = ss;
    __syncthreads();
    float tot = red[0] + red[1] + red[2] + red[3];
    float scale = rsqrtf(tot / (float)D_INNER + EPS);
    #pragma unroll
    for (int i = 0; i < 6; ++i) {
        int c = threadIdx.x + i * 256;
        yn[(size_t)r * D_INNER + c] = vals[i] * scale * norm_w[c];
    }
}

// ---------------------------------------------------------------------------
extern "C" void kernel_launch(void* const* d_in, const int* in_sizes, int n_in,
                              void* d_out, int out_size, void* d_ws, size_t ws_size,
                              hipStream_t stream) {
    const float* u          = (const float*)d_in[0];
    const float* in_proj_w  = (const float*)d_in[1];
    const float* conv_w     = (const float*)d_in[2];
    const float* conv_b     = (const float*)d_in[3];
    const float* dt_bias    = (const float*)d_in[4];
    const float* A_log      = (const float*)d_in[5];
    const float* Dvec       = (const float*)d_in[6];
    const float* norm_w     = (const float*)d_in[7];
    const float* out_proj_w = (const float*)d_in[8];
    float* out = (float*)d_out;

    // workspace carve-up (fp32):
    float* zx     = (float*)d_ws;                        // 4096*3352  = 13,729,792
    float* co     = zx     + (size_t)NROWS * D_IN_PROJ;  // 4096*1792  =  7,340,032
    float* dtb    = co     + (size_t)NROWS * CONV_DIM;   // 4096*24
    float* dAb    = dtb    + (size_t)NROWS * NHEADS;     // 4096*24
    float* ybuf   = dAb    + (size_t)NROWS * NHEADS;     // 4096*1536  =  6,291,456
    float* sstate = ybuf   + (size_t)NROWS * D_INNER;    // 48*16*8192 =  6,291,456
    float* cumW   = sstate + (size_t)BATCH*NHEADS*NCHUNK*STATE_SZ;  // 48*2048 = 98,304
    float* ynb    = co;  // reuse conv_out region after scan passes

    // 1) in-proj GEMM: zx = u @ in_proj_w.T   (M=4096, N=3352, K=768)
    {
        dim3 g((D_IN_PROJ + 63) / 64, NROWS / 64);
        gemm_at_kernel<<<g, 256, 0, stream>>>(u, in_proj_w, zx, NROWS, D_IN_PROJ, D_MODEL);
    }
    // 2) depthwise conv + SiLU
    conv_silu_kernel<<<dim3(CONV_DIM / 256, NROWS), 256, 0, stream>>>(zx, co, conv_w, conv_b);
    // 3) dt_dis / dA
    dt_kernel<<<(NROWS * NHEADS + 255) / 256, 256, 0, stream>>>(zx, dt_bias, A_log, dtb, dAb);
    // 4) selective scan — chunked, 3 passes
    scan_chunk_local<<<BATCH * NHEADS * NCHUNK * 4, 256, 0, stream>>>(co, dtb, dAb, Dvec, ybuf, sstate, cumW);
    scan_chunk_prefix<<<BATCH * NHEADS, 256, 0, stream>>>(cumW, sstate);
    scan_inter<<<BATCH * NHEADS * NCHUNK * 4, 256, 0, stream>>>(co, cumW, sstate, ybuf);
    // 5) gate + RMSNorm
    gate_norm_kernel<<<NROWS, 256, 0, stream>>>(zx, ybuf, norm_w, ynb);
    // 6) out-proj GEMM: out = yn @ out_proj_w.T   (M=4096, N=768, K=1536)
    {
        dim3 g(D_MODEL / 64, NROWS / 64);
        gemm_at_kernel<<<g, 256, 0, stream>>>(ynb, out_proj_w, out, NROWS, D_MODEL, D_INNER);
    }
}

// Round 3
// 656.114 us; speedup vs baseline: 2.2227x; 1.5246x over previous
//
#include <hip/hip_runtime.h>
#include <hip/hip_bf16.h>
#include <math.h>

// Problem constants
#define D_MODEL   768
#define D_INNER   1536
#define D_STATE   128
#define HEADDIM   64
#define NHEADS    24
#define D_CONV    4
#define CONV_DIM  1792            // D_INNER + 2*D_STATE
#define D_IN_PROJ 3352            // 2*D_INNER + 2*D_STATE + NHEADS
#define BATCH     2
#define SEQLEN    2048
#define NROWS     (BATCH*SEQLEN)  // 4096
#define EPS       1e-5f

#define NCHUNK    16
#define CHUNK     128             // SEQLEN / NCHUNK
#define STATE_SZ  (HEADDIM*D_STATE)   // 8192 per (b,h,chunk)

#define N1_PAD    3456            // 27*128, padded N for GEMM1

typedef __bf16 bf16x8 __attribute__((ext_vector_type(8)));
typedef float  f32x4  __attribute__((ext_vector_type(4)));

// RNE float -> bf16 bit pattern
__device__ __forceinline__ short f2b(float f) {
    unsigned u = __float_as_uint(f);
    unsigned r = (u + 0x7FFFu + ((u >> 16) & 1u)) >> 16;
    return (short)r;
}

// ---------------------------------------------------------------------------
// bf16 MFMA GEMM (m97 structure): C[m][n] = sum_k A[m][k]*W[n][k]
// A: MxK bf16 row-major.  W: NPADxK bf16 row-major (NPAD % 128 == 0).
// C: fp32, leading dim Nreal, col-guarded at Nreal.
// 128x128 tile, BK=32, 256 threads = 4 waves (2x2), 4x4 16x16x32 frags/wave.
// Staging: global_load_lds width=16, linear LDS.
// ---------------------------------------------------------------------------
__global__ __launch_bounds__(256) void gemm_bf16_kernel(
    const short* __restrict__ A, const short* __restrict__ W,
    float* __restrict__ C, int K, int Nreal)
{
    __shared__ short As[128][32];
    __shared__ short Bs[128][32];
    const int m0 = blockIdx.y * 128;
    const int n0 = blockIdx.x * 128;
    const int tid  = threadIdx.x;
    const int lane = tid & 63;
    const int wid  = tid >> 6;
    const int wm = wid >> 1, wn = wid & 1;
    const int lr = lane & 15;        // row/col within fragment
    const int kg = lane >> 4;        // k-group (0..3) -> k offset kg*8

    f32x4 acc[4][4];
    #pragma unroll
    for (int i = 0; i < 4; ++i)
        #pragma unroll
        for (int j = 0; j < 4; ++j)
            acc[i][j] = (f32x4){0.f, 0.f, 0.f, 0.f};

    // staging source coords (per lane): 16 rows per wave-iter, 4x8 cols
    const int srow = (lane >> 2);        // 0..15
    const int scol = (lane & 3) * 8;     // 0,8,16,24

    for (int k0 = 0; k0 < K; k0 += 32) {
        #pragma unroll
        for (int it = 0; it < 2; ++it) {
            int r = wid * 32 + it * 16 + srow;
            const short* ga = A + (size_t)(m0 + r) * K + k0 + scol;
            const short* gw = W + (size_t)(n0 + r) * K + k0 + scol;
            __builtin_amdgcn_global_load_lds(
                (const __attribute__((address_space(1))) void*)ga,
                (__attribute__((address_space(3))) void*)&As[wid * 32 + it * 16][0],
                16, 0, 0);
            __builtin_amdgcn_global_load_lds(
                (const __attribute__((address_space(1))) void*)gw,
                (__attribute__((address_space(3))) void*)&Bs[wid * 32 + it * 16][0],
                16, 0, 0);
        }
        __syncthreads();

        bf16x8 af[4], bf[4];
        #pragma unroll
        for (int i = 0; i < 4; ++i)
            af[i] = *(const bf16x8*)&As[wm * 64 + i * 16 + lr][kg * 8];
        #pragma unroll
        for (int j = 0; j < 4; ++j)
            bf[j] = *(const bf16x8*)&Bs[wn * 64 + j * 16 + lr][kg * 8];
        #pragma unroll
        for (int i = 0; i < 4; ++i)
            #pragma unroll
            for (int j = 0; j < 4; ++j)
                acc[i][j] = __builtin_amdgcn_mfma_f32_16x16x32_bf16(af[i], bf[j], acc[i][j], 0, 0, 0);
        __syncthreads();
    }

    // epilogue: col = lane&15, row = (lane>>4)*4 + reg
    #pragma unroll
    for (int i = 0; i < 4; ++i) {
        int mrow = m0 + wm * 64 + i * 16 + kg * 4;
        #pragma unroll
        for (int j = 0; j < 4; ++j) {
            int ncol = n0 + wn * 64 + j * 16 + lr;
            if (ncol < Nreal) {
                #pragma unroll
                for (int r = 0; r < 4; ++r)
                    C[(size_t)(mrow + r) * Nreal + ncol] = acc[i][j][r];
            }
        }
    }
}

// ---------------------------------------------------------------------------
// Cast kernels (fp32 -> bf16), 4 elems/thread
// ---------------------------------------------------------------------------
__global__ __launch_bounds__(256) void cast_bf16_kernel(
    const float* __restrict__ in, short* __restrict__ out, int n4)
{
    int i = blockIdx.x * 256 + threadIdx.x;
    if (i >= n4) return;
    float4 v = *(const float4*)(in + (size_t)i * 4);
    short4 o = make_short4(f2b(v.x), f2b(v.y), f2b(v.z), f2b(v.w));
    *(short4*)(out + (size_t)i * 4) = o;
}

// cast in_proj_w [3352][768] -> padded [3456][768] bf16 (zero pad rows)
__global__ __launch_bounds__(256) void cast_pad_w1_kernel(
    const float* __restrict__ w, short* __restrict__ wb)
{
    int i = blockIdx.x * 256 + threadIdx.x;
    const int n4 = N1_PAD * D_MODEL / 4;
    if (i >= n4) return;
    size_t base = (size_t)i * 4;
    int row = (int)(base / D_MODEL);
    float4 v = make_float4(0.f, 0.f, 0.f, 0.f);
    if (row < D_IN_PROJ) v = *(const float4*)(w + base);
    short4 o = make_short4(f2b(v.x), f2b(v.y), f2b(v.z), f2b(v.w));
    *(short4*)(wb + base) = o;
}

// ---------------------------------------------------------------------------
// Depthwise causal conv (k=4) + bias + SiLU.
// ---------------------------------------------------------------------------
__global__ __launch_bounds__(256) void conv_silu_kernel(
    const float* __restrict__ zx, float* __restrict__ out,
    const float* __restrict__ cw, const float* __restrict__ cb)
{
    int c = blockIdx.x * 256 + threadIdx.x;
    int r = blockIdx.y;
    if (c >= CONV_DIM) return;
    int l = r & (SEQLEN - 1);
    const float4 w = *(const float4*)(cw + (size_t)c * 4);
    const float wj[4] = {w.x, w.y, w.z, w.w};
    const float* col = zx + D_INNER + c;
    float acc = cb[c];
    #pragma unroll
    for (int j = 0; j < 4; ++j) {
        int ll = l - 3 + j;
        if (ll >= 0) acc = fmaf(col[(size_t)(r - 3 + j) * D_IN_PROJ], wj[j], acc);
    }
    out[(size_t)r * CONV_DIM + c] = acc / (1.f + expf(-acc));
}

// ---------------------------------------------------------------------------
// dt_dis = softplus(dt + dt_bias),  dA = exp(dt_dis * (-exp(A_log)))
// ---------------------------------------------------------------------------
__global__ __launch_bounds__(256) void dt_kernel(
    const float* __restrict__ zx, const float* __restrict__ dt_bias,
    const float* __restrict__ A_log, float* __restrict__ dtb, float* __restrict__ dAb)
{
    int idx = blockIdx.x * 256 + threadIdx.x;
    if (idx >= NROWS * NHEADS) return;
    int r = idx / NHEADS, h = idx - r * NHEADS;
    float x = zx[(size_t)r * D_IN_PROJ + (D_INNER + CONV_DIM) + h] + dt_bias[h];
    float sp = (x > 20.f) ? x : log1pf(expf(x));
    float A  = -expf(A_log[h]);
    dtb[idx] = sp;
    dAb[idx] = expf(sp * A);
}

// ---------------------------------------------------------------------------
// Scan pass 1: per-chunk local scan (zero init), 128 steps.
// grid = 6144 blocks = (b,h,chunk,pc); 256 threads (pl=tid>>4, tn=tid&15).
// ---------------------------------------------------------------------------
__global__ __launch_bounds__(256) void scan_chunk_local(
    const float* __restrict__ co, const float* __restrict__ dtb,
    const float* __restrict__ dAb, const float* __restrict__ Dvec,
    float* __restrict__ ybuf, float* __restrict__ sstate, float* __restrict__ cumW)
{
    int t = blockIdx.x;
    int pc = t & 3;  t >>= 2;
    int c  = t & 15; t >>= 4;
    int h  = t % NHEADS;
    int b  = t / NHEADS;
    int tid = threadIdx.x;
    int pl = tid >> 4;
    int tn = tid & 15;
    int p  = pc * 16 + pl;
    int n0 = tn * 8;
    const int R0 = b * SEQLEN + c * CHUNK;

    float s[8];
    #pragma unroll
    for (int i = 0; i < 8; ++i) s[i] = 0.f;
    const float Dh = Dvec[h];

    const float* base = co + (size_t)R0 * CONV_DIM;
    const int xcol = h * HEADDIM + p;
    const int bcol = D_INNER + n0;
    const int ccol = D_INNER + D_STATE + n0;
    float* cwrow = cumW + ((size_t)(b * NHEADS + h)) * SEQLEN + c * CHUNK;

    float4 Bv0 = *(const float4*)(base + bcol);
    float4 Bv1 = *(const float4*)(base + bcol + 4);
    float4 Cv0 = *(const float4*)(base + ccol);
    float4 Cv1 = *(const float4*)(base + ccol + 4);
    float xv  = base[xcol];
    float dAv = dAb[(size_t)R0 * NHEADS + h];
    float dtv = dtb[(size_t)R0 * NHEADS + h];
    float prodA = 1.f;

    for (int l = 0; l < CHUNK; ++l) {
        float4 nB0 = make_float4(0,0,0,0), nB1 = nB0, nC0 = nB0, nC1 = nB0;
        float nx = 0.f, ndA = 0.f, ndt = 0.f;
        if (l + 1 < CHUNK) {
            const float* row = base + (size_t)(l + 1) * CONV_DIM;
            nB0 = *(const float4*)(row + bcol);
            nB1 = *(const float4*)(row + bcol + 4);
            nC0 = *(const float4*)(row + ccol);
            nC1 = *(const float4*)(row + ccol + 4);
            nx  = row[xcol];
            ndA = dAb[(size_t)(R0 + l + 1) * NHEADS + h];
            ndt = dtb[(size_t)(R0 + l + 1) * NHEADS + h];
        }
        const float tt = dtv * xv;
        float yp = 0.f;
        const float Barr[8] = {Bv0.x,Bv0.y,Bv0.z,Bv0.w,Bv1.x,Bv1.y,Bv1.z,Bv1.w};
        const float Carr[8] = {Cv0.x,Cv0.y,Cv0.z,Cv0.w,Cv1.x,Cv1.y,Cv1.z,Cv1.w};
        #pragma unroll
        for (int i = 0; i < 8; ++i) {
            s[i] = fmaf(s[i], dAv, Barr[i] * tt);
            yp   = fmaf(s[i], Carr[i], yp);
        }
        prodA *= dAv;
        if (pc == 0 && tid == 0) cwrow[l] = prodA;
        yp += __shfl_xor(yp, 1);
        yp += __shfl_xor(yp, 2);
        yp += __shfl_xor(yp, 4);
        yp += __shfl_xor(yp, 8);
        if (tn == 0)
            ybuf[(size_t)(R0 + l) * D_INNER + xcol] = yp + Dh * xv;
        Bv0 = nB0; Bv1 = nB1; Cv0 = nC0; Cv1 = nC1;
        xv = nx; dAv = ndA; dtv = ndt;
    }
    size_t sidx = (((size_t)(b * NHEADS + h)) * NCHUNK + c) * STATE_SZ + p * D_STATE + n0;
    *(float4*)(sstate + sidx)     = make_float4(s[0], s[1], s[2], s[3]);
    *(float4*)(sstate + sidx + 4) = make_float4(s[4], s[5], s[6], s[7]);
}

// ---------------------------------------------------------------------------
// Scan pass 2: prefix over chunk states per (b,h). In-place.
// ---------------------------------------------------------------------------
__global__ __launch_bounds__(256) void scan_chunk_prefix(
    const float* __restrict__ cumW, float* __restrict__ sstate)
{
    int bh = blockIdx.x;
    int tid = threadIdx.x;
    float* base = sstate + (size_t)bh * NCHUNK * STATE_SZ;
    const float* cw = cumW + (size_t)bh * SEQLEN;
    float4 run[8];
    #pragma unroll
    for (int k = 0; k < 8; ++k) run[k] = make_float4(0.f, 0.f, 0.f, 0.f);
    for (int c = 0; c < NCHUNK; ++c) {
        float Ac = cw[c * CHUNK + (CHUNK - 1)];
        float* slab = base + (size_t)c * STATE_SZ;
        #pragma unroll
        for (int k = 0; k < 8; ++k) {
            float* ptr = slab + tid * 4 + k * 1024;
            float4 loc = *(float4*)ptr;
            float4 r = run[k];
            *(float4*)ptr = r;
            run[k].x = fmaf(Ac, r.x, loc.x);
            run[k].y = fmaf(Ac, r.y, loc.y);
            run[k].z = fmaf(Ac, r.z, loc.z);
            run[k].w = fmaf(Ac, r.w, loc.w);
        }
    }
}

// ---------------------------------------------------------------------------
// Scan pass 3: y[l] += cumW[l] * (C_l . s_init). Fully parallel.
// ---------------------------------------------------------------------------
__global__ __launch_bounds__(256) void scan_inter(
    const float* __restrict__ co, const float* __restrict__ cumW,
    const float* __restrict__ sstate, float* __restrict__ ybuf)
{
    int t = blockIdx.x;
    int pc = t & 3;  t >>= 2;
    int c  = t & 15; t >>= 4;
    int h  = t % NHEADS;
    int b  = t / NHEADS;
    int tid = threadIdx.x;
    int pl = tid >> 4;
    int tn = tid & 15;
    int p  = pc * 16 + pl;
    int n0 = tn * 8;
    const int R0 = b * SEQLEN + c * CHUNK;
    const int xcol = h * HEADDIM + p;
    const int ccol = D_INNER + D_STATE + n0;

    size_t sidx = (((size_t)(b * NHEADS + h)) * NCHUNK + c) * STATE_SZ + p * D_STATE + n0;
    float4 s0 = *(const float4*)(sstate + sidx);
    float4 s1 = *(const float4*)(sstate + sidx + 4);
    const float sin_[8] = {s0.x, s0.y, s0.z, s0.w, s1.x, s1.y, s1.z, s1.w};
    const float* cwrow = cumW + ((size_t)(b * NHEADS + h)) * SEQLEN + c * CHUNK;
    const float* base = co + (size_t)R0 * CONV_DIM;

    for (int l = 0; l < CHUNK; ++l) {
        const float* row = base + (size_t)l * CONV_DIM + ccol;
        float4 C0 = *(const float4*)(row);
        float4 C1 = *(const float4*)(row + 4);
        float dot = sin_[0] * C0.x;
        dot = fmaf(sin_[1], C0.y, dot);
        dot = fmaf(sin_[2], C0.z, dot);
        dot = fmaf(sin_[3], C0.w, dot);
        dot = fmaf(sin_[4], C1.x, dot);
        dot = fmaf(sin_[5], C1.y, dot);
        dot = fmaf(sin_[6], C1.z, dot);
        dot = fmaf(sin_[7], C1.w, dot);
        dot += __shfl_xor(dot, 1);
        dot += __shfl_xor(dot, 2);
        dot += __shfl_xor(dot, 4);
        dot += __shfl_xor(dot, 8);
        if (tn == 0) {
            float w = cwrow[l];
            size_t idx = (size_t)(R0 + l) * D_INNER + xcol;
            ybuf[idx] += w * dot;
        }
    }
}

// ---------------------------------------------------------------------------
// yz = y * silu(z);  yn = yz * rsqrt(mean(yz^2)+eps) * norm_w  -> bf16
// ---------------------------------------------------------------------------
__global__ __launch_bounds__(256) void gate_norm_kernel(
    const float* __restrict__ zx, const float* __restrict__ ybuf,
    const float* __restrict__ norm_w, short* __restrict__ yn)
{
    int r = blockIdx.x;
    const float* zrow = zx + (size_t)r * D_IN_PROJ;
    const float* yrow = ybuf + (size_t)r * D_INNER;
    float vals[6];
    float ss = 0.f;
    #pragma unroll
    for (int i = 0; i < 6; ++i) {
        int c = threadIdx.x + i * 256;
        float z = zrow[c];
        float y = yrow[c];
        float v = y * (z / (1.f + expf(-z)));
        vals[i] = v;
        ss = fmaf(v, v, ss);
    }
    ss += __shfl_xor(ss, 1);
    ss += __shfl_xor(ss, 2);
    ss += __shfl_xor(ss, 4);
    ss += __shfl_xor(ss, 8);
    ss += __shfl_xor(ss, 16);
    ss += __shfl_xor(ss, 32);
    __shared__ float red[4];
    if ((threadIdx.x & 63) == 0) red[threadIdx.x >> 6] = ss;
    __syncthreads();
    float tot = red[0] + red[1] + red[2] + red[3];
    float scale = rsqrtf(tot / (float)D_INNER + EPS);
    #pragma unroll
    for (int i = 0; i < 6; ++i) {
        int c = threadIdx.x + i * 256;
        yn[(size_t)r * D_INNER + c] = f2b(vals[i] * scale * norm_w[c]);
    }
}

// ---------------------------------------------------------------------------
extern "C" void kernel_launch(void* const* d_in, const int* in_sizes, int n_in,
                              void* d_out, int out_size, void* d_ws, size_t ws_size,
                              hipStream_t stream) {
    const float* u          = (const float*)d_in[0];
    const float* in_proj_w  = (const float*)d_in[1];
    const float* conv_w     = (const float*)d_in[2];
    const float* conv_b     = (const float*)d_in[3];
    const float* dt_bias    = (const float*)d_in[4];
    const float* A_log      = (const float*)d_in[5];
    const float* Dvec       = (const float*)d_in[6];
    const float* norm_w     = (const float*)d_in[7];
    const float* out_proj_w = (const float*)d_in[8];
    float* out = (float*)d_out;

    // fp32 workspace carve-up (same footprint as round 1):
    float* zx     = (float*)d_ws;                        // 4096*3352
    float* co     = zx     + (size_t)NROWS * D_IN_PROJ;  // 4096*1792
    float* dtb    = co     + (size_t)NROWS * CONV_DIM;   // 4096*24
    float* dAb    = dtb    + (size_t)NROWS * NHEADS;     // 4096*24
    float* ybuf   = dAb    + (size_t)NROWS * NHEADS;     // 4096*1536
    float* sstate = ybuf   + (size_t)NROWS * D_INNER;    // 48*16*8192
    float* cumW   = sstate + (size_t)BATCH*NHEADS*NCHUNK*STATE_SZ;  // 48*2048

    // bf16 aliases (regions dead at time of use):
    short* ub  = (short*)ybuf;                               // 4096*768 bf16 (ybuf dead until scan)
    short* w1b = (short*)(ybuf + (size_t)NROWS * D_MODEL/2); // 3456*768 bf16
    short* ynb = (short*)co;                                 // 4096*1536 bf16 (co dead after scan)
    short* w2b = (short*)zx;                                 // 768*1536 bf16 (zx dead after gate_norm)

    // 0) casts for GEMM1
    cast_bf16_kernel<<<(NROWS*D_MODEL/4 + 255)/256, 256, 0, stream>>>(u, ub, NROWS*D_MODEL/4);
    cast_pad_w1_kernel<<<(N1_PAD*D_MODEL/4 + 255)/256, 256, 0, stream>>>(in_proj_w, w1b);
    // 1) in-proj GEMM (bf16 MFMA): zx = u @ in_proj_w.T  (M=4096, N=3352, K=768)
    gemm_bf16_kernel<<<dim3(N1_PAD/128, NROWS/128), 256, 0, stream>>>(ub, w1b, zx, D_MODEL, D_IN_PROJ);
    // 2) depthwise conv + SiLU
    conv_silu_kernel<<<dim3(CONV_DIM/256, NROWS), 256, 0, stream>>>(zx, co, conv_w, conv_b);
    // 3) dt_dis / dA
    dt_kernel<<<(NROWS*NHEADS + 255)/256, 256, 0, stream>>>(zx, dt_bias, A_log, dtb, dAb);
    // 4) selective scan — chunked, 3 passes
    scan_chunk_local<<<BATCH*NHEADS*NCHUNK*4, 256, 0, stream>>>(co, dtb, dAb, Dvec, ybuf, sstate, cumW);
    scan_chunk_prefix<<<BATCH*NHEADS, 256, 0, stream>>>(cumW, sstate);
    scan_inter<<<BATCH*NHEADS*NCHUNK*4, 256, 0, stream>>>(co, cumW, sstate, ybuf);
    // 5) gate + RMSNorm -> bf16
    gate_norm_kernel<<<NROWS, 256, 0, stream>>>(zx, ybuf, norm_w, ynb);
    // 6) cast out_proj_w (zx region now dead)
    cast_bf16_kernel<<<(D_MODEL*D_INNER/4 + 255)/256, 256, 0, stream>>>(out_proj_w, w2b, D_MODEL*D_INNER/4);
    // 7) out-proj GEMM (bf16 MFMA): out = yn @ out_proj_w.T  (M=4096, N=768, K=1536)
    gemm_bf16_kernel<<<dim3(D_MODEL/128, NROWS/128), 256, 0, stream>>>(ynb, w2b, out, D_INNER, D_MODEL);
}

// Round 5
// 292.604 us; speedup vs baseline: 4.9841x; 2.2423x over previous
//
#include <hip/hip_runtime.h>
#include <hip/hip_bf16.h>
#include <math.h>

// Problem constants
#define D_MODEL   768
#define D_INNER   1536
#define D_STATE   128
#define HEADDIM   64
#define NHEADS    24
#define D_CONV    4
#define CONV_DIM  1792            // D_INNER + 2*D_STATE
#define D_IN_PROJ 3352            // 2*D_INNER + 2*D_STATE + NHEADS
#define BATCH     2
#define SEQLEN    2048
#define NROWS     (BATCH*SEQLEN)  // 4096
#define EPS       1e-5f

#define NCHUNK    16
#define CHUNK     128             // SEQLEN / NCHUNK
#define STATE_SZ  (HEADDIM*D_STATE)   // 8192 per (b,h,chunk)

#define N1_PAD    3456            // 27*128, padded N for GEMM1
#define LDST      136             // padded LDS row stride (bf16 elems) for 128-col tiles
#define H72       72              // padded stride for 64-col half tiles

typedef __bf16 bf16x8 __attribute__((ext_vector_type(8)));
typedef float  f32x4  __attribute__((ext_vector_type(4)));

// RNE float -> bf16 bit pattern
__device__ __forceinline__ short f2b(float f) {
    unsigned u = __float_as_uint(f);
    unsigned r = (u + 0x7FFFu + ((u >> 16) & 1u)) >> 16;
    return (short)r;
}

// ---------------------------------------------------------------------------
// bf16 MFMA GEMM (m97 structure): C[m][n] = sum_k A[m][k]*W[n][k]
// ---------------------------------------------------------------------------
__global__ __launch_bounds__(256) void gemm_bf16_kernel(
    const short* __restrict__ A, const short* __restrict__ W,
    float* __restrict__ C, int K, int Nreal)
{
    __shared__ short As[128][32];
    __shared__ short Bs[128][32];
    const int m0 = blockIdx.y * 128;
    const int n0 = blockIdx.x * 128;
    const int tid  = threadIdx.x;
    const int lane = tid & 63;
    const int wid  = tid >> 6;
    const int wm = wid >> 1, wn = wid & 1;
    const int lr = lane & 15;
    const int kg = lane >> 4;

    f32x4 acc[4][4];
    #pragma unroll
    for (int i = 0; i < 4; ++i)
        #pragma unroll
        for (int j = 0; j < 4; ++j)
            acc[i][j] = (f32x4){0.f, 0.f, 0.f, 0.f};

    const int srow = (lane >> 2);
    const int scol = (lane & 3) * 8;

    for (int k0 = 0; k0 < K; k0 += 32) {
        #pragma unroll
        for (int it = 0; it < 2; ++it) {
            int r = wid * 32 + it * 16 + srow;
            const short* ga = A + (size_t)(m0 + r) * K + k0 + scol;
            const short* gw = W + (size_t)(n0 + r) * K + k0 + scol;
            __builtin_amdgcn_global_load_lds(
                (const __attribute__((address_space(1))) void*)ga,
                (__attribute__((address_space(3))) void*)&As[wid * 32 + it * 16][0],
                16, 0, 0);
            __builtin_amdgcn_global_load_lds(
                (const __attribute__((address_space(1))) void*)gw,
                (__attribute__((address_space(3))) void*)&Bs[wid * 32 + it * 16][0],
                16, 0, 0);
        }
        __syncthreads();

        bf16x8 af[4], bf[4];
        #pragma unroll
        for (int i = 0; i < 4; ++i)
            af[i] = *(const bf16x8*)&As[wm * 64 + i * 16 + lr][kg * 8];
        #pragma unroll
        for (int j = 0; j < 4; ++j)
            bf[j] = *(const bf16x8*)&Bs[wn * 64 + j * 16 + lr][kg * 8];
        #pragma unroll
        for (int i = 0; i < 4; ++i)
            #pragma unroll
            for (int j = 0; j < 4; ++j)
                acc[i][j] = __builtin_amdgcn_mfma_f32_16x16x32_bf16(af[i], bf[j], acc[i][j], 0, 0, 0);
        __syncthreads();
    }

    #pragma unroll
    for (int i = 0; i < 4; ++i) {
        int mrow = m0 + wm * 64 + i * 16 + kg * 4;
        #pragma unroll
        for (int j = 0; j < 4; ++j) {
            int ncol = n0 + wn * 64 + j * 16 + lr;
            if (ncol < Nreal) {
                #pragma unroll
                for (int r = 0; r < 4; ++r)
                    C[(size_t)(mrow + r) * Nreal + ncol] = acc[i][j][r];
            }
        }
    }
}

// ---------------------------------------------------------------------------
// Cast kernels (fp32 -> bf16)
// ---------------------------------------------------------------------------
__global__ __launch_bounds__(256) void cast_bf16_kernel(
    const float* __restrict__ in, short* __restrict__ out, int n4)
{
    int i = blockIdx.x * 256 + threadIdx.x;
    if (i >= n4) return;
    float4 v = *(const float4*)(in + (size_t)i * 4);
    short4 o = make_short4(f2b(v.x), f2b(v.y), f2b(v.z), f2b(v.w));
    *(short4*)(out + (size_t)i * 4) = o;
}

__global__ __launch_bounds__(256) void cast_pad_w1_kernel(
    const float* __restrict__ w, short* __restrict__ wb)
{
    int i = blockIdx.x * 256 + threadIdx.x;
    const int n4 = N1_PAD * D_MODEL / 4;
    if (i >= n4) return;
    size_t base = (size_t)i * 4;
    int row = (int)(base / D_MODEL);
    float4 v = make_float4(0.f, 0.f, 0.f, 0.f);
    if (row < D_IN_PROJ) v = *(const float4*)(w + base);
    short4 o = make_short4(f2b(v.x), f2b(v.y), f2b(v.z), f2b(v.w));
    *(short4*)(wb + base) = o;
}

// ---------------------------------------------------------------------------
// Depthwise causal conv (k=4) + bias + SiLU.
// ---------------------------------------------------------------------------
__global__ __launch_bounds__(256) void conv_silu_kernel(
    const float* __restrict__ zx, float* __restrict__ out,
    const float* __restrict__ cw, const float* __restrict__ cb)
{
    int c = blockIdx.x * 256 + threadIdx.x;
    int r = blockIdx.y;
    if (c >= CONV_DIM) return;
    int l = r & (SEQLEN - 1);
    const float4 w = *(const float4*)(cw + (size_t)c * 4);
    const float wj[4] = {w.x, w.y, w.z, w.w};
    const float* col = zx + D_INNER + c;
    float acc = cb[c];
    #pragma unroll
    for (int j = 0; j < 4; ++j) {
        int ll = l - 3 + j;
        if (ll >= 0) acc = fmaf(col[(size_t)(r - 3 + j) * D_IN_PROJ], wj[j], acc);
    }
    out[(size_t)r * CONV_DIM + c] = acc / (1.f + expf(-acc));
}

// ---------------------------------------------------------------------------
// dt_dis = softplus(dt + dt_bias), dta = dt_dis * A   (A = -exp(A_log))
// ---------------------------------------------------------------------------
__global__ __launch_bounds__(256) void dt_kernel(
    const float* __restrict__ zx, const float* __restrict__ dt_bias,
    const float* __restrict__ A_log, float* __restrict__ dtb, float* __restrict__ dta)
{
    int idx = blockIdx.x * 256 + threadIdx.x;
    if (idx >= NROWS * NHEADS) return;
    int r = idx / NHEADS, h = idx - r * NHEADS;
    float x = zx[(size_t)r * D_IN_PROJ + (D_INNER + CONV_DIM) + h] + dt_bias[h];
    float sp = (x > 20.f) ? x : log1pf(expf(x));
    float A  = -expf(A_log[h]);
    dtb[idx] = sp;
    dta[idx] = sp * A;
}

// ---------------------------------------------------------------------------
// SSD intra-chunk kernel (MFMA). One block per (b,h,chunk) = 768 blocks,
// 512 threads = 8 waves. Computes:
//   clog[l]   = inclusive cumsum of dt*A within chunk;  cumW[l] = exp(clog[l])
//   S[l,l']   = C_l . B_l'          (bf16 MFMA, K=128 in two 64-halves)
//   Ps[l,l']  = S * exp(clog[l]-clog[l']) * (l'<=l)   (bf16, LDS)
//   Y[l,p]    = sum_l' Ps[l,l'] * dt_l' x[l',p]  + D_h*x[l,p]   -> ybuf
//   state[p,n]= sum_l exp(clog[E]-clog[l]) dt_l x[l,p] B[l,n]   -> sstate
// LDS phased/aliased to stay under 64 KB static.
// ---------------------------------------------------------------------------
__global__ __launch_bounds__(512) void ssd_intra(
    const float* __restrict__ co, const float* __restrict__ dtb,
    const float* __restrict__ dta, const float* __restrict__ Dvec,
    float* __restrict__ ybuf, float* __restrict__ sstate, float* __restrict__ cumW)
{
    __shared__ short lds[26112];      // 52,224 B arena (phased aliasing)
    __shared__ float clg[128];
    __shared__ float dts[128];

    int t = blockIdx.x;
    int c = t & 15;
    int hb = t >> 4;
    int h = hb % NHEADS;
    int b = hb / NHEADS;
    const int R0 = b * SEQLEN + c * CHUNK;
    const int tid  = threadIdx.x;
    const int lane = tid & 63;
    const int wid  = tid >> 6;       // 0..7
    const int lr = lane & 15;
    const int kg = lane >> 4;
    const float* cobase = co + (size_t)R0 * CONV_DIM;

    // --- A) stage dtA/dt, Hillis-Steele inclusive prefix over 128 ---
    if (tid < 128) {
        clg[tid] = dta[(size_t)(R0 + tid) * NHEADS + h];
        dts[tid] = dtb[(size_t)(R0 + tid) * NHEADS + h];
    }
    __syncthreads();
    for (int off = 1; off < 128; off <<= 1) {
        float v = 0.f;
        if (tid < 128 && tid >= off) v = clg[tid - off];
        __syncthreads();
        if (tid < 128) clg[tid] += v;
        __syncthreads();
    }
    const float clgE = clg[127];
    if (tid < 128)
        cumW[((size_t)(b * NHEADS + h)) * SEQLEN + c * CHUNK + tid] = __expf(clg[tid]);

    // --- B) S = C . B^T via two 64-col halves ---
    short* CsH = lds;                 // [128][H72]
    short* BsH = lds + 128 * H72;     // [128][H72]
    const int wmS = wid >> 2, wnS = wid & 3;
    f32x4 accS[4][2];
    #pragma unroll
    for (int i = 0; i < 4; ++i)
        #pragma unroll
        for (int j = 0; j < 2; ++j)
            accS[i][j] = (f32x4){0.f, 0.f, 0.f, 0.f};

    for (int kh = 0; kh < 2; ++kh) {
        {
            int r = tid >> 2, q = tid & 3;
            const float* cr = cobase + (size_t)r * CONV_DIM + (D_INNER + D_STATE) + kh * 64 + q * 16;
            const float* br = cobase + (size_t)r * CONV_DIM + D_INNER + kh * 64 + q * 16;
            #pragma unroll
            for (int i = 0; i < 4; ++i) {
                float4 cv = *(const float4*)(cr + i * 4);
                float4 bv = *(const float4*)(br + i * 4);
                *(short4*)(CsH + r * H72 + q * 16 + i * 4) =
                    make_short4(f2b(cv.x), f2b(cv.y), f2b(cv.z), f2b(cv.w));
                *(short4*)(BsH + r * H72 + q * 16 + i * 4) =
                    make_short4(f2b(bv.x), f2b(bv.y), f2b(bv.z), f2b(bv.w));
            }
        }
        __syncthreads();
        #pragma unroll
        for (int kk = 0; kk < 2; ++kk) {
            bf16x8 af[4], bf[2];
            #pragma unroll
            for (int i = 0; i < 4; ++i)
                af[i] = *(const bf16x8*)(CsH + (wmS * 64 + i * 16 + lr) * H72 + kk * 32 + kg * 8);
            #pragma unroll
            for (int j = 0; j < 2; ++j)
                bf[j] = *(const bf16x8*)(BsH + (wnS * 32 + j * 16 + lr) * H72 + kk * 32 + kg * 8);
            #pragma unroll
            for (int i = 0; i < 4; ++i)
                #pragma unroll
                for (int j = 0; j < 2; ++j)
                    accS[i][j] = __builtin_amdgcn_mfma_f32_16x16x32_bf16(af[i], bf[j], accS[i][j], 0, 0, 0);
        }
        __syncthreads();
    }

    // --- C) mask+decay -> Ps (aliases arena base); stage Xt ---
    short* Ps = lds;                  // [128][LDST]
    short* Xt = lds + 128 * LDST;     // [64][LDST]
    #pragma unroll
    for (int i = 0; i < 4; ++i) {
        #pragma unroll
        for (int j = 0; j < 2; ++j) {
            #pragma unroll
            for (int r = 0; r < 4; ++r) {
                int l  = wmS * 64 + i * 16 + kg * 4 + r;
                int lp = wnS * 32 + j * 16 + lr;
                float w = (lp <= l) ? __expf(clg[l] - clg[lp]) : 0.f;
                Ps[l * LDST + lp] = f2b(accS[i][j][r] * w);
            }
        }
    }
    if (tid < 256) {
        int r = tid >> 1, q = tid & 1;
        const float* xr = cobase + (size_t)r * CONV_DIM + h * HEADDIM + q * 32;
        float dtv = dts[r];
        #pragma unroll
        for (int i = 0; i < 8; ++i) {
            float4 xv = *(const float4*)(xr + i * 4);
            int p = q * 32 + i * 4;
            Xt[(p + 0) * LDST + r] = f2b(xv.x * dtv);
            Xt[(p + 1) * LDST + r] = f2b(xv.y * dtv);
            Xt[(p + 2) * LDST + r] = f2b(xv.z * dtv);
            Xt[(p + 3) * LDST + r] = f2b(xv.w * dtv);
        }
    }
    __syncthreads();

    // --- D) Y = Ps . Xt^T  (M=128 l, N=64 p, K=128 l') + D*x epilogue ---
    {
        int wm = wid >> 1, wn = wid & 1;
        f32x4 acc[2][2];
        #pragma unroll
        for (int i = 0; i < 2; ++i)
            #pragma unroll
            for (int j = 0; j < 2; ++j)
                acc[i][j] = (f32x4){0.f, 0.f, 0.f, 0.f};
        #pragma unroll
        for (int kk = 0; kk < 4; ++kk) {
            bf16x8 af[2], bf[2];
            #pragma unroll
            for (int i = 0; i < 2; ++i)
                af[i] = *(const bf16x8*)(Ps + (wm * 32 + i * 16 + lr) * LDST + kk * 32 + kg * 8);
            #pragma unroll
            for (int j = 0; j < 2; ++j)
                bf[j] = *(const bf16x8*)(Xt + (wn * 32 + j * 16 + lr) * LDST + kk * 32 + kg * 8);
            #pragma unroll
            for (int i = 0; i < 2; ++i)
                #pragma unroll
                for (int j = 0; j < 2; ++j)
                    acc[i][j] = __builtin_amdgcn_mfma_f32_16x16x32_bf16(af[i], bf[j], acc[i][j], 0, 0, 0);
        }
        const float Dh = Dvec[h];
        #pragma unroll
        for (int i = 0; i < 2; ++i) {
            #pragma unroll
            for (int j = 0; j < 2; ++j) {
                #pragma unroll
                for (int r = 0; r < 4; ++r) {
                    int l = wm * 32 + i * 16 + kg * 4 + r;
                    int p = wn * 32 + j * 16 + lr;
                    float xval = cobase[(size_t)l * CONV_DIM + h * HEADDIM + p];
                    ybuf[(size_t)(R0 + l) * D_INNER + h * HEADDIM + p] = acc[i][j][r] + Dh * xval;
                }
            }
        }
    }
    __syncthreads();

    // --- E) stage Bt[n][l] = exp(clgE-clg[l]) * B[l][n] (aliases Ps region) ---
    short* Bt = lds;                  // [128][LDST]
    {
        int r = tid >> 2, q = tid & 3;
        const float* br = cobase + (size_t)r * CONV_DIM + D_INNER + q * 32;
        float wstr = __expf(clgE - clg[r]);
        #pragma unroll
        for (int i = 0; i < 8; ++i) {
            float4 bv = *(const float4*)(br + i * 4);
            int n = q * 32 + i * 4;
            Bt[(n + 0) * LDST + r] = f2b(bv.x * wstr);
            Bt[(n + 1) * LDST + r] = f2b(bv.y * wstr);
            Bt[(n + 2) * LDST + r] = f2b(bv.z * wstr);
            Bt[(n + 3) * LDST + r] = f2b(bv.w * wstr);
        }
    }
    __syncthreads();

    // --- F) state = Xt . Bt^T  (M=64 p, N=128 n, K=128 l) ---
    {
        int wm = wid >> 2, wn = wid & 3;
        f32x4 acc[2][2];
        #pragma unroll
        for (int i = 0; i < 2; ++i)
            #pragma unroll
            for (int j = 0; j < 2; ++j)
                acc[i][j] = (f32x4){0.f, 0.f, 0.f, 0.f};
        #pragma unroll
        for (int kk = 0; kk < 4; ++kk) {
            bf16x8 af[2], bf[2];
            #pragma unroll
            for (int i = 0; i < 2; ++i)
                af[i] = *(const bf16x8*)(Xt + (wm * 32 + i * 16 + lr) * LDST + kk * 32 + kg * 8);
            #pragma unroll
            for (int j = 0; j < 2; ++j)
                bf[j] = *(const bf16x8*)(Bt + (wn * 32 + j * 16 + lr) * LDST + kk * 32 + kg * 8);
            #pragma unroll
            for (int i = 0; i < 2; ++i)
                #pragma unroll
                for (int j = 0; j < 2; ++j)
                    acc[i][j] = __builtin_amdgcn_mfma_f32_16x16x32_bf16(af[i], bf[j], acc[i][j], 0, 0, 0);
        }
        float* sbase = sstate + (((size_t)(b * NHEADS + h)) * NCHUNK + c) * STATE_SZ;
        #pragma unroll
        for (int i = 0; i < 2; ++i) {
            #pragma unroll
            for (int j = 0; j < 2; ++j) {
                #pragma unroll
                for (int r = 0; r < 4; ++r) {
                    int p = wm * 32 + i * 16 + kg * 4 + r;
                    int n = wn * 32 + j * 16 + lr;
                    sbase[p * D_STATE + n] = acc[i][j][r];
                }
            }
        }
    }
}

// ---------------------------------------------------------------------------
// Scan pass 2: prefix over chunk states per (b,h). In-place. Unchanged.
// ---------------------------------------------------------------------------
__global__ __launch_bounds__(256) void scan_chunk_prefix(
    const float* __restrict__ cumW, float* __restrict__ sstate)
{
    int bh = blockIdx.x;
    int tid = threadIdx.x;
    float* base = sstate + (size_t)bh * NCHUNK * STATE_SZ;
    const float* cw = cumW + (size_t)bh * SEQLEN;
    float4 run[8];
    #pragma unroll
    for (int k = 0; k < 8; ++k) run[k] = make_float4(0.f, 0.f, 0.f, 0.f);
    for (int c = 0; c < NCHUNK; ++c) {
        float Ac = cw[c * CHUNK + (CHUNK - 1)];
        float* slab = base + (size_t)c * STATE_SZ;
        #pragma unroll
        for (int k = 0; k < 8; ++k) {
            float* ptr = slab + tid * 4 + k * 1024;
            float4 loc = *(float4*)ptr;
            float4 r = run[k];
            *(float4*)ptr = r;
            run[k].x = fmaf(Ac, r.x, loc.x);
            run[k].y = fmaf(Ac, r.y, loc.y);
            run[k].z = fmaf(Ac, r.z, loc.z);
            run[k].w = fmaf(Ac, r.w, loc.w);
        }
    }
}

// ---------------------------------------------------------------------------
// SSD inter-chunk kernel (MFMA): ybuf[l,p] += cumW[l] * sum_n C[l,n]*sinit[p,n]
// 768 blocks, 256 threads = 4 waves.
// ---------------------------------------------------------------------------
__global__ __launch_bounds__(256) void ssd_inter(
    const float* __restrict__ co, const float* __restrict__ cumW,
    const float* __restrict__ sstate, float* __restrict__ ybuf)
{
    __shared__ short lds[26112];      // Cs[128][LDST] + Sn[64][LDST]
    short* Cs = lds;
    short* Sn = lds + 128 * LDST;

    int t = blockIdx.x;
    int c = t & 15;
    int hb = t >> 4;
    int h = hb % NHEADS;
    int b = hb / NHEADS;
    const int R0 = b * SEQLEN + c * CHUNK;
    const int tid  = threadIdx.x;
    const int lane = tid & 63;
    const int wid  = tid >> 6;
    const int lr = lane & 15;
    const int kg = lane >> 4;
    const float* cobase = co + (size_t)R0 * CONV_DIM;

    // stage C (bf16)
    {
        int r = tid >> 1, q = tid & 1;
        const float* cr = cobase + (size_t)r * CONV_DIM + (D_INNER + D_STATE) + q * 64;
        #pragma unroll
        for (int i = 0; i < 16; ++i) {
            float4 cv = *(const float4*)(cr + i * 4);
            *(short4*)(Cs + r * LDST + q * 64 + i * 4) =
                make_short4(f2b(cv.x), f2b(cv.y), f2b(cv.z), f2b(cv.w));
        }
    }
    // stage sinit [p][n] (bf16)
    {
        int r = tid >> 2, q = tid & 3;   // r = p 0..63
        const float* sr = sstate + (((size_t)(b * NHEADS + h)) * NCHUNK + c) * STATE_SZ
                          + (size_t)r * D_STATE + q * 32;
        #pragma unroll
        for (int i = 0; i < 8; ++i) {
            float4 sv = *(const float4*)(sr + i * 4);
            *(short4*)(Sn + r * LDST + q * 32 + i * 4) =
                make_short4(f2b(sv.x), f2b(sv.y), f2b(sv.z), f2b(sv.w));
        }
    }
    __syncthreads();

    // GEMM: M=128 (l), N=64 (p), K=128 (n). Waves 2x2: wm l-64, wn p-32.
    int wm = wid >> 1, wn = wid & 1;
    f32x4 acc[4][2];
    #pragma unroll
    for (int i = 0; i < 4; ++i)
        #pragma unroll
        for (int j = 0; j < 2; ++j)
            acc[i][j] = (f32x4){0.f, 0.f, 0.f, 0.f};
    #pragma unroll
    for (int kk = 0; kk < 4; ++kk) {
        bf16x8 af[4], bf[2];
        #pragma unroll
        for (int i = 0; i < 4; ++i)
            af[i] = *(const bf16x8*)(Cs + (wm * 64 + i * 16 + lr) * LDST + kk * 32 + kg * 8);
        #pragma unroll
        for (int j = 0; j < 2; ++j)
            bf[j] = *(const bf16x8*)(Sn + (wn * 32 + j * 16 + lr) * LDST + kk * 32 + kg * 8);
        #pragma unroll
        for (int i = 0; i < 4; ++i)
            #pragma unroll
            for (int j = 0; j < 2; ++j)
                acc[i][j] = __builtin_amdgcn_mfma_f32_16x16x32_bf16(af[i], bf[j], acc[i][j], 0, 0, 0);
    }
    const float* cwrow = cumW + ((size_t)(b * NHEADS + h)) * SEQLEN + c * CHUNK;
    #pragma unroll
    for (int i = 0; i < 4; ++i) {
        #pragma unroll
        for (int j = 0; j < 2; ++j) {
            #pragma unroll
            for (int r = 0; r < 4; ++r) {
                int l = wm * 64 + i * 16 + kg * 4 + r;
                int p = wn * 32 + j * 16 + lr;
                float w = cwrow[l];
                size_t idx = (size_t)(R0 + l) * D_INNER + h * HEADDIM + p;
                ybuf[idx] += w * acc[i][j][r];
            }
        }
    }
}

// ---------------------------------------------------------------------------
// yz = y * silu(z);  yn = yz * rsqrt(mean(yz^2)+eps) * norm_w  -> bf16
// ---------------------------------------------------------------------------
__global__ __launch_bounds__(256) void gate_norm_kernel(
    const float* __restrict__ zx, const float* __restrict__ ybuf,
    const float* __restrict__ norm_w, short* __restrict__ yn)
{
    int r = blockIdx.x;
    const float* zrow = zx + (size_t)r * D_IN_PROJ;
    const float* yrow = ybuf + (size_t)r * D_INNER;
    float vals[6];
    float ss = 0.f;
    #pragma unroll
    for (int i = 0; i < 6; ++i) {
        int c = threadIdx.x + i * 256;
        float z = zrow[c];
        float y = yrow[c];
        float v = y * (z / (1.f + expf(-z)));
        vals[i] = v;
        ss = fmaf(v, v, ss);
    }
    ss += __shfl_xor(ss, 1);
    ss += __shfl_xor(ss, 2);
    ss += __shfl_xor(ss, 4);
    ss += __shfl_xor(ss, 8);
    ss += __shfl_xor(ss, 16);
    ss += __shfl_xor(ss, 32);
    __shared__ float red[4];
    if ((threadIdx.x & 63) == 0) red[threadIdx.x >> 6] = ss;
    __syncthreads();
    float tot = red[0] + red[1] + red[2] + red[3];
    float scale = rsqrtf(tot / (float)D_INNER + EPS);
    #pragma unroll
    for (int i = 0; i < 6; ++i) {
        int c = threadIdx.x + i * 256;
        yn[(size_t)r * D_INNER + c] = f2b(vals[i] * scale * norm_w[c]);
    }
}

// ---------------------------------------------------------------------------
extern "C" void kernel_launch(void* const* d_in, const int* in_sizes, int n_in,
                              void* d_out, int out_size, void* d_ws, size_t ws_size,
                              hipStream_t stream) {
    const float* u          = (const float*)d_in[0];
    const float* in_proj_w  = (const float*)d_in[1];
    const float* conv_w     = (const float*)d_in[2];
    const float* conv_b     = (const float*)d_in[3];
    const float* dt_bias    = (const float*)d_in[4];
    const float* A_log      = (const float*)d_in[5];
    const float* Dvec       = (const float*)d_in[6];
    const float* norm_w     = (const float*)d_in[7];
    const float* out_proj_w = (const float*)d_in[8];
    float* out = (float*)d_out;

    // fp32 workspace carve-up:
    float* zx     = (float*)d_ws;                        // 4096*3352
    float* co     = zx     + (size_t)NROWS * D_IN_PROJ;  // 4096*1792
    float* dtb    = co     + (size_t)NROWS * CONV_DIM;   // 4096*24
    float* dta    = dtb    + (size_t)NROWS * NHEADS;     // 4096*24
    float* ybuf   = dta    + (size_t)NROWS * NHEADS;     // 4096*1536
    float* sstate = ybuf   + (size_t)NROWS * D_INNER;    // 48*16*8192
    float* cumW   = sstate + (size_t)BATCH*NHEADS*NCHUNK*STATE_SZ;  // 48*2048

    // bf16 aliases (regions dead at time of use):
    short* ub  = (short*)ybuf;                               // 4096*768 bf16
    short* w1b = (short*)(ybuf + (size_t)NROWS * D_MODEL/2); // 3456*768 bf16
    short* ynb = (short*)co;                                 // 4096*1536 bf16
    short* w2b = (short*)zx;                                 // 768*1536 bf16

    // 0) casts for GEMM1
    cast_bf16_kernel<<<(NROWS*D_MODEL/4 + 255)/256, 256, 0, stream>>>(u, ub, NROWS*D_MODEL/4);
    cast_pad_w1_kernel<<<(N1_PAD*D_MODEL/4 + 255)/256, 256, 0, stream>>>(in_proj_w, w1b);
    // 1) in-proj GEMM (bf16 MFMA)
    gemm_bf16_kernel<<<dim3(N1_PAD/128, NROWS/128), 256, 0, stream>>>(ub, w1b, zx, D_MODEL, D_IN_PROJ);
    // 2) depthwise conv + SiLU
    conv_silu_kernel<<<dim3(CONV_DIM/256, NROWS), 256, 0, stream>>>(zx, co, conv_w, conv_b);
    // 3) dt_dis / dtA
    dt_kernel<<<(NROWS*NHEADS + 255)/256, 256, 0, stream>>>(zx, dt_bias, A_log, dtb, dta);
    // 4) SSD scan: intra (MFMA) -> prefix -> inter (MFMA)
    ssd_intra<<<BATCH*NHEADS*NCHUNK, 512, 0, stream>>>(co, dtb, dta, Dvec, ybuf, sstate, cumW);
    scan_chunk_prefix<<<BATCH*NHEADS, 256, 0, stream>>>(cumW, sstate);
    ssd_inter<<<BATCH*NHEADS*NCHUNK, 256, 0, stream>>>(co, cumW, sstate, ybuf);
    // 5) gate + RMSNorm -> bf16
    gate_norm_kernel<<<NROWS, 256, 0, stream>>>(zx, ybuf, norm_w, ynb);
    // 6) cast out_proj_w (zx region now dead)
    cast_bf16_kernel<<<(D_MODEL*D_INNER/4 + 255)/256, 256, 0, stream>>>(out_proj_w, w2b, D_MODEL*D_INNER/4);
    // 7) out-proj GEMM (bf16 MFMA)
    gemm_bf16_kernel<<<dim3(D_MODEL/128, NROWS/128), 256, 0, stream>>>(ynb, w2b, out, D_INNER, D_MODEL);
}

// Round 6
// 262.778 us; speedup vs baseline: 5.5498x; 1.1135x over previous
//
#include <hip/hip_runtime.h>
#include <hip/hip_bf16.h>
#include <math.h>

// Problem constants
#define D_MODEL   768
#define D_INNER   1536
#define D_STATE   128
#define HEADDIM   64
#define NHEADS    24
#define D_CONV    4
#define CONV_DIM  1792            // D_INNER + 2*D_STATE
#define D_IN_PROJ 3352            // 2*D_INNER + 2*D_STATE + NHEADS
#define BATCH     2
#define SEQLEN    2048
#define NROWS     (BATCH*SEQLEN)  // 4096
#define EPS       1e-5f

#define NCHUNK    16
#define CHUNK     128             // SEQLEN / NCHUNK
#define STATE_SZ  (HEADDIM*D_STATE)   // 8192 per (b,h,chunk)

#define N1_PAD    3456            // 27*128, padded N for GEMM1
#define LDST      136             // padded LDS row stride (bf16 elems) for 128-col tiles
#define H72       72              // padded stride for 64-col half tiles

typedef __bf16 bf16x8 __attribute__((ext_vector_type(8)));
typedef float  f32x4  __attribute__((ext_vector_type(4)));
typedef short  s16x8  __attribute__((ext_vector_type(8)));

// RNE float -> bf16 bit pattern
__device__ __forceinline__ short f2b(float f) {
    unsigned u = __float_as_uint(f);
    unsigned r = (u + 0x7FFFu + ((u >> 16) & 1u)) >> 16;
    return (short)r;
}
// bf16 bits -> float
__device__ __forceinline__ float b2f(short s) {
    return __uint_as_float(((unsigned)(unsigned short)s) << 16);
}

// ---------------------------------------------------------------------------
// bf16 MFMA GEMM (m97 structure): C[m][n] = sum_k A[m][k]*W[n][k]
// OT = short (bf16 out) or float.
// ---------------------------------------------------------------------------
template<typename OT>
__global__ __launch_bounds__(256) void gemm_bf16_kernel(
    const short* __restrict__ A, const short* __restrict__ W,
    OT* __restrict__ C, int K, int Nreal)
{
    __shared__ short As[128][32];
    __shared__ short Bs[128][32];
    const int m0 = blockIdx.y * 128;
    const int n0 = blockIdx.x * 128;
    const int tid  = threadIdx.x;
    const int lane = tid & 63;
    const int wid  = tid >> 6;
    const int wm = wid >> 1, wn = wid & 1;
    const int lr = lane & 15;
    const int kg = lane >> 4;

    f32x4 acc[4][4];
    #pragma unroll
    for (int i = 0; i < 4; ++i)
        #pragma unroll
        for (int j = 0; j < 4; ++j)
            acc[i][j] = (f32x4){0.f, 0.f, 0.f, 0.f};

    const int srow = (lane >> 2);
    const int scol = (lane & 3) * 8;

    for (int k0 = 0; k0 < K; k0 += 32) {
        #pragma unroll
        for (int it = 0; it < 2; ++it) {
            int r = wid * 32 + it * 16 + srow;
            const short* ga = A + (size_t)(m0 + r) * K + k0 + scol;
            const short* gw = W + (size_t)(n0 + r) * K + k0 + scol;
            __builtin_amdgcn_global_load_lds(
                (const __attribute__((address_space(1))) void*)ga,
                (__attribute__((address_space(3))) void*)&As[wid * 32 + it * 16][0],
                16, 0, 0);
            __builtin_amdgcn_global_load_lds(
                (const __attribute__((address_space(1))) void*)gw,
                (__attribute__((address_space(3))) void*)&Bs[wid * 32 + it * 16][0],
                16, 0, 0);
        }
        __syncthreads();

        bf16x8 af[4], bf[4];
        #pragma unroll
        for (int i = 0; i < 4; ++i)
            af[i] = *(const bf16x8*)&As[wm * 64 + i * 16 + lr][kg * 8];
        #pragma unroll
        for (int j = 0; j < 4; ++j)
            bf[j] = *(const bf16x8*)&Bs[wn * 64 + j * 16 + lr][kg * 8];
        #pragma unroll
        for (int i = 0; i < 4; ++i)
            #pragma unroll
            for (int j = 0; j < 4; ++j)
                acc[i][j] = __builtin_amdgcn_mfma_f32_16x16x32_bf16(af[i], bf[j], acc[i][j], 0, 0, 0);
        __syncthreads();
    }

    #pragma unroll
    for (int i = 0; i < 4; ++i) {
        int mrow = m0 + wm * 64 + i * 16 + kg * 4;
        #pragma unroll
        for (int j = 0; j < 4; ++j) {
            int ncol = n0 + wn * 64 + j * 16 + lr;
            if (ncol < Nreal) {
                #pragma unroll
                for (int r = 0; r < 4; ++r) {
                    if constexpr (sizeof(OT) == 2)
                        C[(size_t)(mrow + r) * Nreal + ncol] = f2b(acc[i][j][r]);
                    else
                        C[(size_t)(mrow + r) * Nreal + ncol] = acc[i][j][r];
                }
            }
        }
    }
}

// ---------------------------------------------------------------------------
// Cast kernels (fp32 -> bf16)
// ---------------------------------------------------------------------------
__global__ __launch_bounds__(256) void cast_bf16_kernel(
    const float* __restrict__ in, short* __restrict__ out, int n4)
{
    int i = blockIdx.x * 256 + threadIdx.x;
    if (i >= n4) return;
    float4 v = *(const float4*)(in + (size_t)i * 4);
    short4 o = make_short4(f2b(v.x), f2b(v.y), f2b(v.z), f2b(v.w));
    *(short4*)(out + (size_t)i * 4) = o;
}

__global__ __launch_bounds__(256) void cast_pad_w1_kernel(
    const float* __restrict__ w, short* __restrict__ wb)
{
    int i = blockIdx.x * 256 + threadIdx.x;
    const int n4 = N1_PAD * D_MODEL / 4;
    if (i >= n4) return;
    size_t base = (size_t)i * 4;
    int row = (int)(base / D_MODEL);
    float4 v = make_float4(0.f, 0.f, 0.f, 0.f);
    if (row < D_IN_PROJ) v = *(const float4*)(w + base);
    short4 o = make_short4(f2b(v.x), f2b(v.y), f2b(v.z), f2b(v.w));
    *(short4*)(wb + base) = o;
}

// ---------------------------------------------------------------------------
// Depthwise causal conv (k=4) + bias + SiLU. bf16 in (zxb) -> bf16 out (cob).
// 8 channels per thread, vectorized s16x8 loads/stores.
// ---------------------------------------------------------------------------
__global__ __launch_bounds__(256) void conv_silu_kernel(
    const short* __restrict__ zxb, short* __restrict__ cob,
    const float* __restrict__ cw, const float* __restrict__ cb)
{
    const int NG = CONV_DIM / 8;             // 224 channel-groups
    int idx = blockIdx.x * 256 + threadIdx.x;
    int g = idx % NG;
    int r = idx / NG;
    int c0 = g * 8;
    int l = r & (SEQLEN - 1);

    float4 w[8];
    #pragma unroll
    for (int e = 0; e < 8; ++e)
        w[e] = *(const float4*)(cw + (size_t)(c0 + e) * 4);

    float acc[8];
    #pragma unroll
    for (int e = 0; e < 8; ++e) acc[e] = cb[c0 + e];

    #pragma unroll
    for (int tap = 0; tap < 4; ++tap) {
        if (l - 3 + tap >= 0) {
            s16x8 v = *(const s16x8*)(zxb + (size_t)(r - 3 + tap) * D_IN_PROJ + D_INNER + c0);
            const float wt[4] = {0, 0, 0, 0};
            #pragma unroll
            for (int e = 0; e < 8; ++e) {
                float we = (tap == 0) ? w[e].x : (tap == 1) ? w[e].y : (tap == 2) ? w[e].z : w[e].w;
                acc[e] = fmaf(b2f(v[e]), we, acc[e]);
            }
            (void)wt;
        }
    }
    s16x8 o;
    #pragma unroll
    for (int e = 0; e < 8; ++e)
        o[e] = f2b(acc[e] / (1.f + expf(-acc[e])));
    *(s16x8*)(cob + (size_t)r * CONV_DIM + c0) = o;
}

// ---------------------------------------------------------------------------
// dt_dis = softplus(dt + dt_bias), dta = dt_dis * A   (A = -exp(A_log))
// ---------------------------------------------------------------------------
__global__ __launch_bounds__(256) void dt_kernel(
    const short* __restrict__ zxb, const float* __restrict__ dt_bias,
    const float* __restrict__ A_log, float* __restrict__ dtb, float* __restrict__ dta)
{
    int idx = blockIdx.x * 256 + threadIdx.x;
    if (idx >= NROWS * NHEADS) return;
    int r = idx / NHEADS, h = idx - r * NHEADS;
    float x = b2f(zxb[(size_t)r * D_IN_PROJ + (D_INNER + CONV_DIM) + h]) + dt_bias[h];
    float sp = (x > 20.f) ? x : log1pf(expf(x));
    float A  = -expf(A_log[h]);
    dtb[idx] = sp;
    dta[idx] = sp * A;
}

// ---------------------------------------------------------------------------
// SSD intra-chunk kernel (MFMA). One block per (b,h,chunk) = 768 blocks,
// 512 threads = 8 waves. co is bf16 now (direct LDS copies for B/C).
// ---------------------------------------------------------------------------
__global__ __launch_bounds__(512) void ssd_intra(
    const short* __restrict__ co, const float* __restrict__ dtb,
    const float* __restrict__ dta, const float* __restrict__ Dvec,
    float* __restrict__ ybuf, float* __restrict__ sstate, float* __restrict__ cumW)
{
    __shared__ short lds[26112];      // 52,224 B arena (phased aliasing)
    __shared__ float clg[128];
    __shared__ float dts[128];

    int t = blockIdx.x;
    int c = t & 15;
    int hb = t >> 4;
    int h = hb % NHEADS;
    int b = hb / NHEADS;
    const int R0 = b * SEQLEN + c * CHUNK;
    const int tid  = threadIdx.x;
    const int lane = tid & 63;
    const int wid  = tid >> 6;       // 0..7
    const int lr = lane & 15;
    const int kg = lane >> 4;
    const short* cobase = co + (size_t)R0 * CONV_DIM;

    // --- A) stage dtA/dt, Hillis-Steele inclusive prefix over 128 ---
    if (tid < 128) {
        clg[tid] = dta[(size_t)(R0 + tid) * NHEADS + h];
        dts[tid] = dtb[(size_t)(R0 + tid) * NHEADS + h];
    }
    __syncthreads();
    for (int off = 1; off < 128; off <<= 1) {
        float v = 0.f;
        if (tid < 128 && tid >= off) v = clg[tid - off];
        __syncthreads();
        if (tid < 128) clg[tid] += v;
        __syncthreads();
    }
    const float clgE = clg[127];
    if (tid < 128)
        cumW[((size_t)(b * NHEADS + h)) * SEQLEN + c * CHUNK + tid] = __expf(clg[tid]);

    // --- B) S = C . B^T via two 64-col halves ---
    short* CsH = lds;                 // [128][H72]
    short* BsH = lds + 128 * H72;     // [128][H72]
    const int wmS = wid >> 2, wnS = wid & 3;
    f32x4 accS[4][2];
    #pragma unroll
    for (int i = 0; i < 4; ++i)
        #pragma unroll
        for (int j = 0; j < 2; ++j)
            accS[i][j] = (f32x4){0.f, 0.f, 0.f, 0.f};

    for (int kh = 0; kh < 2; ++kh) {
        {
            int r = tid >> 2, q = tid & 3;
            const short* cr = cobase + (size_t)r * CONV_DIM + (D_INNER + D_STATE) + kh * 64 + q * 16;
            const short* br = cobase + (size_t)r * CONV_DIM + D_INNER + kh * 64 + q * 16;
            *(s16x8*)(CsH + r * H72 + q * 16)     = *(const s16x8*)cr;
            *(s16x8*)(CsH + r * H72 + q * 16 + 8) = *(const s16x8*)(cr + 8);
            *(s16x8*)(BsH + r * H72 + q * 16)     = *(const s16x8*)br;
            *(s16x8*)(BsH + r * H72 + q * 16 + 8) = *(const s16x8*)(br + 8);
        }
        __syncthreads();
        #pragma unroll
        for (int kk = 0; kk < 2; ++kk) {
            bf16x8 af[4], bf[2];
            #pragma unroll
            for (int i = 0; i < 4; ++i)
                af[i] = *(const bf16x8*)(CsH + (wmS * 64 + i * 16 + lr) * H72 + kk * 32 + kg * 8);
            #pragma unroll
            for (int j = 0; j < 2; ++j)
                bf[j] = *(const bf16x8*)(BsH + (wnS * 32 + j * 16 + lr) * H72 + kk * 32 + kg * 8);
            #pragma unroll
            for (int i = 0; i < 4; ++i)
                #pragma unroll
                for (int j = 0; j < 2; ++j)
                    accS[i][j] = __builtin_amdgcn_mfma_f32_16x16x32_bf16(af[i], bf[j], accS[i][j], 0, 0, 0);
        }
        __syncthreads();
    }

    // --- C) mask+decay -> Ps (aliases arena base); stage Xt ---
    short* Ps = lds;                  // [128][LDST]
    short* Xt = lds + 128 * LDST;     // [64][LDST]
    #pragma unroll
    for (int i = 0; i < 4; ++i) {
        #pragma unroll
        for (int j = 0; j < 2; ++j) {
            #pragma unroll
            for (int r = 0; r < 4; ++r) {
                int l  = wmS * 64 + i * 16 + kg * 4 + r;
                int lp = wnS * 32 + j * 16 + lr;
                float w = (lp <= l) ? __expf(clg[l] - clg[lp]) : 0.f;
                Ps[l * LDST + lp] = f2b(accS[i][j][r] * w);
            }
        }
    }
    if (tid < 256) {
        int r = tid >> 1, q = tid & 1;
        const short* xr = cobase + (size_t)r * CONV_DIM + h * HEADDIM + q * 32;
        float dtv = dts[r];
        #pragma unroll
        for (int i = 0; i < 4; ++i) {
            s16x8 xv = *(const s16x8*)(xr + i * 8);
            #pragma unroll
            for (int e = 0; e < 8; ++e) {
                int p = q * 32 + i * 8 + e;
                Xt[p * LDST + r] = f2b(b2f(xv[e]) * dtv);
            }
        }
    }
    __syncthreads();

    // --- D) Y = Ps . Xt^T  (M=128 l, N=64 p, K=128 l') + D*x epilogue ---
    {
        int wm = wid >> 1, wn = wid & 1;
        f32x4 acc[2][2];
        #pragma unroll
        for (int i = 0; i < 2; ++i)
            #pragma unroll
            for (int j = 0; j < 2; ++j)
                acc[i][j] = (f32x4){0.f, 0.f, 0.f, 0.f};
        #pragma unroll
        for (int kk = 0; kk < 4; ++kk) {
            bf16x8 af[2], bf[2];
            #pragma unroll
            for (int i = 0; i < 2; ++i)
                af[i] = *(const bf16x8*)(Ps + (wm * 32 + i * 16 + lr) * LDST + kk * 32 + kg * 8);
            #pragma unroll
            for (int j = 0; j < 2; ++j)
                bf[j] = *(const bf16x8*)(Xt + (wn * 32 + j * 16 + lr) * LDST + kk * 32 + kg * 8);
            #pragma unroll
            for (int i = 0; i < 2; ++i)
                #pragma unroll
                for (int j = 0; j < 2; ++j)
                    acc[i][j] = __builtin_amdgcn_mfma_f32_16x16x32_bf16(af[i], bf[j], acc[i][j], 0, 0, 0);
        }
        const float Dh = Dvec[h];
        #pragma unroll
        for (int i = 0; i < 2; ++i) {
            #pragma unroll
            for (int j = 0; j < 2; ++j) {
                #pragma unroll
                for (int r = 0; r < 4; ++r) {
                    int l = wm * 32 + i * 16 + kg * 4 + r;
                    int p = wn * 32 + j * 16 + lr;
                    float xval = b2f(cobase[(size_t)l * CONV_DIM + h * HEADDIM + p]);
                    ybuf[(size_t)(R0 + l) * D_INNER + h * HEADDIM + p] = acc[i][j][r] + Dh * xval;
                }
            }
        }
    }
    __syncthreads();

    // --- E) stage Bt[n][l] = exp(clgE-clg[l]) * B[l][n] (aliases Ps region) ---
    short* Bt = lds;                  // [128][LDST]
    {
        int r = tid >> 2, q = tid & 3;
        const short* br = cobase + (size_t)r * CONV_DIM + D_INNER + q * 32;
        float wstr = __expf(clgE - clg[r]);
        #pragma unroll
        for (int i = 0; i < 4; ++i) {
            s16x8 bv = *(const s16x8*)(br + i * 8);
            #pragma unroll
            for (int e = 0; e < 8; ++e) {
                int n = q * 32 + i * 8 + e;
                Bt[n * LDST + r] = f2b(b2f(bv[e]) * wstr);
            }
        }
    }
    __syncthreads();

    // --- F) state = Xt . Bt^T  (M=64 p, N=128 n, K=128 l) ---
    {
        int wm = wid >> 2, wn = wid & 3;
        f32x4 acc[2][2];
        #pragma unroll
        for (int i = 0; i < 2; ++i)
            #pragma unroll
            for (int j = 0; j < 2; ++j)
                acc[i][j] = (f32x4){0.f, 0.f, 0.f, 0.f};
        #pragma unroll
        for (int kk = 0; kk < 4; ++kk) {
            bf16x8 af[2], bf[2];
            #pragma unroll
            for (int i = 0; i < 2; ++i)
                af[i] = *(const bf16x8*)(Xt + (wm * 32 + i * 16 + lr) * LDST + kk * 32 + kg * 8);
            #pragma unroll
            for (int j = 0; j < 2; ++j)
                bf[j] = *(const bf16x8*)(Bt + (wn * 32 + j * 16 + lr) * LDST + kk * 32 + kg * 8);
            #pragma unroll
            for (int i = 0; i < 2; ++i)
                #pragma unroll
                for (int j = 0; j < 2; ++j)
                    acc[i][j] = __builtin_amdgcn_mfma_f32_16x16x32_bf16(af[i], bf[j], acc[i][j], 0, 0, 0);
        }
        float* sbase = sstate + (((size_t)(b * NHEADS + h)) * NCHUNK + c) * STATE_SZ;
        #pragma unroll
        for (int i = 0; i < 2; ++i) {
            #pragma unroll
            for (int j = 0; j < 2; ++j) {
                #pragma unroll
                for (int r = 0; r < 4; ++r) {
                    int p = wm * 32 + i * 16 + kg * 4 + r;
                    int n = wn * 32 + j * 16 + lr;
                    sbase[p * D_STATE + n] = acc[i][j][r];
                }
            }
        }
    }
}

// ---------------------------------------------------------------------------
// Scan pass 2: prefix over chunk states per (b,h). In-place, parallelized
// over state elements: 768 blocks = (bh:48, piece:16), 128 thr x float4.
// ---------------------------------------------------------------------------
__global__ __launch_bounds__(128) void scan_chunk_prefix(
    const float* __restrict__ cumW, float* __restrict__ sstate)
{
    int blk = blockIdx.x;
    int piece = blk & 15;
    int bh = blk >> 4;
    int tid = threadIdx.x;
    float* base = sstate + (size_t)bh * NCHUNK * STATE_SZ + piece * 512 + tid * 4;
    const float* cw = cumW + (size_t)bh * SEQLEN;
    float4 run = make_float4(0.f, 0.f, 0.f, 0.f);
    for (int c = 0; c < NCHUNK; ++c) {
        float Ac = cw[c * CHUNK + (CHUNK - 1)];
        float* ptr = base + (size_t)c * STATE_SZ;
        float4 loc = *(float4*)ptr;
        *(float4*)ptr = run;
        run.x = fmaf(Ac, run.x, loc.x);
        run.y = fmaf(Ac, run.y, loc.y);
        run.z = fmaf(Ac, run.z, loc.z);
        run.w = fmaf(Ac, run.w, loc.w);
    }
}

// ---------------------------------------------------------------------------
// SSD inter-chunk kernel (MFMA): ybuf[l,p] += cumW[l] * sum_n C[l,n]*sinit[p,n]
// 768 blocks, 256 threads = 4 waves.
// ---------------------------------------------------------------------------
__global__ __launch_bounds__(256) void ssd_inter(
    const short* __restrict__ co, const float* __restrict__ cumW,
    const float* __restrict__ sstate, float* __restrict__ ybuf)
{
    __shared__ short lds[26112];      // Cs[128][LDST] + Sn[64][LDST]
    short* Cs = lds;
    short* Sn = lds + 128 * LDST;

    int t = blockIdx.x;
    int c = t & 15;
    int hb = t >> 4;
    int h = hb % NHEADS;
    int b = hb / NHEADS;
    const int R0 = b * SEQLEN + c * CHUNK;
    const int tid  = threadIdx.x;
    const int lane = tid & 63;
    const int wid  = tid >> 6;
    const int lr = lane & 15;
    const int kg = lane >> 4;
    const short* cobase = co + (size_t)R0 * CONV_DIM;

    // stage C (bf16, direct copy)
    {
        int r = tid >> 1, q = tid & 1;
        const short* cr = cobase + (size_t)r * CONV_DIM + (D_INNER + D_STATE) + q * 64;
        #pragma unroll
        for (int i = 0; i < 8; ++i)
            *(s16x8*)(Cs + r * LDST + q * 64 + i * 8) = *(const s16x8*)(cr + i * 8);
    }
    // stage sinit [p][n] (fp32 -> bf16)
    {
        int r = tid >> 2, q = tid & 3;   // r = p 0..63
        const float* sr = sstate + (((size_t)(b * NHEADS + h)) * NCHUNK + c) * STATE_SZ
                          + (size_t)r * D_STATE + q * 32;
        #pragma unroll
        for (int i = 0; i < 8; ++i) {
            float4 sv = *(const float4*)(sr + i * 4);
            *(short4*)(Sn + r * LDST + q * 32 + i * 4) =
                make_short4(f2b(sv.x), f2b(sv.y), f2b(sv.z), f2b(sv.w));
        }
    }
    __syncthreads();

    // GEMM: M=128 (l), N=64 (p), K=128 (n). Waves 2x2: wm l-64, wn p-32.
    int wm = wid >> 1, wn = wid & 1;
    f32x4 acc[4][2];
    #pragma unroll
    for (int i = 0; i < 4; ++i)
        #pragma unroll
        for (int j = 0; j < 2; ++j)
            acc[i][j] = (f32x4){0.f, 0.f, 0.f, 0.f};
    #pragma unroll
    for (int kk = 0; kk < 4; ++kk) {
        bf16x8 af[4], bf[2];
        #pragma unroll
        for (int i = 0; i < 4; ++i)
            af[i] = *(const bf16x8*)(Cs + (wm * 64 + i * 16 + lr) * LDST + kk * 32 + kg * 8);
        #pragma unroll
        for (int j = 0; j < 2; ++j)
            bf[j] = *(const bf16x8*)(Sn + (wn * 32 + j * 16 + lr) * LDST + kk * 32 + kg * 8);
        #pragma unroll
        for (int i = 0; i < 4; ++i)
            #pragma unroll
            for (int j = 0; j < 2; ++j)
                acc[i][j] = __builtin_amdgcn_mfma_f32_16x16x32_bf16(af[i], bf[j], acc[i][j], 0, 0, 0);
    }
    const float* cwrow = cumW + ((size_t)(b * NHEADS + h)) * SEQLEN + c * CHUNK;
    #pragma unroll
    for (int i = 0; i < 4; ++i) {
        #pragma unroll
        for (int j = 0; j < 2; ++j) {
            #pragma unroll
            for (int r = 0; r < 4; ++r) {
                int l = wm * 64 + i * 16 + kg * 4 + r;
                int p = wn * 32 + j * 16 + lr;
                float w = cwrow[l];
                size_t idx = (size_t)(R0 + l) * D_INNER + h * HEADDIM + p;
                ybuf[idx] += w * acc[i][j][r];
            }
        }
    }
}

// ---------------------------------------------------------------------------
// yz = y * silu(z);  yn = yz * rsqrt(mean(yz^2)+eps) * norm_w  -> bf16
// z from zxb (bf16).
// ---------------------------------------------------------------------------
__global__ __launch_bounds__(256) void gate_norm_kernel(
    const short* __restrict__ zxb, const float* __restrict__ ybuf,
    const float* __restrict__ norm_w, short* __restrict__ yn)
{
    int r = blockIdx.x;
    const short* zrow = zxb + (size_t)r * D_IN_PROJ;
    const float* yrow = ybuf + (size_t)r * D_INNER;
    float vals[6];
    float ss = 0.f;
    #pragma unroll
    for (int i = 0; i < 6; ++i) {
        int c = threadIdx.x + i * 256;
        float z = b2f(zrow[c]);
        float y = yrow[c];
        float v = y * (z / (1.f + expf(-z)));
        vals[i] = v;
        ss = fmaf(v, v, ss);
    }
    ss += __shfl_xor(ss, 1);
    ss += __shfl_xor(ss, 2);
    ss += __shfl_xor(ss, 4);
    ss += __shfl_xor(ss, 8);
    ss += __shfl_xor(ss, 16);
    ss += __shfl_xor(ss, 32);
    __shared__ float red[4];
    if ((threadIdx.x & 63) == 0) red[threadIdx.x >> 6] = ss;
    __syncthreads();
    float tot = red[0] + red[1] + red[2] + red[3];
    float scale = rsqrtf(tot / (float)D_INNER + EPS);
    #pragma unroll
    for (int i = 0; i < 6; ++i) {
        int c = threadIdx.x + i * 256;
        yn[(size_t)r * D_INNER + c] = f2b(vals[i] * scale * norm_w[c]);
    }
}

// ---------------------------------------------------------------------------
extern "C" void kernel_launch(void* const* d_in, const int* in_sizes, int n_in,
                              void* d_out, int out_size, void* d_ws, size_t ws_size,
                              hipStream_t stream) {
    const float* u          = (const float*)d_in[0];
    const float* in_proj_w  = (const float*)d_in[1];
    const float* conv_w     = (const float*)d_in[2];
    const float* conv_b     = (const float*)d_in[3];
    const float* dt_bias    = (const float*)d_in[4];
    const float* A_log      = (const float*)d_in[5];
    const float* Dvec       = (const float*)d_in[6];
    const float* norm_w     = (const float*)d_in[7];
    const float* out_proj_w = (const float*)d_in[8];
    float* out = (float*)d_out;

    // workspace carve-up:
    short* zxb    = (short*)d_ws;                            // 4096*3352 bf16
    short* cob    = zxb + (size_t)NROWS * D_IN_PROJ;         // 4096*1792 bf16
    float* dtb    = (float*)(cob + (size_t)NROWS * CONV_DIM);
    float* dta    = dtb  + (size_t)NROWS * NHEADS;
    float* ybuf   = dta  + (size_t)NROWS * NHEADS;           // 4096*1536 fp32
    float* sstate = ybuf + (size_t)NROWS * D_INNER;          // 48*16*8192 fp32
    float* cumW   = sstate + (size_t)BATCH*NHEADS*NCHUNK*STATE_SZ;

    // bf16 aliases (regions dead at time of use):
    short* ub  = (short*)ybuf;                 // 4096*768  (ybuf dead until ssd_intra)
    short* w1b = ub + (size_t)NROWS * D_MODEL; // 3456*768
    short* ynb = (short*)sstate;               // 4096*1536 (sstate dead after ssd_inter)
    short* w2b = zxb;                          // 768*1536  (zxb dead after gate_norm)

    // 0) casts for GEMM1
    cast_bf16_kernel<<<(NROWS*D_MODEL/4 + 255)/256, 256, 0, stream>>>(u, ub, NROWS*D_MODEL/4);
    cast_pad_w1_kernel<<<(N1_PAD*D_MODEL/4 + 255)/256, 256, 0, stream>>>(in_proj_w, w1b);
    // 1) in-proj GEMM (bf16 MFMA) -> zxb (bf16)
    gemm_bf16_kernel<short><<<dim3(N1_PAD/128, NROWS/128), 256, 0, stream>>>(ub, w1b, zxb, D_MODEL, D_IN_PROJ);
    // 2) depthwise conv + SiLU (bf16 -> bf16)
    conv_silu_kernel<<<NROWS*(CONV_DIM/8)/256, 256, 0, stream>>>(zxb, cob, conv_w, conv_b);
    // 3) dt_dis / dtA
    dt_kernel<<<(NROWS*NHEADS + 255)/256, 256, 0, stream>>>(zxb, dt_bias, A_log, dtb, dta);
    // 4) SSD scan: intra (MFMA) -> prefix (parallel) -> inter (MFMA)
    ssd_intra<<<BATCH*NHEADS*NCHUNK, 512, 0, stream>>>(cob, dtb, dta, Dvec, ybuf, sstate, cumW);
    scan_chunk_prefix<<<BATCH*NHEADS*16, 128, 0, stream>>>(cumW, sstate);
    ssd_inter<<<BATCH*NHEADS*NCHUNK, 256, 0, stream>>>(cob, cumW, sstate, ybuf);
    // 5) gate + RMSNorm -> bf16 (reads zxb z cols, then zxb is dead)
    gate_norm_kernel<<<NROWS, 256, 0, stream>>>(zxb, ybuf, norm_w, ynb);
    // 6) cast out_proj_w into zxb region
    cast_bf16_kernel<<<(D_MODEL*D_INNER/4 + 255)/256, 256, 0, stream>>>(out_proj_w, w2b, D_MODEL*D_INNER/4);
    // 7) out-proj GEMM (bf16 MFMA) -> fp32 out
    gemm_bf16_kernel<float><<<dim3(D_MODEL/128, NROWS/128), 256, 0, stream>>>(ynb, w2b, out, D_INNER, D_MODEL);
}

// Round 7
// 243.329 us; speedup vs baseline: 5.9934x; 1.0799x over previous
//
#include <hip/hip_runtime.h>
#include <hip/hip_bf16.h>
#include <math.h>

// Problem constants
#define D_MODEL   768
#define D_INNER   1536
#define D_STATE   128
#define HEADDIM   64
#define NHEADS    24
#define D_CONV    4
#define CONV_DIM  1792            // D_INNER + 2*D_STATE
#define D_IN_PROJ 3352            // 2*D_INNER + 2*D_STATE + NHEADS
#define BATCH     2
#define SEQLEN    2048
#define NROWS     (BATCH*SEQLEN)  // 4096
#define EPS       1e-5f

#define NCHUNK    16
#define CHUNK     128             // SEQLEN / NCHUNK
#define STATE_SZ  (HEADDIM*D_STATE)   // 8192 per (b,h,chunk)

#define N1_PAD    3456            // 27*128, padded N for GEMM1
#define LDST      136             // padded LDS row stride (bf16 elems) for 128-col tiles
#define H72       72              // padded stride for 64-col half tiles

typedef __bf16 bf16x8 __attribute__((ext_vector_type(8)));
typedef float  f32x4  __attribute__((ext_vector_type(4)));
typedef short  s16x8  __attribute__((ext_vector_type(8)));

// RNE float -> bf16 bit pattern
__device__ __forceinline__ short f2b(float f) {
    unsigned u = __float_as_uint(f);
    unsigned r = (u + 0x7FFFu + ((u >> 16) & 1u)) >> 16;
    return (short)r;
}
// bf16 bits -> float
__device__ __forceinline__ float b2f(short s) {
    return __uint_as_float(((unsigned)(unsigned short)s) << 16);
}

// ---------------------------------------------------------------------------
// bf16 MFMA GEMM, 2-phase double-buffered (T3-min): C[m][n] = sum_k A[m][k]*W[n][k]
// STAGE(t+1) issued BEFORE COMPUTE(t); one barrier per K-step (prefetch
// latency hides under MFMA; the barrier's vmcnt(0) is then cheap).
// bf16 output path repacks C-tile through LDS for coalesced 16B stores.
// ---------------------------------------------------------------------------
template<typename OT>
__global__ __launch_bounds__(256) void gemm_bf16_kernel(
    const short* __restrict__ A, const short* __restrict__ W,
    OT* __restrict__ C, int K, int Nreal)
{
    __shared__ short smem[2][2][128][32];   // [buf][A=0/B=1][row][col] = 32 KB
    const int m0 = blockIdx.y * 128;
    const int n0 = blockIdx.x * 128;
    const int tid  = threadIdx.x;
    const int lane = tid & 63;
    const int wid  = tid >> 6;
    const int wm = wid >> 1, wn = wid & 1;
    const int lr = lane & 15;
    const int kg = lane >> 4;

    f32x4 acc[4][4];
    #pragma unroll
    for (int i = 0; i < 4; ++i)
        #pragma unroll
        for (int j = 0; j < 4; ++j)
            acc[i][j] = (f32x4){0.f, 0.f, 0.f, 0.f};

    const int srow = (lane >> 2);        // 0..15
    const int scol = (lane & 3) * 8;     // 0,8,16,24

    auto STAGE = [&](int buf, int k0) {
        #pragma unroll
        for (int it = 0; it < 2; ++it) {
            int r = wid * 32 + it * 16;
            const short* ga = A + (size_t)(m0 + r + srow) * K + k0 + scol;
            const short* gw = W + (size_t)(n0 + r + srow) * K + k0 + scol;
            __builtin_amdgcn_global_load_lds(
                (const __attribute__((address_space(1))) void*)ga,
                (__attribute__((address_space(3))) void*)&smem[buf][0][r][0], 16, 0, 0);
            __builtin_amdgcn_global_load_lds(
                (const __attribute__((address_space(1))) void*)gw,
                (__attribute__((address_space(3))) void*)&smem[buf][1][r][0], 16, 0, 0);
        }
    };
    auto COMPUTE = [&](int buf) {
        bf16x8 af[4], bf[4];
        #pragma unroll
        for (int i = 0; i < 4; ++i)
            af[i] = *(const bf16x8*)&smem[buf][0][wm * 64 + i * 16 + lr][kg * 8];
        #pragma unroll
        for (int j = 0; j < 4; ++j)
            bf[j] = *(const bf16x8*)&smem[buf][1][wn * 64 + j * 16 + lr][kg * 8];
        #pragma unroll
        for (int i = 0; i < 4; ++i)
            #pragma unroll
            for (int j = 0; j < 4; ++j)
                acc[i][j] = __builtin_amdgcn_mfma_f32_16x16x32_bf16(af[i], bf[j], acc[i][j], 0, 0, 0);
    };

    const int nt = K >> 5;
    STAGE(0, 0);
    __syncthreads();
    int cur = 0;
    for (int t = 0; t < nt - 1; ++t) {
        STAGE(cur ^ 1, (t + 1) << 5);   // prefetch next tile (in flight during MFMA)
        COMPUTE(cur);
        __syncthreads();                // vmcnt(0)+barrier: next tile landed, cur free
        cur ^= 1;
    }
    COMPUTE(cur);

    if constexpr (sizeof(OT) == 2) {
        // repack through LDS (arena is free now) for coalesced 16B bf16 stores
        __syncthreads();
        short* eb = &smem[0][0][0][0];   // 128 x 128 bf16 = 32 KB
        #pragma unroll
        for (int i = 0; i < 4; ++i) {
            #pragma unroll
            for (int j = 0; j < 4; ++j) {
                #pragma unroll
                for (int r = 0; r < 4; ++r) {
                    int row = wm * 64 + i * 16 + kg * 4 + r;
                    int col = wn * 64 + j * 16 + lr;
                    eb[row * 128 + col] = f2b(acc[i][j][r]);
                }
            }
        }
        __syncthreads();
        #pragma unroll
        for (int ch = 0; ch < 8; ++ch) {
            int cidx = ch * 256 + tid;       // 2048 16B-chunks
            int row  = cidx >> 4;
            int cp   = cidx & 15;
            int ncol = n0 + cp * 8;
            if (ncol < Nreal)
                *(s16x8*)((short*)C + (size_t)(m0 + row) * Nreal + ncol) =
                    *(const s16x8*)(eb + row * 128 + cp * 8);
        }
    } else {
        #pragma unroll
        for (int i = 0; i < 4; ++i) {
            int mrow = m0 + wm * 64 + i * 16 + kg * 4;
            #pragma unroll
            for (int j = 0; j < 4; ++j) {
                int ncol = n0 + wn * 64 + j * 16 + lr;
                if (ncol < Nreal) {
                    #pragma unroll
                    for (int r = 0; r < 4; ++r)
                        C[(size_t)(mrow + r) * Nreal + ncol] = acc[i][j][r];
                }
            }
        }
    }
}

// ---------------------------------------------------------------------------
// Cast kernels (fp32 -> bf16)
// ---------------------------------------------------------------------------
__global__ __launch_bounds__(256) void cast_bf16_kernel(
    const float* __restrict__ in, short* __restrict__ out, int n4)
{
    int i = blockIdx.x * 256 + threadIdx.x;
    if (i >= n4) return;
    float4 v = *(const float4*)(in + (size_t)i * 4);
    short4 o = make_short4(f2b(v.x), f2b(v.y), f2b(v.z), f2b(v.w));
    *(short4*)(out + (size_t)i * 4) = o;
}

__global__ __launch_bounds__(256) void cast_pad_w1_kernel(
    const float* __restrict__ w, short* __restrict__ wb)
{
    int i = blockIdx.x * 256 + threadIdx.x;
    const int n4 = N1_PAD * D_MODEL / 4;
    if (i >= n4) return;
    size_t base = (size_t)i * 4;
    int row = (int)(base / D_MODEL);
    float4 v = make_float4(0.f, 0.f, 0.f, 0.f);
    if (row < D_IN_PROJ) v = *(const float4*)(w + base);
    short4 o = make_short4(f2b(v.x), f2b(v.y), f2b(v.z), f2b(v.w));
    *(short4*)(wb + base) = o;
}

// ---------------------------------------------------------------------------
// Depthwise causal conv (k=4) + bias + SiLU. bf16 in (zxb) -> bf16 out (cob).
// ---------------------------------------------------------------------------
__global__ __launch_bounds__(256) void conv_silu_kernel(
    const short* __restrict__ zxb, short* __restrict__ cob,
    const float* __restrict__ cw, const float* __restrict__ cb)
{
    const int NG = CONV_DIM / 8;             // 224 channel-groups
    int idx = blockIdx.x * 256 + threadIdx.x;
    int g = idx % NG;
    int r = idx / NG;
    int c0 = g * 8;
    int l = r & (SEQLEN - 1);

    float4 w[8];
    #pragma unroll
    for (int e = 0; e < 8; ++e)
        w[e] = *(const float4*)(cw + (size_t)(c0 + e) * 4);

    float acc[8];
    #pragma unroll
    for (int e = 0; e < 8; ++e) acc[e] = cb[c0 + e];

    #pragma unroll
    for (int tap = 0; tap < 4; ++tap) {
        if (l - 3 + tap >= 0) {
            s16x8 v = *(const s16x8*)(zxb + (size_t)(r - 3 + tap) * D_IN_PROJ + D_INNER + c0);
            #pragma unroll
            for (int e = 0; e < 8; ++e) {
                float we = (tap == 0) ? w[e].x : (tap == 1) ? w[e].y : (tap == 2) ? w[e].z : w[e].w;
                acc[e] = fmaf(b2f(v[e]), we, acc[e]);
            }
        }
    }
    s16x8 o;
    #pragma unroll
    for (int e = 0; e < 8; ++e)
        o[e] = f2b(acc[e] / (1.f + expf(-acc[e])));
    *(s16x8*)(cob + (size_t)r * CONV_DIM + c0) = o;
}

// ---------------------------------------------------------------------------
// dt_dis = softplus(dt + dt_bias), dta = dt_dis * A   (A = -exp(A_log))
// ---------------------------------------------------------------------------
__global__ __launch_bounds__(256) void dt_kernel(
    const short* __restrict__ zxb, const float* __restrict__ dt_bias,
    const float* __restrict__ A_log, float* __restrict__ dtb, float* __restrict__ dta)
{
    int idx = blockIdx.x * 256 + threadIdx.x;
    if (idx >= NROWS * NHEADS) return;
    int r = idx / NHEADS, h = idx - r * NHEADS;
    float x = b2f(zxb[(size_t)r * D_IN_PROJ + (D_INNER + CONV_DIM) + h]) + dt_bias[h];
    float sp = (x > 20.f) ? x : log1pf(expf(x));
    float A  = -expf(A_log[h]);
    dtb[idx] = sp;
    dta[idx] = sp * A;
}

// ---------------------------------------------------------------------------
// SSD intra-chunk kernel (MFMA). One block per (b,h,chunk) = 768 blocks,
// 512 threads = 8 waves.
// ---------------------------------------------------------------------------
__global__ __launch_bounds__(512) void ssd_intra(
    const short* __restrict__ co, const float* __restrict__ dtb,
    const float* __restrict__ dta, const float* __restrict__ Dvec,
    float* __restrict__ ybuf, float* __restrict__ sstate, float* __restrict__ cumW)
{
    __shared__ short lds[26112];      // 52,224 B arena (phased aliasing)
    __shared__ float clg[128];
    __shared__ float dts[128];

    int t = blockIdx.x;
    int c = t & 15;
    int hb = t >> 4;
    int h = hb % NHEADS;
    int b = hb / NHEADS;
    const int R0 = b * SEQLEN + c * CHUNK;
    const int tid  = threadIdx.x;
    const int lane = tid & 63;
    const int wid  = tid >> 6;       // 0..7
    const int lr = lane & 15;
    const int kg = lane >> 4;
    const short* cobase = co + (size_t)R0 * CONV_DIM;

    // --- A) stage dtA/dt, Hillis-Steele inclusive prefix over 128 ---
    if (tid < 128) {
        clg[tid] = dta[(size_t)(R0 + tid) * NHEADS + h];
        dts[tid] = dtb[(size_t)(R0 + tid) * NHEADS + h];
    }
    __syncthreads();
    for (int off = 1; off < 128; off <<= 1) {
        float v = 0.f;
        if (tid < 128 && tid >= off) v = clg[tid - off];
        __syncthreads();
        if (tid < 128) clg[tid] += v;
        __syncthreads();
    }
    const float clgE = clg[127];
    if (tid < 128)
        cumW[((size_t)(b * NHEADS + h)) * SEQLEN + c * CHUNK + tid] = __expf(clg[tid]);

    // --- B) S = C . B^T via two 64-col halves ---
    short* CsH = lds;                 // [128][H72]
    short* BsH = lds + 128 * H72;     // [128][H72]
    const int wmS = wid >> 2, wnS = wid & 3;
    f32x4 accS[4][2];
    #pragma unroll
    for (int i = 0; i < 4; ++i)
        #pragma unroll
        for (int j = 0; j < 2; ++j)
            accS[i][j] = (f32x4){0.f, 0.f, 0.f, 0.f};

    for (int kh = 0; kh < 2; ++kh) {
        {
            int r = tid >> 2, q = tid & 3;
            const short* cr = cobase + (size_t)r * CONV_DIM + (D_INNER + D_STATE) + kh * 64 + q * 16;
            const short* br = cobase + (size_t)r * CONV_DIM + D_INNER + kh * 64 + q * 16;
            *(s16x8*)(CsH + r * H72 + q * 16)     = *(const s16x8*)cr;
            *(s16x8*)(CsH + r * H72 + q * 16 + 8) = *(const s16x8*)(cr + 8);
            *(s16x8*)(BsH + r * H72 + q * 16)     = *(const s16x8*)br;
            *(s16x8*)(BsH + r * H72 + q * 16 + 8) = *(const s16x8*)(br + 8);
        }
        __syncthreads();
        #pragma unroll
        for (int kk = 0; kk < 2; ++kk) {
            bf16x8 af[4], bf[2];
            #pragma unroll
            for (int i = 0; i < 4; ++i)
                af[i] = *(const bf16x8*)(CsH + (wmS * 64 + i * 16 + lr) * H72 + kk * 32 + kg * 8);
            #pragma unroll
            for (int j = 0; j < 2; ++j)
                bf[j] = *(const bf16x8*)(BsH + (wnS * 32 + j * 16 + lr) * H72 + kk * 32 + kg * 8);
            #pragma unroll
            for (int i = 0; i < 4; ++i)
                #pragma unroll
                for (int j = 0; j < 2; ++j)
                    accS[i][j] = __builtin_amdgcn_mfma_f32_16x16x32_bf16(af[i], bf[j], accS[i][j], 0, 0, 0);
        }
        __syncthreads();
    }

    // --- C) mask+decay -> Ps (aliases arena base); stage Xt ---
    short* Ps = lds;                  // [128][LDST]
    short* Xt = lds + 128 * LDST;     // [64][LDST]
    #pragma unroll
    for (int i = 0; i < 4; ++i) {
        #pragma unroll
        for (int j = 0; j < 2; ++j) {
            #pragma unroll
            for (int r = 0; r < 4; ++r) {
                int l  = wmS * 64 + i * 16 + kg * 4 + r;
                int lp = wnS * 32 + j * 16 + lr;
                float w = (lp <= l) ? __expf(clg[l] - clg[lp]) : 0.f;
                Ps[l * LDST + lp] = f2b(accS[i][j][r] * w);
            }
        }
    }
    if (tid < 256) {
        int r = tid >> 1, q = tid & 1;
        const short* xr = cobase + (size_t)r * CONV_DIM + h * HEADDIM + q * 32;
        float dtv = dts[r];
        #pragma unroll
        for (int i = 0; i < 4; ++i) {
            s16x8 xv = *(const s16x8*)(xr + i * 8);
            #pragma unroll
            for (int e = 0; e < 8; ++e) {
                int p = q * 32 + i * 8 + e;
                Xt[p * LDST + r] = f2b(b2f(xv[e]) * dtv);
            }
        }
    }
    __syncthreads();

    // --- D) Y = Ps . Xt^T  (M=128 l, N=64 p, K=128 l') + D*x epilogue ---
    {
        int wm = wid >> 1, wn = wid & 1;
        f32x4 acc[2][2];
        #pragma unroll
        for (int i = 0; i < 2; ++i)
            #pragma unroll
            for (int j = 0; j < 2; ++j)
                acc[i][j] = (f32x4){0.f, 0.f, 0.f, 0.f};
        #pragma unroll
        for (int kk = 0; kk < 4; ++kk) {
            bf16x8 af[2], bf[2];
            #pragma unroll
            for (int i = 0; i < 2; ++i)
                af[i] = *(const bf16x8*)(Ps + (wm * 32 + i * 16 + lr) * LDST + kk * 32 + kg * 8);
            #pragma unroll
            for (int j = 0; j < 2; ++j)
                bf[j] = *(const bf16x8*)(Xt + (wn * 32 + j * 16 + lr) * LDST + kk * 32 + kg * 8);
            #pragma unroll
            for (int i = 0; i < 2; ++i)
                #pragma unroll
                for (int j = 0; j < 2; ++j)
                    acc[i][j] = __builtin_amdgcn_mfma_f32_16x16x32_bf16(af[i], bf[j], acc[i][j], 0, 0, 0);
        }
        const float Dh = Dvec[h];
        #pragma unroll
        for (int i = 0; i < 2; ++i) {
            #pragma unroll
            for (int j = 0; j < 2; ++j) {
                #pragma unroll
                for (int r = 0; r < 4; ++r) {
                    int l = wm * 32 + i * 16 + kg * 4 + r;
                    int p = wn * 32 + j * 16 + lr;
                    float xval = b2f(cobase[(size_t)l * CONV_DIM + h * HEADDIM + p]);
                    ybuf[(size_t)(R0 + l) * D_INNER + h * HEADDIM + p] = acc[i][j][r] + Dh * xval;
                }
            }
        }
    }
    __syncthreads();

    // --- E) stage Bt[n][l] = exp(clgE-clg[l]) * B[l][n] (aliases Ps region) ---
    short* Bt = lds;                  // [128][LDST]
    {
        int r = tid >> 2, q = tid & 3;
        const short* br = cobase + (size_t)r * CONV_DIM + D_INNER + q * 32;
        float wstr = __expf(clgE - clg[r]);
        #pragma unroll
        for (int i = 0; i < 4; ++i) {
            s16x8 bv = *(const s16x8*)(br + i * 8);
            #pragma unroll
            for (int e = 0; e < 8; ++e) {
                int n = q * 32 + i * 8 + e;
                Bt[n * LDST + r] = f2b(b2f(bv[e]) * wstr);
            }
        }
    }
    __syncthreads();

    // --- F) state = Xt . Bt^T  (M=64 p, N=128 n, K=128 l) ---
    {
        int wm = wid >> 2, wn = wid & 3;
        f32x4 acc[2][2];
        #pragma unroll
        for (int i = 0; i < 2; ++i)
            #pragma unroll
            for (int j = 0; j < 2; ++j)
                acc[i][j] = (f32x4){0.f, 0.f, 0.f, 0.f};
        #pragma unroll
        for (int kk = 0; kk < 4; ++kk) {
            bf16x8 af[2], bf[2];
            #pragma unroll
            for (int i = 0; i < 2; ++i)
                af[i] = *(const bf16x8*)(Xt + (wm * 32 + i * 16 + lr) * LDST + kk * 32 + kg * 8);
            #pragma unroll
            for (int j = 0; j < 2; ++j)
                bf[j] = *(const bf16x8*)(Bt + (wn * 32 + j * 16 + lr) * LDST + kk * 32 + kg * 8);
            #pragma unroll
            for (int i = 0; i < 2; ++i)
                #pragma unroll
                for (int j = 0; j < 2; ++j)
                    acc[i][j] = __builtin_amdgcn_mfma_f32_16x16x32_bf16(af[i], bf[j], acc[i][j], 0, 0, 0);
        }
        float* sbase = sstate + (((size_t)(b * NHEADS + h)) * NCHUNK + c) * STATE_SZ;
        #pragma unroll
        for (int i = 0; i < 2; ++i) {
            #pragma unroll
            for (int j = 0; j < 2; ++j) {
                #pragma unroll
                for (int r = 0; r < 4; ++r) {
                    int p = wm * 32 + i * 16 + kg * 4 + r;
                    int n = wn * 32 + j * 16 + lr;
                    sbase[p * D_STATE + n] = acc[i][j][r];
                }
            }
        }
    }
}

// ---------------------------------------------------------------------------
// Scan pass 2: prefix over chunk states per (b,h). In-place, parallelized
// over state elements: 768 blocks = (bh:48, piece:16), 128 thr x float4.
// ---------------------------------------------------------------------------
__global__ __launch_bounds__(128) void scan_chunk_prefix(
    const float* __restrict__ cumW, float* __restrict__ sstate)
{
    int blk = blockIdx.x;
    int piece = blk & 15;
    int bh = blk >> 4;
    int tid = threadIdx.x;
    float* base = sstate + (size_t)bh * NCHUNK * STATE_SZ + piece * 512 + tid * 4;
    const float* cw = cumW + (size_t)bh * SEQLEN;
    float4 run = make_float4(0.f, 0.f, 0.f, 0.f);
    for (int c = 0; c < NCHUNK; ++c) {
        float Ac = cw[c * CHUNK + (CHUNK - 1)];
        float* ptr = base + (size_t)c * STATE_SZ;
        float4 loc = *(float4*)ptr;
        *(float4*)ptr = run;
        run.x = fmaf(Ac, run.x, loc.x);
        run.y = fmaf(Ac, run.y, loc.y);
        run.z = fmaf(Ac, run.z, loc.z);
        run.w = fmaf(Ac, run.w, loc.w);
    }
}

// ---------------------------------------------------------------------------
// SSD inter-chunk kernel (MFMA): ybuf[l,p] += cumW[l] * sum_n C[l,n]*sinit[p,n]
// 768 blocks, 256 threads = 4 waves.
// ---------------------------------------------------------------------------
__global__ __launch_bounds__(256) void ssd_inter(
    const short* __restrict__ co, const float* __restrict__ cumW,
    const float* __restrict__ sstate, float* __restrict__ ybuf)
{
    __shared__ short lds[26112];      // Cs[128][LDST] + Sn[64][LDST]
    short* Cs = lds;
    short* Sn = lds + 128 * LDST;

    int t = blockIdx.x;
    int c = t & 15;
    int hb = t >> 4;
    int h = hb % NHEADS;
    int b = hb / NHEADS;
    const int R0 = b * SEQLEN + c * CHUNK;
    const int tid  = threadIdx.x;
    const int lane = tid & 63;
    const int wid  = tid >> 6;
    const int lr = lane & 15;
    const int kg = lane >> 4;
    const short* cobase = co + (size_t)R0 * CONV_DIM;

    // stage C (bf16, direct copy)
    {
        int r = tid >> 1, q = tid & 1;
        const short* cr = cobase + (size_t)r * CONV_DIM + (D_INNER + D_STATE) + q * 64;
        #pragma unroll
        for (int i = 0; i < 8; ++i)
            *(s16x8*)(Cs + r * LDST + q * 64 + i * 8) = *(const s16x8*)(cr + i * 8);
    }
    // stage sinit [p][n] (fp32 -> bf16)
    {
        int r = tid >> 2, q = tid & 3;   // r = p 0..63
        const float* sr = sstate + (((size_t)(b * NHEADS + h)) * NCHUNK + c) * STATE_SZ
                          + (size_t)r * D_STATE + q * 32;
        #pragma unroll
        for (int i = 0; i < 8; ++i) {
            float4 sv = *(const float4*)(sr + i * 4);
            *(short4*)(Sn + r * LDST + q * 32 + i * 4) =
                make_short4(f2b(sv.x), f2b(sv.y), f2b(sv.z), f2b(sv.w));
        }
    }
    __syncthreads();

    // GEMM: M=128 (l), N=64 (p), K=128 (n). Waves 2x2: wm l-64, wn p-32.
    int wm = wid >> 1, wn = wid & 1;
    f32x4 acc[4][2];
    #pragma unroll
    for (int i = 0; i < 4; ++i)
        #pragma unroll
        for (int j = 0; j < 2; ++j)
            acc[i][j] = (f32x4){0.f, 0.f, 0.f, 0.f};
    #pragma unroll
    for (int kk = 0; kk < 4; ++kk) {
        bf16x8 af[4], bf[2];
        #pragma unroll
        for (int i = 0; i < 4; ++i)
            af[i] = *(const bf16x8*)(Cs + (wm * 64 + i * 16 + lr) * LDST + kk * 32 + kg * 8);
        #pragma unroll
        for (int j = 0; j < 2; ++j)
            bf[j] = *(const bf16x8*)(Sn + (wn * 32 + j * 16 + lr) * LDST + kk * 32 + kg * 8);
        #pragma unroll
        for (int i = 0; i < 4; ++i)
            #pragma unroll
            for (int j = 0; j < 2; ++j)
                acc[i][j] = __builtin_amdgcn_mfma_f32_16x16x32_bf16(af[i], bf[j], acc[i][j], 0, 0, 0);
    }
    const float* cwrow = cumW + ((size_t)(b * NHEADS + h)) * SEQLEN + c * CHUNK;
    #pragma unroll
    for (int i = 0; i < 4; ++i) {
        #pragma unroll
        for (int j = 0; j < 2; ++j) {
            #pragma unroll
            for (int r = 0; r < 4; ++r) {
                int l = wm * 64 + i * 16 + kg * 4 + r;
                int p = wn * 32 + j * 16 + lr;
                float w = cwrow[l];
                size_t idx = (size_t)(R0 + l) * D_INNER + h * HEADDIM + p;
                ybuf[idx] += w * acc[i][j][r];
            }
        }
    }
}

// ---------------------------------------------------------------------------
// yz = y * silu(z);  yn = yz * rsqrt(mean(yz^2)+eps) * norm_w  -> bf16
// ---------------------------------------------------------------------------
__global__ __launch_bounds__(256) void gate_norm_kernel(
    const short* __restrict__ zxb, const float* __restrict__ ybuf,
    const float* __restrict__ norm_w, short* __restrict__ yn)
{
    int r = blockIdx.x;
    const short* zrow = zxb + (size_t)r * D_IN_PROJ;
    const float* yrow = ybuf + (size_t)r * D_INNER;
    float vals[6];
    float ss = 0.f;
    #pragma unroll
    for (int i = 0; i < 6; ++i) {
        int c = threadIdx.x + i * 256;
        float z = b2f(zrow[c]);
        float y = yrow[c];
        float v = y * (z / (1.f + expf(-z)));
        vals[i] = v;
        ss = fmaf(v, v, ss);
    }
    ss += __shfl_xor(ss, 1);
    ss += __shfl_xor(ss, 2);
    ss += __shfl_xor(ss, 4);
    ss += __shfl_xor(ss, 8);
    ss += __shfl_xor(ss, 16);
    ss += __shfl_xor(ss, 32);
    __shared__ float red[4];
    if ((threadIdx.x & 63) == 0) red[threadIdx.x >> 6] = ss;
    __syncthreads();
    float tot = red[0] + red[1] + red[2] + red[3];
    float scale = rsqrtf(tot / (float)D_INNER + EPS);
    #pragma unroll
    for (int i = 0; i < 6; ++i) {
        int c = threadIdx.x + i * 256;
        yn[(size_t)r * D_INNER + c] = f2b(vals[i] * scale * norm_w[c]);
    }
}

// ---------------------------------------------------------------------------
extern "C" void kernel_launch(void* const* d_in, const int* in_sizes, int n_in,
                              void* d_out, int out_size, void* d_ws, size_t ws_size,
                              hipStream_t stream) {
    const float* u          = (const float*)d_in[0];
    const float* in_proj_w  = (const float*)d_in[1];
    const float* conv_w     = (const float*)d_in[2];
    const float* conv_b     = (const float*)d_in[3];
    const float* dt_bias    = (const float*)d_in[4];
    const float* A_log      = (const float*)d_in[5];
    const float* Dvec       = (const float*)d_in[6];
    const float* norm_w     = (const float*)d_in[7];
    const float* out_proj_w = (const float*)d_in[8];
    float* out = (float*)d_out;

    // workspace carve-up:
    short* zxb    = (short*)d_ws;                            // 4096*3352 bf16
    short* cob    = zxb + (size_t)NROWS * D_IN_PROJ;         // 4096*1792 bf16
    float* dtb    = (float*)(cob + (size_t)NROWS * CONV_DIM);
    float* dta    = dtb  + (size_t)NROWS * NHEADS;
    float* ybuf   = dta  + (size_t)NROWS * NHEADS;           // 4096*1536 fp32
    float* sstate = ybuf + (size_t)NROWS * D_INNER;          // 48*16*8192 fp32
    float* cumW   = sstate + (size_t)BATCH*NHEADS*NCHUNK*STATE_SZ;

    // bf16 aliases (regions dead at time of use):
    short* ub  = (short*)ybuf;                 // 4096*768  (ybuf dead until ssd_intra)
    short* w1b = ub + (size_t)NROWS * D_MODEL; // 3456*768
    short* ynb = (short*)sstate;               // 4096*1536 (sstate dead after ssd_inter)
    short* w2b = zxb;                          // 768*1536  (zxb dead after gate_norm)

    // 0) casts for GEMM1
    cast_bf16_kernel<<<(NROWS*D_MODEL/4 + 255)/256, 256, 0, stream>>>(u, ub, NROWS*D_MODEL/4);
    cast_pad_w1_kernel<<<(N1_PAD*D_MODEL/4 + 255)/256, 256, 0, stream>>>(in_proj_w, w1b);
    // 1) in-proj GEMM (bf16 MFMA) -> zxb (bf16)
    gemm_bf16_kernel<short><<<dim3(N1_PAD/128, NROWS/128), 256, 0, stream>>>(ub, w1b, zxb, D_MODEL, D_IN_PROJ);
    // 2) depthwise conv + SiLU (bf16 -> bf16)
    conv_silu_kernel<<<NROWS*(CONV_DIM/8)/256, 256, 0, stream>>>(zxb, cob, conv_w, conv_b);
    // 3) dt_dis / dtA
    dt_kernel<<<(NROWS*NHEADS + 255)/256, 256, 0, stream>>>(zxb, dt_bias, A_log, dtb, dta);
    // 4) SSD scan: intra (MFMA) -> prefix (parallel) -> inter (MFMA)
    ssd_intra<<<BATCH*NHEADS*NCHUNK, 512, 0, stream>>>(cob, dtb, dta, Dvec, ybuf, sstate, cumW);
    scan_chunk_prefix<<<BATCH*NHEADS*16, 128, 0, stream>>>(cumW, sstate);
    ssd_inter<<<BATCH*NHEADS*NCHUNK, 256, 0, stream>>>(cob, cumW, sstate, ybuf);
    // 5) gate + RMSNorm -> bf16 (reads zxb z cols, then zxb is dead)
    gate_norm_kernel<<<NROWS, 256, 0, stream>>>(zxb, ybuf, norm_w, ynb);
    // 6) cast out_proj_w into zxb region
    cast_bf16_kernel<<<(D_MODEL*D_INNER/4 + 255)/256, 256, 0, stream>>>(out_proj_w, w2b, D_MODEL*D_INNER/4);
    // 7) out-proj GEMM (bf16 MFMA) -> fp32 out
    gemm_bf16_kernel<float><<<dim3(D_MODEL/128, NROWS/128), 256, 0, stream>>>(ynb, w2b, out, D_INNER, D_MODEL);
}

// Round 8
// 235.954 us; speedup vs baseline: 6.1807x; 1.0313x over previous
//
#include <hip/hip_runtime.h>
#include <hip/hip_bf16.h>
#include <math.h>

// Problem constants
#define D_MODEL   768
#define D_INNER   1536
#define D_STATE   128
#define HEADDIM   64
#define NHEADS    24
#define D_CONV    4
#define CONV_DIM  1792            // D_INNER + 2*D_STATE
#define D_IN_PROJ 3352            // 2*D_INNER + 2*D_STATE + NHEADS
#define BATCH     2
#define SEQLEN    2048
#define NROWS     (BATCH*SEQLEN)  // 4096
#define EPS       1e-5f

#define NCHUNK    16
#define CHUNK     128             // SEQLEN / NCHUNK
#define STATE_SZ  (HEADDIM*D_STATE)   // 8192 per (b,h,chunk)

#define N1_PAD    3456            // 27*128, padded N for GEMM1
#define LDST      136             // padded LDS row stride (bf16 elems), 272B (16B-mult)
#define H72       72              // padded stride for 64-col half tiles (144B)

typedef __bf16 bf16x8 __attribute__((ext_vector_type(8)));
typedef float  f32x4  __attribute__((ext_vector_type(4)));
typedef short  s16x8  __attribute__((ext_vector_type(8)));

// RNE float -> bf16 bit pattern
__device__ __forceinline__ short f2b(float f) {
    unsigned u = __float_as_uint(f);
    unsigned r = (u + 0x7FFFu + ((u >> 16) & 1u)) >> 16;
    return (short)r;
}
// bf16 bits -> float
__device__ __forceinline__ float b2f(short s) {
    return __uint_as_float(((unsigned)(unsigned short)s) << 16);
}

// ---------------------------------------------------------------------------
// GEMM1: bf16 MFMA, 128x128 tile, 2-phase dbuf, XCD-swizzled 1D grid,
// bf16 output via LDS repack (coalesced 16B stores).
// C[m][n] = sum_k A[m][k]*W[n][k]. Grid = MT*NT blocks (MT=M/128).
// ---------------------------------------------------------------------------
__global__ __launch_bounds__(256) void gemm_bf16_kernel(
    const short* __restrict__ A, const short* __restrict__ W,
    short* __restrict__ C, int K, int Nreal, int NT)
{
    __shared__ short smem[2][2][128][32];   // 32 KB dbuf
    // bijective XCD swizzle (gridDim.x % 8 == 0)
    int flat = blockIdx.x;
    int swz  = (flat & 7) * (gridDim.x >> 3) + (flat >> 3);
    const int m0 = (swz / NT) * 128;
    const int n0 = (swz % NT) * 128;
    const int tid  = threadIdx.x;
    const int lane = tid & 63;
    const int wid  = tid >> 6;
    const int wm = wid >> 1, wn = wid & 1;
    const int lr = lane & 15;
    const int kg = lane >> 4;

    f32x4 acc[4][4];
    #pragma unroll
    for (int i = 0; i < 4; ++i)
        #pragma unroll
        for (int j = 0; j < 4; ++j)
            acc[i][j] = (f32x4){0.f, 0.f, 0.f, 0.f};

    const int srow = (lane >> 2);
    const int scol = (lane & 3) * 8;

    auto STAGE = [&](int buf, int k0) {
        #pragma unroll
        for (int it = 0; it < 2; ++it) {
            int r = wid * 32 + it * 16;
            const short* ga = A + (size_t)(m0 + r + srow) * K + k0 + scol;
            const short* gw = W + (size_t)(n0 + r + srow) * K + k0 + scol;
            __builtin_amdgcn_global_load_lds(
                (const __attribute__((address_space(1))) void*)ga,
                (__attribute__((address_space(3))) void*)&smem[buf][0][r][0], 16, 0, 0);
            __builtin_amdgcn_global_load_lds(
                (const __attribute__((address_space(1))) void*)gw,
                (__attribute__((address_space(3))) void*)&smem[buf][1][r][0], 16, 0, 0);
        }
    };
    auto COMPUTE = [&](int buf) {
        bf16x8 af[4], bf[4];
        #pragma unroll
        for (int i = 0; i < 4; ++i)
            af[i] = *(const bf16x8*)&smem[buf][0][wm * 64 + i * 16 + lr][kg * 8];
        #pragma unroll
        for (int j = 0; j < 4; ++j)
            bf[j] = *(const bf16x8*)&smem[buf][1][wn * 64 + j * 16 + lr][kg * 8];
        #pragma unroll
        for (int i = 0; i < 4; ++i)
            #pragma unroll
            for (int j = 0; j < 4; ++j)
                acc[i][j] = __builtin_amdgcn_mfma_f32_16x16x32_bf16(af[i], bf[j], acc[i][j], 0, 0, 0);
    };

    const int nt = K >> 5;
    STAGE(0, 0);
    __syncthreads();
    int cur = 0;
    for (int t = 0; t < nt - 1; ++t) {
        STAGE(cur ^ 1, (t + 1) << 5);
        COMPUTE(cur);
        __syncthreads();
        cur ^= 1;
    }
    COMPUTE(cur);

    __syncthreads();
    short* eb = &smem[0][0][0][0];   // 128 x 128 bf16
    #pragma unroll
    for (int i = 0; i < 4; ++i)
        #pragma unroll
        for (int j = 0; j < 4; ++j)
            #pragma unroll
            for (int r = 0; r < 4; ++r) {
                int row = wm * 64 + i * 16 + kg * 4 + r;
                int col = wn * 64 + j * 16 + lr;
                eb[row * 128 + col] = f2b(acc[i][j][r]);
            }
    __syncthreads();
    #pragma unroll
    for (int ch = 0; ch < 8; ++ch) {
        int cidx = ch * 256 + tid;
        int row  = cidx >> 4;
        int cp   = cidx & 15;
        int ncol = n0 + cp * 8;
        if (ncol < Nreal)
            *(s16x8*)(C + (size_t)(m0 + row) * Nreal + ncol) =
                *(const s16x8*)(eb + row * 128 + cp * 8);
    }
}

// ---------------------------------------------------------------------------
// GEMM2: bf16 MFMA, 128x64 tile (384 blocks), fp32 out, XCD-swizzled.
// ---------------------------------------------------------------------------
__global__ __launch_bounds__(256) void gemm_bf16_n64_kernel(
    const short* __restrict__ A, const short* __restrict__ W,
    float* __restrict__ C, int K, int N, int NT)
{
    __shared__ short As[2][128][32];
    __shared__ short Ws[2][64][32];
    int flat = blockIdx.x;
    int swz  = (flat & 7) * (gridDim.x >> 3) + (flat >> 3);
    const int m0 = (swz / NT) * 128;
    const int n0 = (swz % NT) * 64;
    const int tid  = threadIdx.x;
    const int lane = tid & 63;
    const int wid  = tid >> 6;
    const int lr = lane & 15;
    const int kg = lane >> 4;

    f32x4 acc[2][4];
    #pragma unroll
    for (int i = 0; i < 2; ++i)
        #pragma unroll
        for (int j = 0; j < 4; ++j)
            acc[i][j] = (f32x4){0.f, 0.f, 0.f, 0.f};

    const int srow = (lane >> 2);
    const int scol = (lane & 3) * 8;

    auto STAGE = [&](int buf, int k0) {
        #pragma unroll
        for (int it = 0; it < 2; ++it) {
            int r = wid * 32 + it * 16;
            const short* ga = A + (size_t)(m0 + r + srow) * K + k0 + scol;
            __builtin_amdgcn_global_load_lds(
                (const __attribute__((address_space(1))) void*)ga,
                (__attribute__((address_space(3))) void*)&As[buf][r][0], 16, 0, 0);
        }
        int r2 = wid * 16;
        const short* gw = W + (size_t)(n0 + r2 + srow) * K + k0 + scol;
        __builtin_amdgcn_global_load_lds(
            (const __attribute__((address_space(1))) void*)gw,
            (__attribute__((address_space(3))) void*)&Ws[buf][r2][0], 16, 0, 0);
    };
    auto COMPUTE = [&](int buf) {
        bf16x8 af[2], bf[4];
        #pragma unroll
        for (int i = 0; i < 2; ++i)
            af[i] = *(const bf16x8*)&As[buf][wid * 32 + i * 16 + lr][kg * 8];
        #pragma unroll
        for (int j = 0; j < 4; ++j)
            bf[j] = *(const bf16x8*)&Ws[buf][j * 16 + lr][kg * 8];
        #pragma unroll
        for (int i = 0; i < 2; ++i)
            #pragma unroll
            for (int j = 0; j < 4; ++j)
                acc[i][j] = __builtin_amdgcn_mfma_f32_16x16x32_bf16(af[i], bf[j], acc[i][j], 0, 0, 0);
    };

    const int nt = K >> 5;
    STAGE(0, 0);
    __syncthreads();
    int cur = 0;
    for (int t = 0; t < nt - 1; ++t) {
        STAGE(cur ^ 1, (t + 1) << 5);
        COMPUTE(cur);
        __syncthreads();
        cur ^= 1;
    }
    COMPUTE(cur);

    #pragma unroll
    for (int i = 0; i < 2; ++i) {
        int mrow = m0 + wid * 32 + i * 16 + kg * 4;
        #pragma unroll
        for (int j = 0; j < 4; ++j) {
            int ncol = n0 + j * 16 + lr;
            #pragma unroll
            for (int r = 0; r < 4; ++r)
                C[(size_t)(mrow + r) * N + ncol] = acc[i][j][r];
        }
    }
}

// ---------------------------------------------------------------------------
// Cast kernels (fp32 -> bf16)
// ---------------------------------------------------------------------------
__global__ __launch_bounds__(256) void cast_bf16_kernel(
    const float* __restrict__ in, short* __restrict__ out, int n4)
{
    int i = blockIdx.x * 256 + threadIdx.x;
    if (i >= n4) return;
    float4 v = *(const float4*)(in + (size_t)i * 4);
    short4 o = make_short4(f2b(v.x), f2b(v.y), f2b(v.z), f2b(v.w));
    *(short4*)(out + (size_t)i * 4) = o;
}

__global__ __launch_bounds__(256) void cast_pad_w1_kernel(
    const float* __restrict__ w, short* __restrict__ wb)
{
    int i = blockIdx.x * 256 + threadIdx.x;
    const int n4 = N1_PAD * D_MODEL / 4;
    if (i >= n4) return;
    size_t base = (size_t)i * 4;
    int row = (int)(base / D_MODEL);
    float4 v = make_float4(0.f, 0.f, 0.f, 0.f);
    if (row < D_IN_PROJ) v = *(const float4*)(w + base);
    short4 o = make_short4(f2b(v.x), f2b(v.y), f2b(v.z), f2b(v.w));
    *(short4*)(wb + base) = o;
}

// ---------------------------------------------------------------------------
// Depthwise causal conv (k=4) + bias + SiLU. bf16 -> bf16.
// ---------------------------------------------------------------------------
__global__ __launch_bounds__(256) void conv_silu_kernel(
    const short* __restrict__ zxb, short* __restrict__ cob,
    const float* __restrict__ cw, const float* __restrict__ cb)
{
    const int NG = CONV_DIM / 8;
    int idx = blockIdx.x * 256 + threadIdx.x;
    int g = idx % NG;
    int r = idx / NG;
    int c0 = g * 8;
    int l = r & (SEQLEN - 1);

    float4 w[8];
    #pragma unroll
    for (int e = 0; e < 8; ++e)
        w[e] = *(const float4*)(cw + (size_t)(c0 + e) * 4);

    float acc[8];
    #pragma unroll
    for (int e = 0; e < 8; ++e) acc[e] = cb[c0 + e];

    #pragma unroll
    for (int tap = 0; tap < 4; ++tap) {
        if (l - 3 + tap >= 0) {
            s16x8 v = *(const s16x8*)(zxb + (size_t)(r - 3 + tap) * D_IN_PROJ + D_INNER + c0);
            #pragma unroll
            for (int e = 0; e < 8; ++e) {
                float we = (tap == 0) ? w[e].x : (tap == 1) ? w[e].y : (tap == 2) ? w[e].z : w[e].w;
                acc[e] = fmaf(b2f(v[e]), we, acc[e]);
            }
        }
    }
    s16x8 o;
    #pragma unroll
    for (int e = 0; e < 8; ++e)
        o[e] = f2b(acc[e] / (1.f + expf(-acc[e])));
    *(s16x8*)(cob + (size_t)r * CONV_DIM + c0) = o;
}

// ---------------------------------------------------------------------------
// dt_dis = softplus(dt + dt_bias), dta = dt_dis * A   (A = -exp(A_log))
// ---------------------------------------------------------------------------
__global__ __launch_bounds__(256) void dt_kernel(
    const short* __restrict__ zxb, const float* __restrict__ dt_bias,
    const float* __restrict__ A_log, float* __restrict__ dtb, float* __restrict__ dta)
{
    int idx = blockIdx.x * 256 + threadIdx.x;
    if (idx >= NROWS * NHEADS) return;
    int r = idx / NHEADS, h = idx - r * NHEADS;
    float x = b2f(zxb[(size_t)r * D_IN_PROJ + (D_INNER + CONV_DIM) + h]) + dt_bias[h];
    float sp = (x > 20.f) ? x : log1pf(expf(x));
    float A  = -expf(A_log[h]);
    dtb[idx] = sp;
    dta[idx] = sp * A;
}

// ---------------------------------------------------------------------------
// SSD pass A: per (b,h,chunk) chunk-end local state + clg/cumW.
// 768 blocks x 256 threads (4 waves).
//   clg = cumsum(dtA); cumW = exp(clg); clgbuf = clg
//   state[p,n] = sum_l (dt_l x[l,p]) * (exp(clgE-clg[l]) B[l,n])   (MFMA)
// ---------------------------------------------------------------------------
__global__ __launch_bounds__(256) void ssd_states(
    const short* __restrict__ co, const float* __restrict__ dtb,
    const float* __restrict__ dta, float* __restrict__ sstate,
    float* __restrict__ cumW, float* __restrict__ clgbuf)
{
    __shared__ short lds[26112];      // Bt[128][LDST] @0, Xt[64][LDST] @17408
    __shared__ float clg[128];
    __shared__ float dts[128];

    int t = blockIdx.x;
    int c = t & 15;
    int hb = t >> 4;
    int h = hb % NHEADS;
    int b = hb / NHEADS;
    const int R0 = b * SEQLEN + c * CHUNK;
    const int tid  = threadIdx.x;
    const int lane = tid & 63;
    const int wid  = tid >> 6;       // 0..3
    const int lr = lane & 15;
    const int kg = lane >> 4;
    const short* cobase = co + (size_t)R0 * CONV_DIM;

    if (tid < 128) {
        clg[tid] = dta[(size_t)(R0 + tid) * NHEADS + h];
        dts[tid] = dtb[(size_t)(R0 + tid) * NHEADS + h];
    }
    __syncthreads();
    for (int off = 1; off < 128; off <<= 1) {
        float v = 0.f;
        if (tid < 128 && tid >= off) v = clg[tid - off];
        __syncthreads();
        if (tid < 128) clg[tid] += v;
        __syncthreads();
    }
    const float clgE = clg[127];
    if (tid < 128) {
        size_t o = ((size_t)(b * NHEADS + h)) * SEQLEN + c * CHUNK + tid;
        cumW[o]   = __expf(clg[tid]);
        clgbuf[o] = clg[tid];
    }

    // stage Xt[p][l] = dt_l*x[l][p]; Bt[n][l] = exp(clgE-clg[l])*B[l][n]
    short* Bt = lds;
    short* Xt = lds + 128 * LDST;
    {
        int r = tid >> 1, q = tid & 1;   // r = l
        float dtv = dts[r];
        const short* xr = cobase + (size_t)r * CONV_DIM + h * HEADDIM + q * 32;
        #pragma unroll
        for (int i = 0; i < 4; ++i) {
            s16x8 xv = *(const s16x8*)(xr + i * 8);
            #pragma unroll
            for (int e = 0; e < 8; ++e)
                Xt[(q * 32 + i * 8 + e) * LDST + r] = f2b(b2f(xv[e]) * dtv);
        }
        float wstr = __expf(clgE - clg[r]);
        const short* br = cobase + (size_t)r * CONV_DIM + D_INNER + q * 64;
        #pragma unroll
        for (int i = 0; i < 8; ++i) {
            s16x8 bv = *(const s16x8*)(br + i * 8);
            #pragma unroll
            for (int e = 0; e < 8; ++e)
                Bt[(q * 64 + i * 8 + e) * LDST + r] = f2b(b2f(bv[e]) * wstr);
        }
    }
    __syncthreads();

    // state GEMM: M=64 (p), N=128 (n), K=128 (l). Wave wid covers n = wid*32.
    f32x4 acc[4][2];
    #pragma unroll
    for (int i = 0; i < 4; ++i)
        #pragma unroll
        for (int j = 0; j < 2; ++j)
            acc[i][j] = (f32x4){0.f, 0.f, 0.f, 0.f};
    #pragma unroll
    for (int kk = 0; kk < 4; ++kk) {
        bf16x8 af[4], bf[2];
        #pragma unroll
        for (int i = 0; i < 4; ++i)
            af[i] = *(const bf16x8*)(Xt + (i * 16 + lr) * LDST + kk * 32 + kg * 8);
        #pragma unroll
        for (int j = 0; j < 2; ++j)
            bf[j] = *(const bf16x8*)(Bt + (wid * 32 + j * 16 + lr) * LDST + kk * 32 + kg * 8);
        #pragma unroll
        for (int i = 0; i < 4; ++i)
            #pragma unroll
            for (int j = 0; j < 2; ++j)
                acc[i][j] = __builtin_amdgcn_mfma_f32_16x16x32_bf16(af[i], bf[j], acc[i][j], 0, 0, 0);
    }
    float* sbase = sstate + (((size_t)(b * NHEADS + h)) * NCHUNK + c) * STATE_SZ;
    #pragma unroll
    for (int i = 0; i < 4; ++i)
        #pragma unroll
        for (int j = 0; j < 2; ++j)
            #pragma unroll
            for (int r = 0; r < 4; ++r) {
                int p = i * 16 + kg * 4 + r;
                int n = wid * 32 + j * 16 + lr;
                sbase[p * D_STATE + n] = acc[i][j][r];
            }
}

// ---------------------------------------------------------------------------
// Scan pass: prefix over chunk states per (b,h). In-place, parallel.
// ---------------------------------------------------------------------------
__global__ __launch_bounds__(128) void scan_chunk_prefix(
    const float* __restrict__ cumW, float* __restrict__ sstate)
{
    int blk = blockIdx.x;
    int piece = blk & 15;
    int bh = blk >> 4;
    int tid = threadIdx.x;
    float* base = sstate + (size_t)bh * NCHUNK * STATE_SZ + piece * 512 + tid * 4;
    const float* cw = cumW + (size_t)bh * SEQLEN;
    float4 run = make_float4(0.f, 0.f, 0.f, 0.f);
    for (int c = 0; c < NCHUNK; ++c) {
        float Ac = cw[c * CHUNK + (CHUNK - 1)];
        float* ptr = base + (size_t)c * STATE_SZ;
        float4 loc = *(float4*)ptr;
        *(float4*)ptr = run;
        run.x = fmaf(Ac, run.x, loc.x);
        run.y = fmaf(Ac, run.y, loc.y);
        run.z = fmaf(Ac, run.z, loc.z);
        run.w = fmaf(Ac, run.w, loc.w);
    }
}

// ---------------------------------------------------------------------------
// SSD pass B: full Y per (b,h,chunk). 768 blocks x 512 threads (8 waves).
//   S = C.B^T; Ps = mask/decay(S); Y1 = Ps.Xt^T; Y2 = C.sinit^T
//   y[l,p] = Y1 + exp(clg[l])*Y2 + D*x   -> ybuf (bf16, coalesced via LDS)
// ---------------------------------------------------------------------------
__global__ __launch_bounds__(512) void ssd_y(
    const short* __restrict__ co, const float* __restrict__ dtb,
    const float* __restrict__ clgbuf, const float* __restrict__ sstate,
    const float* __restrict__ Dvec, short* __restrict__ ybuf)
{
    __shared__ short lds[26112];
    __shared__ float clg[128];
    __shared__ float dts[128];

    int t = blockIdx.x;
    int c = t & 15;
    int hb = t >> 4;
    int h = hb % NHEADS;
    int b = hb / NHEADS;
    const int R0 = b * SEQLEN + c * CHUNK;
    const int tid  = threadIdx.x;
    const int lane = tid & 63;
    const int wid  = tid >> 6;       // 0..7
    const int lr = lane & 15;
    const int kg = lane >> 4;
    const short* cobase = co + (size_t)R0 * CONV_DIM;

    if (tid < 128) {
        size_t o = ((size_t)(b * NHEADS + h)) * SEQLEN + c * CHUNK + tid;
        clg[tid] = clgbuf[o];
        dts[tid] = dtb[(size_t)(R0 + tid) * NHEADS + h];
    }
    __syncthreads();

    // --- S = C . B^T (two 64-col halves) ---
    short* CsH = lds;                 // [128][H72]
    short* BsH = lds + 128 * H72;
    const int wmS = wid >> 2, wnS = wid & 3;
    f32x4 accS[4][2];
    #pragma unroll
    for (int i = 0; i < 4; ++i)
        #pragma unroll
        for (int j = 0; j < 2; ++j)
            accS[i][j] = (f32x4){0.f, 0.f, 0.f, 0.f};

    for (int kh = 0; kh < 2; ++kh) {
        {
            int r = tid >> 2, q = tid & 3;
            const short* cr = cobase + (size_t)r * CONV_DIM + (D_INNER + D_STATE) + kh * 64 + q * 16;
            const short* br = cobase + (size_t)r * CONV_DIM + D_INNER + kh * 64 + q * 16;
            *(s16x8*)(CsH + r * H72 + q * 16)     = *(const s16x8*)cr;
            *(s16x8*)(CsH + r * H72 + q * 16 + 8) = *(const s16x8*)(cr + 8);
            *(s16x8*)(BsH + r * H72 + q * 16)     = *(const s16x8*)br;
            *(s16x8*)(BsH + r * H72 + q * 16 + 8) = *(const s16x8*)(br + 8);
        }
        __syncthreads();
        #pragma unroll
        for (int kk = 0; kk < 2; ++kk) {
            bf16x8 af[4], bf[2];
            #pragma unroll
            for (int i = 0; i < 4; ++i)
                af[i] = *(const bf16x8*)(CsH + (wmS * 64 + i * 16 + lr) * H72 + kk * 32 + kg * 8);
            #pragma unroll
            for (int j = 0; j < 2; ++j)
                bf[j] = *(const bf16x8*)(BsH + (wnS * 32 + j * 16 + lr) * H72 + kk * 32 + kg * 8);
            #pragma unroll
            for (int i = 0; i < 4; ++i)
                #pragma unroll
                for (int j = 0; j < 2; ++j)
                    accS[i][j] = __builtin_amdgcn_mfma_f32_16x16x32_bf16(af[i], bf[j], accS[i][j], 0, 0, 0);
        }
        __syncthreads();
    }

    // --- Ps = mask/decay(S); stage Xt ---
    short* Ps = lds;                  // [128][LDST]
    short* Xt = lds + 128 * LDST;     // [64][LDST]
    #pragma unroll
    for (int i = 0; i < 4; ++i)
        #pragma unroll
        for (int j = 0; j < 2; ++j)
            #pragma unroll
            for (int r = 0; r < 4; ++r) {
                int l  = wmS * 64 + i * 16 + kg * 4 + r;
                int lp = wnS * 32 + j * 16 + lr;
                float w = (lp <= l) ? __expf(clg[l] - clg[lp]) : 0.f;
                Ps[l * LDST + lp] = f2b(accS[i][j][r] * w);
            }
    if (tid < 256) {
        int r = tid >> 1, q = tid & 1;
        const short* xr = cobase + (size_t)r * CONV_DIM + h * HEADDIM + q * 32;
        float dtv = dts[r];
        #pragma unroll
        for (int i = 0; i < 4; ++i) {
            s16x8 xv = *(const s16x8*)(xr + i * 8);
            #pragma unroll
            for (int e = 0; e < 8; ++e)
                Xt[(q * 32 + i * 8 + e) * LDST + r] = f2b(b2f(xv[e]) * dtv);
        }
    }
    __syncthreads();

    // --- Y1 = Ps . Xt^T ---
    const int wm = wid >> 1, wn = wid & 1;
    f32x4 acc1[2][2];
    #pragma unroll
    for (int i = 0; i < 2; ++i)
        #pragma unroll
        for (int j = 0; j < 2; ++j)
            acc1[i][j] = (f32x4){0.f, 0.f, 0.f, 0.f};
    #pragma unroll
    for (int kk = 0; kk < 4; ++kk) {
        bf16x8 af[2], bf[2];
        #pragma unroll
        for (int i = 0; i < 2; ++i)
            af[i] = *(const bf16x8*)(Ps + (wm * 32 + i * 16 + lr) * LDST + kk * 32 + kg * 8);
        #pragma unroll
        for (int j = 0; j < 2; ++j)
            bf[j] = *(const bf16x8*)(Xt + (wn * 32 + j * 16 + lr) * LDST + kk * 32 + kg * 8);
        #pragma unroll
        for (int i = 0; i < 2; ++i)
            #pragma unroll
            for (int j = 0; j < 2; ++j)
                acc1[i][j] = __builtin_amdgcn_mfma_f32_16x16x32_bf16(af[i], bf[j], acc1[i][j], 0, 0, 0);
    }
    __syncthreads();

    // --- restage Cs (full width) + Sn(bf16 sinit) ---
    short* Cs = lds;                  // [128][LDST]
    short* Sn = lds + 128 * LDST;     // [64][LDST]
    {
        int r = tid >> 2, q = tid & 3;
        const short* cr = cobase + (size_t)r * CONV_DIM + (D_INNER + D_STATE) + q * 32;
        #pragma unroll
        for (int i = 0; i < 4; ++i)
            *(s16x8*)(Cs + r * LDST + q * 32 + i * 8) = *(const s16x8*)(cr + i * 8);
    }
    {
        int r = tid >> 3, q = tid & 7;   // r = p 0..63
        const float* sr = sstate + (((size_t)(b * NHEADS + h)) * NCHUNK + c) * STATE_SZ
                          + (size_t)r * D_STATE + q * 16;
        #pragma unroll
        for (int i = 0; i < 4; ++i) {
            float4 sv = *(const float4*)(sr + i * 4);
            *(short4*)(Sn + r * LDST + q * 16 + i * 4) =
                make_short4(f2b(sv.x), f2b(sv.y), f2b(sv.z), f2b(sv.w));
        }
    }
    __syncthreads();

    // --- Y2 = C . sinit^T ---
    f32x4 acc2[2][2];
    #pragma unroll
    for (int i = 0; i < 2; ++i)
        #pragma unroll
        for (int j = 0; j < 2; ++j)
            acc2[i][j] = (f32x4){0.f, 0.f, 0.f, 0.f};
    #pragma unroll
    for (int kk = 0; kk < 4; ++kk) {
        bf16x8 af[2], bf[2];
        #pragma unroll
        for (int i = 0; i < 2; ++i)
            af[i] = *(const bf16x8*)(Cs + (wm * 32 + i * 16 + lr) * LDST + kk * 32 + kg * 8);
        #pragma unroll
        for (int j = 0; j < 2; ++j)
            bf[j] = *(const bf16x8*)(Sn + (wn * 32 + j * 16 + lr) * LDST + kk * 32 + kg * 8);
        #pragma unroll
        for (int i = 0; i < 2; ++i)
            #pragma unroll
            for (int j = 0; j < 2; ++j)
                acc2[i][j] = __builtin_amdgcn_mfma_f32_16x16x32_bf16(af[i], bf[j], acc2[i][j], 0, 0, 0);
    }
    __syncthreads();

    // --- combine + coalesced bf16 store via LDS repack ---
    short* yt = lds;                  // [128][H72]
    const float Dh = Dvec[h];
    #pragma unroll
    for (int i = 0; i < 2; ++i)
        #pragma unroll
        for (int j = 0; j < 2; ++j)
            #pragma unroll
            for (int r = 0; r < 4; ++r) {
                int l = wm * 32 + i * 16 + kg * 4 + r;
                int p = wn * 32 + j * 16 + lr;
                float cw = __expf(clg[l]);
                float xval = b2f(cobase[(size_t)l * CONV_DIM + h * HEADDIM + p]);
                yt[l * H72 + p] = f2b(acc1[i][j][r] + cw * acc2[i][j][r] + Dh * xval);
            }
    __syncthreads();
    #pragma unroll
    for (int k = 0; k < 2; ++k) {
        int idx = tid * 2 + k;           // 0..1023 = 128 rows x 8 chunks
        int row = idx >> 3;
        int cp  = idx & 7;
        *(s16x8*)(ybuf + (size_t)(R0 + row) * D_INNER + h * HEADDIM + cp * 8) =
            *(const s16x8*)(yt + row * H72 + cp * 8);
    }
}

// ---------------------------------------------------------------------------
// yz = y * silu(z);  yn = yz * rsqrt(mean(yz^2)+eps) * norm_w  -> bf16
// y (bf16) + z (bf16), 192 threads x 8 cols, vectorized.
// ---------------------------------------------------------------------------
__global__ __launch_bounds__(192) void gate_norm_kernel(
    const short* __restrict__ zxb, const short* __restrict__ ybuf,
    const float* __restrict__ norm_w, short* __restrict__ yn)
{
    int r = blockIdx.x;
    int c0 = threadIdx.x * 8;
    s16x8 zv = *(const s16x8*)(zxb + (size_t)r * D_IN_PROJ + c0);
    s16x8 yv = *(const s16x8*)(ybuf + (size_t)r * D_INNER + c0);
    float vals[8];
    float ss = 0.f;
    #pragma unroll
    for (int e = 0; e < 8; ++e) {
        float z = b2f(zv[e]);
        float y = b2f(yv[e]);
        float v = y * (z / (1.f + expf(-z)));
        vals[e] = v;
        ss = fmaf(v, v, ss);
    }
    ss += __shfl_xor(ss, 1);
    ss += __shfl_xor(ss, 2);
    ss += __shfl_xor(ss, 4);
    ss += __shfl_xor(ss, 8);
    ss += __shfl_xor(ss, 16);
    ss += __shfl_xor(ss, 32);
    __shared__ float red[3];
    if ((threadIdx.x & 63) == 0) red[threadIdx.x >> 6] = ss;
    __syncthreads();
    float tot = red[0] + red[1] + red[2];
    float scale = rsqrtf(tot / (float)D_INNER + EPS);
    float4 nw0 = *(const float4*)(norm_w + c0);
    float4 nw1 = *(const float4*)(norm_w + c0 + 4);
    const float nw[8] = {nw0.x, nw0.y, nw0.z, nw0.w, nw1.x, nw1.y, nw1.z, nw1.w};
    s16x8 o;
    #pragma unroll
    for (int e = 0; e < 8; ++e)
        o[e] = f2b(vals[e] * scale * nw[e]);
    *(s16x8*)(yn + (size_t)r * D_INNER + c0) = o;
}

// ---------------------------------------------------------------------------
extern "C" void kernel_launch(void* const* d_in, const int* in_sizes, int n_in,
                              void* d_out, int out_size, void* d_ws, size_t ws_size,
                              hipStream_t stream) {
    const float* u          = (const float*)d_in[0];
    const float* in_proj_w  = (const float*)d_in[1];
    const float* conv_w     = (const float*)d_in[2];
    const float* conv_b     = (const float*)d_in[3];
    const float* dt_bias    = (const float*)d_in[4];
    const float* A_log      = (const float*)d_in[5];
    const float* Dvec       = (const float*)d_in[6];
    const float* norm_w     = (const float*)d_in[7];
    const float* out_proj_w = (const float*)d_in[8];
    float* out = (float*)d_out;

    // workspace carve-up:
    short* zxb    = (short*)d_ws;                            // 4096*3352 bf16
    short* cob    = zxb + (size_t)NROWS * D_IN_PROJ;         // 4096*1792 bf16
    float* dtb    = (float*)(cob + (size_t)NROWS * CONV_DIM);
    float* dta    = dtb  + (size_t)NROWS * NHEADS;
    short* ybuf   = (short*)(dta + (size_t)NROWS * NHEADS);  // 4096*1536 bf16
    float* sstate = (float*)(ybuf + (size_t)NROWS * D_INNER);// 48*16*8192 fp32
    float* cumW   = sstate + (size_t)BATCH*NHEADS*NCHUNK*STATE_SZ;
    float* clgbuf = cumW + (size_t)BATCH*NHEADS*SEQLEN;

    // aliases (regions dead at time of use):
    short* ub  = (short*)sstate;               // 4096*768 (dead before ssd_states)
    short* w1b = ub + (size_t)NROWS * D_MODEL; // 3456*768
    short* ynb = (short*)sstate;               // 4096*1536 (after ssd_y reads sstate)
    short* w2b = zxb;                          // 768*1536  (after gate_norm reads z)

    // 0) casts for GEMM1
    cast_bf16_kernel<<<(NROWS*D_MODEL/4 + 255)/256, 256, 0, stream>>>(u, ub, NROWS*D_MODEL/4);
    cast_pad_w1_kernel<<<(N1_PAD*D_MODEL/4 + 255)/256, 256, 0, stream>>>(in_proj_w, w1b);
    // 1) in-proj GEMM (bf16 MFMA, XCD-swizzled) -> zxb bf16
    gemm_bf16_kernel<<<(NROWS/128)*(N1_PAD/128), 256, 0, stream>>>(ub, w1b, zxb, D_MODEL, D_IN_PROJ, N1_PAD/128);
    // 2) depthwise conv + SiLU
    conv_silu_kernel<<<NROWS*(CONV_DIM/8)/256, 256, 0, stream>>>(zxb, cob, conv_w, conv_b);
    // 3) dt_dis / dtA
    dt_kernel<<<(NROWS*NHEADS + 255)/256, 256, 0, stream>>>(zxb, dt_bias, A_log, dtb, dta);
    // 4) SSD: states -> prefix -> Y
    ssd_states<<<BATCH*NHEADS*NCHUNK, 256, 0, stream>>>(cob, dtb, dta, sstate, cumW, clgbuf);
    scan_chunk_prefix<<<BATCH*NHEADS*16, 128, 0, stream>>>(cumW, sstate);
    ssd_y<<<BATCH*NHEADS*NCHUNK, 512, 0, stream>>>(cob, dtb, clgbuf, sstate, Dvec, ybuf);
    // 5) gate + RMSNorm -> bf16
    gate_norm_kernel<<<NROWS, 192, 0, stream>>>(zxb, ybuf, norm_w, ynb);
    // 6) cast out_proj_w (zxb dead)
    cast_bf16_kernel<<<(D_MODEL*D_INNER/4 + 255)/256, 256, 0, stream>>>(out_proj_w, w2b, D_MODEL*D_INNER/4);
    // 7) out-proj GEMM (128x64 tiles, 384 blocks, XCD-swizzled) -> fp32 out
    gemm_bf16_n64_kernel<<<(NROWS/128)*(D_MODEL/64), 256, 0, stream>>>(ynb, w2b, out, D_INNER, D_MODEL, D_MODEL/64);
}

// Round 9
// 235.096 us; speedup vs baseline: 6.2033x; 1.0037x over previous
//
#include <hip/hip_runtime.h>
#include <hip/hip_bf16.h>
#include <math.h>

// Problem constants
#define D_MODEL   768
#define D_INNER   1536
#define D_STATE   128
#define HEADDIM   64
#define NHEADS    24
#define D_CONV    4
#define CONV_DIM  1792            // D_INNER + 2*D_STATE
#define D_IN_PROJ 3352            // 2*D_INNER + 2*D_STATE + NHEADS
#define BATCH     2
#define SEQLEN    2048
#define NROWS     (BATCH*SEQLEN)  // 4096
#define EPS       1e-5f

#define NCHUNK    16
#define CHUNK     128             // SEQLEN / NCHUNK
#define STATE_SZ  (HEADDIM*D_STATE)   // 8192 per (b,h,chunk)

#define N1_PAD    3456            // 27*128, padded N for GEMM1
#define LDST      136             // padded LDS row stride (bf16 elems), 272B
#define H72       72              // padded stride for 64-col half tiles (144B)

typedef __bf16 bf16x8 __attribute__((ext_vector_type(8)));
typedef float  f32x4  __attribute__((ext_vector_type(4)));
typedef short  s16x8  __attribute__((ext_vector_type(8)));

// RNE float -> bf16 bit pattern
__device__ __forceinline__ short f2b(float f) {
    unsigned u = __float_as_uint(f);
    unsigned r = (u + 0x7FFFu + ((u >> 16) & 1u)) >> 16;
    return (short)r;
}
// bf16 bits -> float
__device__ __forceinline__ float b2f(short s) {
    return __uint_as_float(((unsigned)(unsigned short)s) << 16);
}

// ---------------------------------------------------------------------------
// GEMM1: bf16 MFMA, 128x128 tile, 3-buffer counted-vmcnt pipeline (T4),
// XCD-swizzled 1D grid, bf16 output via LDS repack.
// Per-thread STAGE = 4 global_load_lds; 2 stages in flight -> vmcnt(4).
// ---------------------------------------------------------------------------
__global__ __launch_bounds__(256) void gemm_bf16_kernel(
    const short* __restrict__ A, const short* __restrict__ W,
    short* __restrict__ C, int K, int Nreal, int NT)
{
    __shared__ short smem[3][2][128][32];   // 48 KB, 3-deep
    int flat = blockIdx.x;
    int swz  = (flat & 7) * (gridDim.x >> 3) + (flat >> 3);
    const int m0 = (swz / NT) * 128;
    const int n0 = (swz % NT) * 128;
    const int tid  = threadIdx.x;
    const int lane = tid & 63;
    const int wid  = tid >> 6;
    const int wm = wid >> 1, wn = wid & 1;
    const int lr = lane & 15;
    const int kg = lane >> 4;

    f32x4 acc[4][4];
    #pragma unroll
    for (int i = 0; i < 4; ++i)
        #pragma unroll
        for (int j = 0; j < 4; ++j)
            acc[i][j] = (f32x4){0.f, 0.f, 0.f, 0.f};

    const int srow = (lane >> 2);
    const int scol = (lane & 3) * 8;

    auto STAGE = [&](int buf, int k0) {
        #pragma unroll
        for (int it = 0; it < 2; ++it) {
            int r = wid * 32 + it * 16;
            const short* ga = A + (size_t)(m0 + r + srow) * K + k0 + scol;
            const short* gw = W + (size_t)(n0 + r + srow) * K + k0 + scol;
            __builtin_amdgcn_global_load_lds(
                (const __attribute__((address_space(1))) void*)ga,
                (__attribute__((address_space(3))) void*)&smem[buf][0][r][0], 16, 0, 0);
            __builtin_amdgcn_global_load_lds(
                (const __attribute__((address_space(1))) void*)gw,
                (__attribute__((address_space(3))) void*)&smem[buf][1][r][0], 16, 0, 0);
        }
    };
    auto COMPUTE = [&](int buf) {
        bf16x8 af[4], bf[4];
        #pragma unroll
        for (int i = 0; i < 4; ++i)
            af[i] = *(const bf16x8*)&smem[buf][0][wm * 64 + i * 16 + lr][kg * 8];
        #pragma unroll
        for (int j = 0; j < 4; ++j)
            bf[j] = *(const bf16x8*)&smem[buf][1][wn * 64 + j * 16 + lr][kg * 8];
        #pragma unroll
        for (int i = 0; i < 4; ++i)
            #pragma unroll
            for (int j = 0; j < 4; ++j)
                acc[i][j] = __builtin_amdgcn_mfma_f32_16x16x32_bf16(af[i], bf[j], acc[i][j], 0, 0, 0);
    };

    const int nt = K >> 5;      // >= 2 always here (24 or 48)
    STAGE(0, 0);
    STAGE(1, 32);
    int cur = 0, nxt = 2;
    for (int t = 0; t < nt - 1; ++t) {
        asm volatile("s_waitcnt vmcnt(4)" ::: "memory");   // buf cur ready; newer stage stays in flight
        __builtin_amdgcn_s_barrier();
        if (t + 2 < nt) STAGE(nxt, (t + 2) << 5);
        COMPUTE(cur);
        cur = (cur == 2) ? 0 : cur + 1;
        nxt = (nxt == 2) ? 0 : nxt + 1;
    }
    asm volatile("s_waitcnt vmcnt(0)" ::: "memory");
    __builtin_amdgcn_s_barrier();
    COMPUTE(cur);

    __syncthreads();
    short* eb = &smem[0][0][0][0];   // 128 x 128 bf16 repack
    #pragma unroll
    for (int i = 0; i < 4; ++i)
        #pragma unroll
        for (int j = 0; j < 4; ++j)
            #pragma unroll
            for (int r = 0; r < 4; ++r) {
                int row = wm * 64 + i * 16 + kg * 4 + r;
                int col = wn * 64 + j * 16 + lr;
                eb[row * 128 + col] = f2b(acc[i][j][r]);
            }
    __syncthreads();
    #pragma unroll
    for (int ch = 0; ch < 8; ++ch) {
        int cidx = ch * 256 + tid;
        int row  = cidx >> 4;
        int cp   = cidx & 15;
        int ncol = n0 + cp * 8;
        if (ncol < Nreal)
            *(s16x8*)(C + (size_t)(m0 + row) * Nreal + ncol) =
                *(const s16x8*)(eb + row * 128 + cp * 8);
    }
}

// ---------------------------------------------------------------------------
// GEMM2: bf16 MFMA, 128x64 tile, 3-buffer counted-vmcnt pipeline, fp32 out.
// Per-thread STAGE = 3 loads; vmcnt(3).
// ---------------------------------------------------------------------------
__global__ __launch_bounds__(256) void gemm_bf16_n64_kernel(
    const short* __restrict__ A, const short* __restrict__ W,
    float* __restrict__ C, int K, int N, int NT)
{
    __shared__ short As[3][128][32];   // 24 KB
    __shared__ short Ws[3][64][32];    // 12 KB
    int flat = blockIdx.x;
    int swz  = (flat & 7) * (gridDim.x >> 3) + (flat >> 3);
    const int m0 = (swz / NT) * 128;
    const int n0 = (swz % NT) * 64;
    const int tid  = threadIdx.x;
    const int lane = tid & 63;
    const int wid  = tid >> 6;
    const int lr = lane & 15;
    const int kg = lane >> 4;

    f32x4 acc[2][4];
    #pragma unroll
    for (int i = 0; i < 2; ++i)
        #pragma unroll
        for (int j = 0; j < 4; ++j)
            acc[i][j] = (f32x4){0.f, 0.f, 0.f, 0.f};

    const int srow = (lane >> 2);
    const int scol = (lane & 3) * 8;

    auto STAGE = [&](int buf, int k0) {
        #pragma unroll
        for (int it = 0; it < 2; ++it) {
            int r = wid * 32 + it * 16;
            const short* ga = A + (size_t)(m0 + r + srow) * K + k0 + scol;
            __builtin_amdgcn_global_load_lds(
                (const __attribute__((address_space(1))) void*)ga,
                (__attribute__((address_space(3))) void*)&As[buf][r][0], 16, 0, 0);
        }
        int r2 = wid * 16;
        const short* gw = W + (size_t)(n0 + r2 + srow) * K + k0 + scol;
        __builtin_amdgcn_global_load_lds(
            (const __attribute__((address_space(1))) void*)gw,
            (__attribute__((address_space(3))) void*)&Ws[buf][r2][0], 16, 0, 0);
    };
    auto COMPUTE = [&](int buf) {
        bf16x8 af[2], bf[4];
        #pragma unroll
        for (int i = 0; i < 2; ++i)
            af[i] = *(const bf16x8*)&As[buf][wid * 32 + i * 16 + lr][kg * 8];
        #pragma unroll
        for (int j = 0; j < 4; ++j)
            bf[j] = *(const bf16x8*)&Ws[buf][j * 16 + lr][kg * 8];
        #pragma unroll
        for (int i = 0; i < 2; ++i)
            #pragma unroll
            for (int j = 0; j < 4; ++j)
                acc[i][j] = __builtin_amdgcn_mfma_f32_16x16x32_bf16(af[i], bf[j], acc[i][j], 0, 0, 0);
    };

    const int nt = K >> 5;
    STAGE(0, 0);
    STAGE(1, 32);
    int cur = 0, nxt = 2;
    for (int t = 0; t < nt - 1; ++t) {
        asm volatile("s_waitcnt vmcnt(3)" ::: "memory");
        __builtin_amdgcn_s_barrier();
        if (t + 2 < nt) STAGE(nxt, (t + 2) << 5);
        COMPUTE(cur);
        cur = (cur == 2) ? 0 : cur + 1;
        nxt = (nxt == 2) ? 0 : nxt + 1;
    }
    asm volatile("s_waitcnt vmcnt(0)" ::: "memory");
    __builtin_amdgcn_s_barrier();
    COMPUTE(cur);

    #pragma unroll
    for (int i = 0; i < 2; ++i) {
        int mrow = m0 + wid * 32 + i * 16 + kg * 4;
        #pragma unroll
        for (int j = 0; j < 4; ++j) {
            int ncol = n0 + j * 16 + lr;
            #pragma unroll
            for (int r = 0; r < 4; ++r)
                C[(size_t)(mrow + r) * N + ncol] = acc[i][j][r];
        }
    }
}

// ---------------------------------------------------------------------------
// Cast kernels (fp32 -> bf16)
// ---------------------------------------------------------------------------
__global__ __launch_bounds__(256) void cast_bf16_kernel(
    const float* __restrict__ in, short* __restrict__ out, int n4)
{
    int i = blockIdx.x * 256 + threadIdx.x;
    if (i >= n4) return;
    float4 v = *(const float4*)(in + (size_t)i * 4);
    short4 o = make_short4(f2b(v.x), f2b(v.y), f2b(v.z), f2b(v.w));
    *(short4*)(out + (size_t)i * 4) = o;
}

__global__ __launch_bounds__(256) void cast_pad_w1_kernel(
    const float* __restrict__ w, short* __restrict__ wb)
{
    int i = blockIdx.x * 256 + threadIdx.x;
    const int n4 = N1_PAD * D_MODEL / 4;
    if (i >= n4) return;
    size_t base = (size_t)i * 4;
    int row = (int)(base / D_MODEL);
    float4 v = make_float4(0.f, 0.f, 0.f, 0.f);
    if (row < D_IN_PROJ) v = *(const float4*)(w + base);
    short4 o = make_short4(f2b(v.x), f2b(v.y), f2b(v.z), f2b(v.w));
    *(short4*)(wb + base) = o;
}

// ---------------------------------------------------------------------------
// Depthwise causal conv (k=4) + bias + SiLU. bf16 -> bf16.
// ---------------------------------------------------------------------------
__global__ __launch_bounds__(256) void conv_silu_kernel(
    const short* __restrict__ zxb, short* __restrict__ cob,
    const float* __restrict__ cw, const float* __restrict__ cb)
{
    const int NG = CONV_DIM / 8;
    int idx = blockIdx.x * 256 + threadIdx.x;
    int g = idx % NG;
    int r = idx / NG;
    int c0 = g * 8;
    int l = r & (SEQLEN - 1);

    float4 w[8];
    #pragma unroll
    for (int e = 0; e < 8; ++e)
        w[e] = *(const float4*)(cw + (size_t)(c0 + e) * 4);

    float acc[8];
    #pragma unroll
    for (int e = 0; e < 8; ++e) acc[e] = cb[c0 + e];

    #pragma unroll
    for (int tap = 0; tap < 4; ++tap) {
        if (l - 3 + tap >= 0) {
            s16x8 v = *(const s16x8*)(zxb + (size_t)(r - 3 + tap) * D_IN_PROJ + D_INNER + c0);
            #pragma unroll
            for (int e = 0; e < 8; ++e) {
                float we = (tap == 0) ? w[e].x : (tap == 1) ? w[e].y : (tap == 2) ? w[e].z : w[e].w;
                acc[e] = fmaf(b2f(v[e]), we, acc[e]);
            }
        }
    }
    s16x8 o;
    #pragma unroll
    for (int e = 0; e < 8; ++e)
        o[e] = f2b(acc[e] / (1.f + expf(-acc[e])));
    *(s16x8*)(cob + (size_t)r * CONV_DIM + c0) = o;
}

// ---------------------------------------------------------------------------
// dt_dis = softplus(dt + dt_bias), dta = dt_dis * A   (A = -exp(A_log))
// ---------------------------------------------------------------------------
__global__ __launch_bounds__(256) void dt_kernel(
    const short* __restrict__ zxb, const float* __restrict__ dt_bias,
    const float* __restrict__ A_log, float* __restrict__ dtb, float* __restrict__ dta)
{
    int idx = blockIdx.x * 256 + threadIdx.x;
    if (idx >= NROWS * NHEADS) return;
    int r = idx / NHEADS, h = idx - r * NHEADS;
    float x = b2f(zxb[(size_t)r * D_IN_PROJ + (D_INNER + CONV_DIM) + h]) + dt_bias[h];
    float sp = (x > 20.f) ? x : log1pf(expf(x));
    float A  = -expf(A_log[h]);
    dtb[idx] = sp;
    dta[idx] = sp * A;
}

// ---------------------------------------------------------------------------
// SSD pass A: per (b,h,chunk) chunk-end local state + clg/cumW.
// 768 blocks x 256 threads (4 waves).
// ---------------------------------------------------------------------------
__global__ __launch_bounds__(256) void ssd_states(
    const short* __restrict__ co, const float* __restrict__ dtb,
    const float* __restrict__ dta, float* __restrict__ sstate,
    float* __restrict__ cumW, float* __restrict__ clgbuf)
{
    __shared__ short lds[26112];
    __shared__ float clg[128];
    __shared__ float dts[128];

    int t = blockIdx.x;
    int c = t & 15;
    int hb = t >> 4;
    int h = hb % NHEADS;
    int b = hb / NHEADS;
    const int R0 = b * SEQLEN + c * CHUNK;
    const int tid  = threadIdx.x;
    const int lane = tid & 63;
    const int wid  = tid >> 6;
    const int lr = lane & 15;
    const int kg = lane >> 4;
    const short* cobase = co + (size_t)R0 * CONV_DIM;

    if (tid < 128) {
        clg[tid] = dta[(size_t)(R0 + tid) * NHEADS + h];
        dts[tid] = dtb[(size_t)(R0 + tid) * NHEADS + h];
    }
    __syncthreads();
    for (int off = 1; off < 128; off <<= 1) {
        float v = 0.f;
        if (tid < 128 && tid >= off) v = clg[tid - off];
        __syncthreads();
        if (tid < 128) clg[tid] += v;
        __syncthreads();
    }
    const float clgE = clg[127];
    if (tid < 128) {
        size_t o = ((size_t)(b * NHEADS + h)) * SEQLEN + c * CHUNK + tid;
        cumW[o]   = __expf(clg[tid]);
        clgbuf[o] = clg[tid];
    }

    short* Bt = lds;
    short* Xt = lds + 128 * LDST;
    {
        int r = tid >> 1, q = tid & 1;
        float dtv = dts[r];
        const short* xr = cobase + (size_t)r * CONV_DIM + h * HEADDIM + q * 32;
        #pragma unroll
        for (int i = 0; i < 4; ++i) {
            s16x8 xv = *(const s16x8*)(xr + i * 8);
            #pragma unroll
            for (int e = 0; e < 8; ++e)
                Xt[(q * 32 + i * 8 + e) * LDST + r] = f2b(b2f(xv[e]) * dtv);
        }
        float wstr = __expf(clgE - clg[r]);
        const short* br = cobase + (size_t)r * CONV_DIM + D_INNER + q * 64;
        #pragma unroll
        for (int i = 0; i < 8; ++i) {
            s16x8 bv = *(const s16x8*)(br + i * 8);
            #pragma unroll
            for (int e = 0; e < 8; ++e)
                Bt[(q * 64 + i * 8 + e) * LDST + r] = f2b(b2f(bv[e]) * wstr);
        }
    }
    __syncthreads();

    f32x4 acc[4][2];
    #pragma unroll
    for (int i = 0; i < 4; ++i)
        #pragma unroll
        for (int j = 0; j < 2; ++j)
            acc[i][j] = (f32x4){0.f, 0.f, 0.f, 0.f};
    #pragma unroll
    for (int kk = 0; kk < 4; ++kk) {
        bf16x8 af[4], bf[2];
        #pragma unroll
        for (int i = 0; i < 4; ++i)
            af[i] = *(const bf16x8*)(Xt + (i * 16 + lr) * LDST + kk * 32 + kg * 8);
        #pragma unroll
        for (int j = 0; j < 2; ++j)
            bf[j] = *(const bf16x8*)(Bt + (wid * 32 + j * 16 + lr) * LDST + kk * 32 + kg * 8);
        #pragma unroll
        for (int i = 0; i < 4; ++i)
            #pragma unroll
            for (int j = 0; j < 2; ++j)
                acc[i][j] = __builtin_amdgcn_mfma_f32_16x16x32_bf16(af[i], bf[j], acc[i][j], 0, 0, 0);
    }
    float* sbase = sstate + (((size_t)(b * NHEADS + h)) * NCHUNK + c) * STATE_SZ;
    #pragma unroll
    for (int i = 0; i < 4; ++i)
        #pragma unroll
        for (int j = 0; j < 2; ++j)
            #pragma unroll
            for (int r = 0; r < 4; ++r) {
                int p = i * 16 + kg * 4 + r;
                int n = wid * 32 + j * 16 + lr;
                sbase[p * D_STATE + n] = acc[i][j][r];
            }
}

// ---------------------------------------------------------------------------
// Scan pass: prefix over chunk states per (b,h). In-place, parallel.
// ---------------------------------------------------------------------------
__global__ __launch_bounds__(128) void scan_chunk_prefix(
    const float* __restrict__ cumW, float* __restrict__ sstate)
{
    int blk = blockIdx.x;
    int piece = blk & 15;
    int bh = blk >> 4;
    int tid = threadIdx.x;
    float* base = sstate + (size_t)bh * NCHUNK * STATE_SZ + piece * 512 + tid * 4;
    const float* cw = cumW + (size_t)bh * SEQLEN;
    float4 run = make_float4(0.f, 0.f, 0.f, 0.f);
    for (int c = 0; c < NCHUNK; ++c) {
        float Ac = cw[c * CHUNK + (CHUNK - 1)];
        float* ptr = base + (size_t)c * STATE_SZ;
        float4 loc = *(float4*)ptr;
        *(float4*)ptr = run;
        run.x = fmaf(Ac, run.x, loc.x);
        run.y = fmaf(Ac, run.y, loc.y);
        run.z = fmaf(Ac, run.z, loc.z);
        run.w = fmaf(Ac, run.w, loc.w);
    }
}

// ---------------------------------------------------------------------------
// SSD pass B: full Y per (b,h,chunk). 768 blocks x 512 threads (8 waves).
// ---------------------------------------------------------------------------
__global__ __launch_bounds__(512) void ssd_y(
    const short* __restrict__ co, const float* __restrict__ dtb,
    const float* __restrict__ clgbuf, const float* __restrict__ sstate,
    const float* __restrict__ Dvec, short* __restrict__ ybuf)
{
    __shared__ short lds[26112];
    __shared__ float clg[128];
    __shared__ float dts[128];

    int t = blockIdx.x;
    int c = t & 15;
    int hb = t >> 4;
    int h = hb % NHEADS;
    int b = hb / NHEADS;
    const int R0 = b * SEQLEN + c * CHUNK;
    const int tid  = threadIdx.x;
    const int lane = tid & 63;
    const int wid  = tid >> 6;
    const int lr = lane & 15;
    const int kg = lane >> 4;
    const short* cobase = co + (size_t)R0 * CONV_DIM;

    if (tid < 128) {
        size_t o = ((size_t)(b * NHEADS + h)) * SEQLEN + c * CHUNK + tid;
        clg[tid] = clgbuf[o];
        dts[tid] = dtb[(size_t)(R0 + tid) * NHEADS + h];
    }
    __syncthreads();

    short* CsH = lds;
    short* BsH = lds + 128 * H72;
    const int wmS = wid >> 2, wnS = wid & 3;
    f32x4 accS[4][2];
    #pragma unroll
    for (int i = 0; i < 4; ++i)
        #pragma unroll
        for (int j = 0; j < 2; ++j)
            accS[i][j] = (f32x4){0.f, 0.f, 0.f, 0.f};

    for (int kh = 0; kh < 2; ++kh) {
        {
            int r = tid >> 2, q = tid & 3;
            const short* cr = cobase + (size_t)r * CONV_DIM + (D_INNER + D_STATE) + kh * 64 + q * 16;
            const short* br = cobase + (size_t)r * CONV_DIM + D_INNER + kh * 64 + q * 16;
            *(s16x8*)(CsH + r * H72 + q * 16)     = *(const s16x8*)cr;
            *(s16x8*)(CsH + r * H72 + q * 16 + 8) = *(const s16x8*)(cr + 8);
            *(s16x8*)(BsH + r * H72 + q * 16)     = *(const s16x8*)br;
            *(s16x8*)(BsH + r * H72 + q * 16 + 8) = *(const s16x8*)(br + 8);
        }
        __syncthreads();
        #pragma unroll
        for (int kk = 0; kk < 2; ++kk) {
            bf16x8 af[4], bf[2];
            #pragma unroll
            for (int i = 0; i < 4; ++i)
                af[i] = *(const bf16x8*)(CsH + (wmS * 64 + i * 16 + lr) * H72 + kk * 32 + kg * 8);
            #pragma unroll
            for (int j = 0; j < 2; ++j)
                bf[j] = *(const bf16x8*)(BsH + (wnS * 32 + j * 16 + lr) * H72 + kk * 32 + kg * 8);
            #pragma unroll
            for (int i = 0; i < 4; ++i)
                #pragma unroll
                for (int j = 0; j < 2; ++j)
                    accS[i][j] = __builtin_amdgcn_mfma_f32_16x16x32_bf16(af[i], bf[j], accS[i][j], 0, 0, 0);
        }
        __syncthreads();
    }

    short* Ps = lds;
    short* Xt = lds + 128 * LDST;
    #pragma unroll
    for (int i = 0; i < 4; ++i)
        #pragma unroll
        for (int j = 0; j < 2; ++j)
            #pragma unroll
            for (int r = 0; r < 4; ++r) {
                int l  = wmS * 64 + i * 16 + kg * 4 + r;
                int lp = wnS * 32 + j * 16 + lr;
                float w = (lp <= l) ? __expf(clg[l] - clg[lp]) : 0.f;
                Ps[l * LDST + lp] = f2b(accS[i][j][r] * w);
            }
    if (tid < 256) {
        int r = tid >> 1, q = tid & 1;
        const short* xr = cobase + (size_t)r * CONV_DIM + h * HEADDIM + q * 32;
        float dtv = dts[r];
        #pragma unroll
        for (int i = 0; i < 4; ++i) {
            s16x8 xv = *(const s16x8*)(xr + i * 8);
            #pragma unroll
            for (int e = 0; e < 8; ++e)
                Xt[(q * 32 + i * 8 + e) * LDST + r] = f2b(b2f(xv[e]) * dtv);
        }
    }
    __syncthreads();

    const int wm = wid >> 1, wn = wid & 1;
    f32x4 acc1[2][2];
    #pragma unroll
    for (int i = 0; i < 2; ++i)
        #pragma unroll
        for (int j = 0; j < 2; ++j)
            acc1[i][j] = (f32x4){0.f, 0.f, 0.f, 0.f};
    #pragma unroll
    for (int kk = 0; kk < 4; ++kk) {
        bf16x8 af[2], bf[2];
        #pragma unroll
        for (int i = 0; i < 2; ++i)
            af[i] = *(const bf16x8*)(Ps + (wm * 32 + i * 16 + lr) * LDST + kk * 32 + kg * 8);
        #pragma unroll
        for (int j = 0; j < 2; ++j)
            bf[j] = *(const bf16x8*)(Xt + (wn * 32 + j * 16 + lr) * LDST + kk * 32 + kg * 8);
        #pragma unroll
        for (int i = 0; i < 2; ++i)
            #pragma unroll
            for (int j = 0; j < 2; ++j)
                acc1[i][j] = __builtin_amdgcn_mfma_f32_16x16x32_bf16(af[i], bf[j], acc1[i][j], 0, 0, 0);
    }
    __syncthreads();

    short* Cs = lds;
    short* Sn = lds + 128 * LDST;
    {
        int r = tid >> 2, q = tid & 3;
        const short* cr = cobase + (size_t)r * CONV_DIM + (D_INNER + D_STATE) + q * 32;
        #pragma unroll
        for (int i = 0; i < 4; ++i)
            *(s16x8*)(Cs + r * LDST + q * 32 + i * 8) = *(const s16x8*)(cr + i * 8);
    }
    {
        int r = tid >> 3, q = tid & 7;
        const float* sr = sstate + (((size_t)(b * NHEADS + h)) * NCHUNK + c) * STATE_SZ
                          + (size_t)r * D_STATE + q * 16;
        #pragma unroll
        for (int i = 0; i < 4; ++i) {
            float4 sv = *(const float4*)(sr + i * 4);
            *(short4*)(Sn + r * LDST + q * 16 + i * 4) =
                make_short4(f2b(sv.x), f2b(sv.y), f2b(sv.z), f2b(sv.w));
        }
    }
    __syncthreads();

    f32x4 acc2[2][2];
    #pragma unroll
    for (int i = 0; i < 2; ++i)
        #pragma unroll
        for (int j = 0; j < 2; ++j)
            acc2[i][j] = (f32x4){0.f, 0.f, 0.f, 0.f};
    #pragma unroll
    for (int kk = 0; kk < 4; ++kk) {
        bf16x8 af[2], bf[2];
        #pragma unroll
        for (int i = 0; i < 2; ++i)
            af[i] = *(const bf16x8*)(Cs + (wm * 32 + i * 16 + lr) * LDST + kk * 32 + kg * 8);
        #pragma unroll
        for (int j = 0; j < 2; ++j)
            bf[j] = *(const bf16x8*)(Sn + (wn * 32 + j * 16 + lr) * LDST + kk * 32 + kg * 8);
        #pragma unroll
        for (int i = 0; i < 2; ++i)
            #pragma unroll
            for (int j = 0; j < 2; ++j)
                acc2[i][j] = __builtin_amdgcn_mfma_f32_16x16x32_bf16(af[i], bf[j], acc2[i][j], 0, 0, 0);
    }
    __syncthreads();

    short* yt = lds;
    const float Dh = Dvec[h];
    #pragma unroll
    for (int i = 0; i < 2; ++i)
        #pragma unroll
        for (int j = 0; j < 2; ++j)
            #pragma unroll
            for (int r = 0; r < 4; ++r) {
                int l = wm * 32 + i * 16 + kg * 4 + r;
                int p = wn * 32 + j * 16 + lr;
                float cw = __expf(clg[l]);
                float xval = b2f(cobase[(size_t)l * CONV_DIM + h * HEADDIM + p]);
                yt[l * H72 + p] = f2b(acc1[i][j][r] + cw * acc2[i][j][r] + Dh * xval);
            }
    __syncthreads();
    #pragma unroll
    for (int k = 0; k < 2; ++k) {
        int idx = tid * 2 + k;
        int row = idx >> 3;
        int cp  = idx & 7;
        *(s16x8*)(ybuf + (size_t)(R0 + row) * D_INNER + h * HEADDIM + cp * 8) =
            *(const s16x8*)(yt + row * H72 + cp * 8);
    }
}

// ---------------------------------------------------------------------------
// yz = y * silu(z);  yn = yz * rsqrt(mean(yz^2)+eps) * norm_w  -> bf16
// ---------------------------------------------------------------------------
__global__ __launch_bounds__(192) void gate_norm_kernel(
    const short* __restrict__ zxb, const short* __restrict__ ybuf,
    const float* __restrict__ norm_w, short* __restrict__ yn)
{
    int r = blockIdx.x;
    int c0 = threadIdx.x * 8;
    s16x8 zv = *(const s16x8*)(zxb + (size_t)r * D_IN_PROJ + c0);
    s16x8 yv = *(const s16x8*)(ybuf + (size_t)r * D_INNER + c0);
    float vals[8];
    float ss = 0.f;
    #pragma unroll
    for (int e = 0; e < 8; ++e) {
        float z = b2f(zv[e]);
        float y = b2f(yv[e]);
        float v = y * (z / (1.f + expf(-z)));
        vals[e] = v;
        ss = fmaf(v, v, ss);
    }
    ss += __shfl_xor(ss, 1);
    ss += __shfl_xor(ss, 2);
    ss += __shfl_xor(ss, 4);
    ss += __shfl_xor(ss, 8);
    ss += __shfl_xor(ss, 16);
    ss += __shfl_xor(ss, 32);
    __shared__ float red[3];
    if ((threadIdx.x & 63) == 0) red[threadIdx.x >> 6] = ss;
    __syncthreads();
    float tot = red[0] + red[1] + red[2];
    float scale = rsqrtf(tot / (float)D_INNER + EPS);
    float4 nw0 = *(const float4*)(norm_w + c0);
    float4 nw1 = *(const float4*)(norm_w + c0 + 4);
    const float nw[8] = {nw0.x, nw0.y, nw0.z, nw0.w, nw1.x, nw1.y, nw1.z, nw1.w};
    s16x8 o;
    #pragma unroll
    for (int e = 0; e < 8; ++e)
        o[e] = f2b(vals[e] * scale * nw[e]);
    *(s16x8*)(yn + (size_t)r * D_INNER + c0) = o;
}

// ---------------------------------------------------------------------------
extern "C" void kernel_launch(void* const* d_in, const int* in_sizes, int n_in,
                              void* d_out, int out_size, void* d_ws, size_t ws_size,
                              hipStream_t stream) {
    const float* u          = (const float*)d_in[0];
    const float* in_proj_w  = (const float*)d_in[1];
    const float* conv_w     = (const float*)d_in[2];
    const float* conv_b     = (const float*)d_in[3];
    const float* dt_bias    = (const float*)d_in[4];
    const float* A_log      = (const float*)d_in[5];
    const float* Dvec       = (const float*)d_in[6];
    const float* norm_w     = (const float*)d_in[7];
    const float* out_proj_w = (const float*)d_in[8];
    float* out = (float*)d_out;

    // workspace carve-up:
    short* zxb    = (short*)d_ws;                            // 4096*3352 bf16
    short* cob    = zxb + (size_t)NROWS * D_IN_PROJ;         // 4096*1792 bf16
    float* dtb    = (float*)(cob + (size_t)NROWS * CONV_DIM);
    float* dta    = dtb  + (size_t)NROWS * NHEADS;
    short* ybuf   = (short*)(dta + (size_t)NROWS * NHEADS);  // 4096*1536 bf16
    float* sstate = (float*)(ybuf + (size_t)NROWS * D_INNER);// 48*16*8192 fp32
    float* cumW   = sstate + (size_t)BATCH*NHEADS*NCHUNK*STATE_SZ;
    float* clgbuf = cumW + (size_t)BATCH*NHEADS*SEQLEN;

    // aliases (regions dead at time of use):
    short* ub  = (short*)sstate;               // 4096*768 (dead before ssd_states)
    short* w1b = ub + (size_t)NROWS * D_MODEL; // 3456*768
    short* ynb = (short*)sstate;               // 4096*1536 (after ssd_y reads sstate)
    short* w2b = zxb;                          // 768*1536  (after gate_norm reads z)

    // 0) casts for GEMM1
    cast_bf16_kernel<<<(NROWS*D_MODEL/4 + 255)/256, 256, 0, stream>>>(u, ub, NROWS*D_MODEL/4);
    cast_pad_w1_kernel<<<(N1_PAD*D_MODEL/4 + 255)/256, 256, 0, stream>>>(in_proj_w, w1b);
    // 1) in-proj GEMM (bf16 MFMA, counted-vmcnt pipeline) -> zxb bf16
    gemm_bf16_kernel<<<(NROWS/128)*(N1_PAD/128), 256, 0, stream>>>(ub, w1b, zxb, D_MODEL, D_IN_PROJ, N1_PAD/128);
    // 2) depthwise conv + SiLU
    conv_silu_kernel<<<NROWS*(CONV_DIM/8)/256, 256, 0, stream>>>(zxb, cob, conv_w, conv_b);
    // 3) dt_dis / dtA
    dt_kernel<<<(NROWS*NHEADS + 255)/256, 256, 0, stream>>>(zxb, dt_bias, A_log, dtb, dta);
    // 4) SSD: states -> prefix -> Y
    ssd_states<<<BATCH*NHEADS*NCHUNK, 256, 0, stream>>>(cob, dtb, dta, sstate, cumW, clgbuf);
    scan_chunk_prefix<<<BATCH*NHEADS*16, 128, 0, stream>>>(cumW, sstate);
    ssd_y<<<BATCH*NHEADS*NCHUNK, 512, 0, stream>>>(cob, dtb, clgbuf, sstate, Dvec, ybuf);
    // 5) gate + RMSNorm -> bf16
    gate_norm_kernel<<<NROWS, 192, 0, stream>>>(zxb, ybuf, norm_w, ynb);
    // 6) cast out_proj_w (zxb dead)
    cast_bf16_kernel<<<(D_MODEL*D_INNER/4 + 255)/256, 256, 0, stream>>>(out_proj_w, w2b, D_MODEL*D_INNER/4);
    // 7) out-proj GEMM (counted-vmcnt pipeline) -> fp32 out
    gemm_bf16_n64_kernel<<<(NROWS/128)*(D_MODEL/64), 256, 0, stream>>>(ynb, w2b, out, D_INNER, D_MODEL, D_MODEL/64);
}